// Round 1
// baseline (955.202 us; speedup 1.0000x reference)
//
#include <hip/hip_runtime.h>
#include <math.h>

#define WAVE 64

// ---------------- CSR build ----------------
__global__ void k_zero_i(int* p, int n){
  int i = blockIdx.x*blockDim.x + threadIdx.x;
  if (i < n) p[i] = 0;
}

__global__ void k_count(const int* __restrict__ ei, int E, int N, int* __restrict__ cnt){
  int i = blockIdx.x*blockDim.x + threadIdx.x;
  if (i >= E + N) return;
  int d = (i < E) ? ei[E + i] : (i - E);   // edges then self-loops
  atomicAdd(&cnt[d], 1);
}

__global__ void k_scan(const int* __restrict__ cnt, int* __restrict__ rp, int N){
  __shared__ int sd[1024];
  __shared__ int carry;
  int t = threadIdx.x;
  if (t == 0) carry = 0;
  __syncthreads();
  int iters = (N + 1023) / 1024;
  for (int it = 0; it < iters; ++it){
    int i = it*1024 + t;
    int v = (i < N) ? cnt[i] : 0;
    int c0 = carry;
    sd[t] = v;
    __syncthreads();
    for (int off = 1; off < 1024; off <<= 1){
      int x = (t >= off) ? sd[t-off] : 0;
      __syncthreads();
      sd[t] += x;
      __syncthreads();
    }
    if (i < N) rp[i] = c0 + sd[t] - v;   // exclusive
    int total = sd[1023];
    __syncthreads();
    if (t == 0) carry = c0 + total;
    __syncthreads();
  }
  if (t == 0) rp[N] = carry;
}

__global__ void k_copy_i(const int* __restrict__ a, int* __restrict__ b, int n){
  int i = blockIdx.x*blockDim.x + threadIdx.x;
  if (i < n) b[i] = a[i];
}

__global__ void k_fill(const int* __restrict__ ei, int E, int N,
                       int* __restrict__ cur, int* __restrict__ es){
  int i = blockIdx.x*blockDim.x + threadIdx.x;
  if (i >= E + N) return;
  int s, d;
  if (i < E){ s = ei[i]; d = ei[E + i]; } else { s = d = i - E; }
  int pos = atomicAdd(&cur[d], 1);
  es[pos] = s;
}

__global__ void k_bounds(const int* __restrict__ batch, int N, int B, int* __restrict__ bs){
  int b = blockIdx.x*blockDim.x + threadIdx.x;
  if (b > B) return;
  int lo = 0, hi = N;
  while (lo < hi){ int mid = (lo + hi) >> 1; if (batch[mid] < b) lo = mid + 1; else hi = mid; }
  bs[b] = lo;
}

// ---------------- GEMM: C[M,Nc] = A[M,K] @ W[K,Nc], f32 ----------------
#define BM 64
#define BN 64
#define BK 16
__global__ __launch_bounds__(256)
void k_gemm(const float* __restrict__ A, const float* __restrict__ Bw,
            float* __restrict__ Cc, int M, int K, int Nc){
  __shared__ float As[BK][BM + 4];
  __shared__ float Bs[BK][BN + 4];
  int tid = threadIdx.x;
  int m0 = blockIdx.x * BM, n0 = blockIdx.y * BN;
  int tx = tid & 15, ty = tid >> 4;
  float c[4][4] = {};
  int ar  = tid >> 2, akq = (tid & 3) * 4;   // A: 64 rows x 4 quads
  int bk  = tid >> 4, bn4 = (tid & 15) * 4;  // B: 16 k-rows x 16 quads

  for (int k0 = 0; k0 < K; k0 += BK){
    float4 av = make_float4(0.f,0.f,0.f,0.f);
    int row = m0 + ar;
    if (row < M) av = *(const float4*)(A + (size_t)row*K + k0 + akq);
    As[akq+0][ar] = av.x; As[akq+1][ar] = av.y;
    As[akq+2][ar] = av.z; As[akq+3][ar] = av.w;
    float4 bv = *(const float4*)(Bw + (size_t)(k0 + bk)*Nc + n0 + bn4);
    *(float4*)&Bs[bk][bn4] = bv;
    __syncthreads();
    #pragma unroll
    for (int kk = 0; kk < BK; ++kk){
      float4 a4 = *(const float4*)&As[kk][ty*4];
      float4 b4 = *(const float4*)&Bs[kk][tx*4];
      float a[4] = {a4.x,a4.y,a4.z,a4.w};
      float b[4] = {b4.x,b4.y,b4.z,b4.w};
      #pragma unroll
      for (int i = 0; i < 4; ++i)
        #pragma unroll
        for (int j = 0; j < 4; ++j)
          c[i][j] = fmaf(a[i], b[j], c[i][j]);
    }
    __syncthreads();
  }
  #pragma unroll
  for (int i = 0; i < 4; ++i){
    int row = m0 + ty*4 + i;
    if (row < M){
      float4 r = make_float4(c[i][0], c[i][1], c[i][2], c[i][3]);
      *(float4*)(Cc + (size_t)row*Nc + n0 + tx*4) = r;
    }
  }
}

// ---------------- per-node alpha_s / alpha_d ----------------
template<int HC, int C>
__global__ __launch_bounds__(256)
void k_alpha(const float* __restrict__ h, const float* __restrict__ asr,
             const float* __restrict__ adt, float* __restrict__ as4,
             float* __restrict__ ad4, int N){
  int wid  = (blockIdx.x*blockDim.x + threadIdx.x) >> 6;
  int lane = threadIdx.x & 63;
  if (wid >= N) return;
  const float* hr = h + (size_t)wid * HC;
  float ps[4] = {0,0,0,0}, pd[4] = {0,0,0,0};
  #pragma unroll
  for (int q = 0; q < HC/64; ++q){
    int comp = lane + 64*q;
    float v = hr[comp];
    const int hh = (64*q) / C;           // head is lane-independent
    ps[hh] += v * asr[comp];
    pd[hh] += v * adt[comp];
  }
  #pragma unroll
  for (int off = 32; off > 0; off >>= 1){
    #pragma unroll
    for (int hh = 0; hh < 4; ++hh){
      ps[hh] += __shfl_xor(ps[hh], off, WAVE);
      pd[hh] += __shfl_xor(pd[hh], off, WAVE);
    }
  }
  if (lane == 0){
    *(float4*)(as4 + (size_t)wid*4) = make_float4(ps[0],ps[1],ps[2],ps[3]);
    *(float4*)(ad4 + (size_t)wid*4) = make_float4(pd[0],pd[1],pd[2],pd[3]);
  }
}

// ---------------- GAT aggregation: one wave per destination node ----------------
template<int HC, int C>
__global__ __launch_bounds__(256)
void k_agg(const int* __restrict__ rp, const int* __restrict__ es,
           const float* __restrict__ as4, const float* __restrict__ ad4,
           const float* __restrict__ h, const float* __restrict__ bias,
           float* __restrict__ out, int N){
  constexpr int KQ = HC / 256;            // float4s per lane
  int wid  = (blockIdx.x*blockDim.x + threadIdx.x) >> 6;
  int lane = threadIdx.x & 63;
  if (wid >= N) return;
  int beg = rp[wid], end = rp[wid+1];

  const float4 adv = *(const float4*)(ad4 + (size_t)wid*4);
  float ad[4] = {adv.x, adv.y, adv.z, adv.w};

  // phase A: online softmax stats per head
  float m[4]  = {-1e30f,-1e30f,-1e30f,-1e30f};
  float sm[4] = {0.f,0.f,0.f,0.f};
  for (int i = beg + lane; i < end; i += WAVE){
    int s = es[i];
    const float4 av = *(const float4*)(as4 + (size_t)s*4);
    float a[4] = {av.x,av.y,av.z,av.w};
    #pragma unroll
    for (int hh = 0; hh < 4; ++hh){
      float e = a[hh] + ad[hh];
      e = (e >= 0.f) ? e : 0.2f*e;
      float mn = fmaxf(m[hh], e);
      sm[hh] = sm[hh]*expf(m[hh]-mn) + expf(e-mn);
      m[hh] = mn;
    }
  }
  #pragma unroll
  for (int off = 32; off > 0; off >>= 1){
    #pragma unroll
    for (int hh = 0; hh < 4; ++hh){
      float mo = __shfl_xor(m[hh],  off, WAVE);
      float so = __shfl_xor(sm[hh], off, WAVE);
      float mn = fmaxf(m[hh], mo);
      sm[hh] = sm[hh]*expf(m[hh]-mn) + so*expf(mo-mn);
      m[hh] = mn;
    }
  }
  float invd[4];
  #pragma unroll
  for (int hh = 0; hh < 4; ++hh) invd[hh] = 1.f/(sm[hh] + 1e-16f);

  // phase B: weighted gather of h[src]
  float4 acc[KQ];
  #pragma unroll
  for (int k = 0; k < KQ; ++k) acc[k] = make_float4(0,0,0,0);
  int myh[KQ];
  #pragma unroll
  for (int k = 0; k < KQ; ++k) myh[k] = (4*(lane + 64*k)) / C;

  for (int cb = beg; cb < end; cb += WAVE){
    int nn = min(WAVE, end - cb);
    int sidx = 0;
    float w4[4] = {0,0,0,0};
    if (cb + lane < end){
      sidx = es[cb + lane];
      const float4 av = *(const float4*)(as4 + (size_t)sidx*4);
      float a[4] = {av.x,av.y,av.z,av.w};
      #pragma unroll
      for (int hh = 0; hh < 4; ++hh){
        float e = a[hh] + ad[hh];
        e = (e >= 0.f) ? e : 0.2f*e;
        w4[hh] = expf(e - m[hh]) * invd[hh];
      }
    }
    for (int j = 0; j < nn; ++j){
      int s = __shfl(sidx, j, WAVE);
      float wb[4];
      #pragma unroll
      for (int hh = 0; hh < 4; ++hh) wb[hh] = __shfl(w4[hh], j, WAVE);
      const float4* hr = (const float4*)(h + (size_t)s * HC);
      #pragma unroll
      for (int k = 0; k < KQ; ++k){
        float4 v = hr[lane + 64*k];
        float w = wb[myh[k]];
        acc[k].x += w*v.x; acc[k].y += w*v.y;
        acc[k].z += w*v.z; acc[k].w += w*v.w;
      }
    }
  }

  const float4* bp = (const float4*)bias;
  float4* op = (float4*)(out + (size_t)wid*HC);
  #pragma unroll
  for (int k = 0; k < KQ; ++k){
    float4 bv = bp[lane + 64*k];
    float4 r;
    r.x = acc[k].x + bv.x; r.y = acc[k].y + bv.y;
    r.z = acc[k].z + bv.z; r.w = acc[k].w + bv.w;
    r.x = r.x > 0.f ? r.x : expm1f(r.x);
    r.y = r.y > 0.f ? r.y : expm1f(r.y);
    r.z = r.z > 0.f ? r.z : expm1f(r.z);
    r.w = r.w > 0.f ? r.w : expm1f(r.w);
    op[lane + 64*k] = r;
  }
}

// ---------------- pooling + FC ----------------
__global__ void k_pool_partial(const float* __restrict__ h, const int* __restrict__ bs,
                               float* __restrict__ psum, float* __restrict__ pmax){
  int b = blockIdx.x, ch = blockIdx.y;
  int f = threadIdx.x;                    // 512 feats
  int s = bs[b], e = bs[b+1];
  long long len = e - s;
  int i0 = s + (int)(len * ch / 8);
  int i1 = s + (int)(len * (ch+1) / 8);
  float sm = 0.f, mx = -3.0e38f;
  for (int i = i0; i < i1; ++i){
    float v = h[(size_t)i*512 + f];
    sm += v; mx = fmaxf(mx, v);
  }
  int idx = (b*8 + ch)*512 + f;
  psum[idx] = sm; pmax[idx] = mx;
}

__global__ void k_pool_final(const float* __restrict__ psum, const float* __restrict__ pmax,
                             const int* __restrict__ bs, float* __restrict__ g){
  int b = blockIdx.x, f = threadIdx.x;
  float sm = 0.f, mx = -3.0e38f;
  for (int c = 0; c < 8; ++c){
    int idx = (b*8 + c)*512 + f;
    sm += psum[idx]; mx = fmaxf(mx, pmax[idx]);
  }
  int cnt = bs[b+1] - bs[b];
  g[b*1024 + f] = sm / fmaxf((float)cnt, 1.f);
  g[b*1024 + 512 + f] = (mx > -1e37f) ? mx : 0.f;
}

__global__ __launch_bounds__(256)
void k_fc(const float* __restrict__ g, const float* __restrict__ fcW,
          const float* __restrict__ fcb, float* __restrict__ out){
  __shared__ float gs[1024];
  int b = blockIdx.x, t = threadIdx.x;
  for (int i = t; i < 1024; i += 256) gs[i] = g[b*1024 + i];
  __syncthreads();
  for (int o = t; o < 512; o += 256){
    float acc = fcb[o];
    #pragma unroll 4
    for (int k = 0; k < 1024; ++k)
      acc = fmaf(gs[k], fcW[(size_t)k*512 + o], acc);
    out[b*512 + o] = acc;
  }
}

// ---------------- launcher ----------------
extern "C" void kernel_launch(void* const* d_in, const int* in_sizes, int n_in,
                              void* d_out, int out_size, void* d_ws, size_t ws_size,
                              hipStream_t stream){
  (void)n_in; (void)out_size; (void)ws_size;
  const float* x     = (const float*)d_in[0];
  const int*   ei    = (const int*)d_in[1];
  const int*   batch = (const int*)d_in[2];
  const float* W[4]   = {(const float*)d_in[3],(const float*)d_in[7],(const float*)d_in[11],(const float*)d_in[15]};
  const float* asr[4] = {(const float*)d_in[4],(const float*)d_in[8],(const float*)d_in[12],(const float*)d_in[16]};
  const float* adt[4] = {(const float*)d_in[5],(const float*)d_in[9],(const float*)d_in[13],(const float*)d_in[17]};
  const float* bb[4]  = {(const float*)d_in[6],(const float*)d_in[10],(const float*)d_in[14],(const float*)d_in[18]};
  const float* fcW = (const float*)d_in[19];
  const float* fcb = (const float*)d_in[20];

  const int N  = in_sizes[0] / 128;
  const int E  = in_sizes[1] / 2;
  const int EN = E + N;
  const int B  = 32;

  char* p = (char*)d_ws;
  auto alloc = [&](size_t bytes){ void* r = (void*)p; p += (bytes + 255) & ~(size_t)255; return r; };
  float* bufA = (float*)alloc((size_t)N*512*4);
  float* bufB = (float*)alloc((size_t)N*512*4);
  float* as4  = (float*)alloc((size_t)N*4*4);
  float* ad4  = (float*)alloc((size_t)N*4*4);
  int*   cnt  = (int*)alloc((size_t)N*4);
  int*   rp   = (int*)alloc((size_t)(N+1)*4);
  int*   cur  = (int*)alloc((size_t)N*4);
  int*   es   = (int*)alloc((size_t)EN*4);
  int*   bs   = (int*)alloc((size_t)(B+1)*4);
  float* gpo  = (float*)alloc((size_t)B*1024*4);
  float* psum = (float*)alloc((size_t)B*8*512*4);
  float* pmax = (float*)alloc((size_t)B*8*512*4);

  // CSR build (once per launch; identical every call)
  k_zero_i<<<(N+255)/256, 256, 0, stream>>>(cnt, N);
  k_count<<<(EN+255)/256, 256, 0, stream>>>(ei, E, N, cnt);
  k_scan<<<1, 1024, 0, stream>>>(cnt, rp, N);
  k_copy_i<<<(N+255)/256, 256, 0, stream>>>(rp, cur, N);
  k_fill<<<(EN+255)/256, 256, 0, stream>>>(ei, E, N, cur, es);
  k_bounds<<<1, 64, 0, stream>>>(batch, N, B, bs);

  const int Kd[4]  = {128, 256, 256, 256};
  const int HCd[4] = {256, 256, 256, 512};
  const float* in_ptr = x;
  const int wgrid = (N + 3) / 4;     // 4 waves / block

  for (int L = 0; L < 4; ++L){
    dim3 gg((N + BM - 1)/BM, HCd[L]/BN);
    k_gemm<<<gg, 256, 0, stream>>>(in_ptr, W[L], bufB, N, Kd[L], HCd[L]);
    if (HCd[L] == 256){
      k_alpha<256,64><<<wgrid, 256, 0, stream>>>(bufB, asr[L], adt[L], as4, ad4, N);
      k_agg<256,64><<<wgrid, 256, 0, stream>>>(rp, es, as4, ad4, bufB, bb[L], bufA, N);
    } else {
      k_alpha<512,128><<<wgrid, 256, 0, stream>>>(bufB, asr[L], adt[L], as4, ad4, N);
      k_agg<512,128><<<wgrid, 256, 0, stream>>>(rp, es, as4, ad4, bufB, bb[L], bufA, N);
    }
    in_ptr = bufA;
  }

  dim3 pg(B, 8);
  k_pool_partial<<<pg, 512, 0, stream>>>(bufA, bs, psum, pmax);
  k_pool_final<<<B, 512, 0, stream>>>(psum, pmax, bs, gpo);
  k_fc<<<B, 256, 0, stream>>>(gpo, fcW, fcb, (float*)d_out);
}

// Round 2
// 846.302 us; speedup vs baseline: 1.1287x; 1.1287x over previous
//
#include <hip/hip_runtime.h>
#include <math.h>

#define WAVE 64

// ---------------- CSR build ----------------
__global__ void k_zero_i(int* p, int n){
  int i = blockIdx.x*blockDim.x + threadIdx.x;
  if (i < n) p[i] = 0;
}

__global__ void k_count(const int* __restrict__ ei, int E, int N, int* __restrict__ cnt){
  int i = blockIdx.x*blockDim.x + threadIdx.x;
  if (i >= E + N) return;
  int d = (i < E) ? ei[E + i] : (i - E);   // edges then self-loops
  atomicAdd(&cnt[d], 1);
}

// multi-block exclusive scan: k_scan1 (block scans) -> k_scan2 (scan of block sums) -> k_scan3 (fixup)
__global__ __launch_bounds__(1024)
void k_scan1(const int* __restrict__ cnt, int* __restrict__ rp, int* __restrict__ bsum, int N){
  __shared__ int sd[1024];
  int t = threadIdx.x, i = blockIdx.x*1024 + t;
  int v = (i < N) ? cnt[i] : 0;
  sd[t] = v;
  __syncthreads();
  for (int off = 1; off < 1024; off <<= 1){
    int x = (t >= off) ? sd[t-off] : 0;
    __syncthreads();
    sd[t] += x;
    __syncthreads();
  }
  if (i < N) rp[i] = sd[t] - v;            // exclusive within block
  if (t == 1023) bsum[blockIdx.x] = sd[1023];
}

__global__ void k_scan2(int* __restrict__ bsum, int nb, int* __restrict__ rp, int N){
  int t = threadIdx.x;                      // 64 threads
  int orig = (t < nb) ? bsum[t] : 0;
  int v = orig;
  #pragma unroll
  for (int off = 1; off < 64; off <<= 1){
    int x = __shfl_up(v, off, WAVE);
    if (t >= off) v += x;
  }
  if (t < nb) bsum[t] = v - orig;           // exclusive block offset
  if (t == 63) rp[N] = v;                   // grand total
}

__global__ __launch_bounds__(1024)
void k_scan3(int* __restrict__ rp, const int* __restrict__ bsum, int N){
  int i = blockIdx.x*1024 + threadIdx.x;
  if (i < N) rp[i] += bsum[blockIdx.x];
}

__global__ void k_copy_i(const int* __restrict__ a, int* __restrict__ b, int n){
  int i = blockIdx.x*blockDim.x + threadIdx.x;
  if (i < n) b[i] = a[i];
}

__global__ void k_fill(const int* __restrict__ ei, int E, int N,
                       int* __restrict__ cur, int* __restrict__ es){
  int i = blockIdx.x*blockDim.x + threadIdx.x;
  if (i >= E + N) return;
  int s, d;
  if (i < E){ s = ei[i]; d = ei[E + i]; } else { s = d = i - E; }
  int pos = atomicAdd(&cur[d], 1);
  es[pos] = s;
}

__global__ void k_bounds(const int* __restrict__ batch, int N, int B, int* __restrict__ bs){
  int b = blockIdx.x*blockDim.x + threadIdx.x;
  if (b > B) return;
  int lo = 0, hi = N;
  while (lo < hi){ int mid = (lo + hi) >> 1; if (batch[mid] < b) lo = mid + 1; else hi = mid; }
  bs[b] = lo;
}

// ---------------- GEMM: C[M,Nc] = A[M,K] @ W[K,Nc], f32 ----------------
#define BM 64
#define BN 64
#define BK 16
__global__ __launch_bounds__(256)
void k_gemm(const float* __restrict__ A, const float* __restrict__ Bw,
            float* __restrict__ Cc, int M, int K, int Nc){
  __shared__ float As[BK][BM + 4];
  __shared__ float Bs[BK][BN + 4];
  int tid = threadIdx.x;
  int m0 = blockIdx.x * BM, n0 = blockIdx.y * BN;
  int tx = tid & 15, ty = tid >> 4;
  float c[4][4] = {};
  int ar  = tid >> 2, akq = (tid & 3) * 4;   // A: 64 rows x 4 quads
  int bk  = tid >> 4, bn4 = (tid & 15) * 4;  // B: 16 k-rows x 16 quads

  for (int k0 = 0; k0 < K; k0 += BK){
    float4 av = make_float4(0.f,0.f,0.f,0.f);
    int row = m0 + ar;
    if (row < M) av = *(const float4*)(A + (size_t)row*K + k0 + akq);
    As[akq+0][ar] = av.x; As[akq+1][ar] = av.y;
    As[akq+2][ar] = av.z; As[akq+3][ar] = av.w;
    float4 bv = *(const float4*)(Bw + (size_t)(k0 + bk)*Nc + n0 + bn4);
    *(float4*)&Bs[bk][bn4] = bv;
    __syncthreads();
    #pragma unroll
    for (int kk = 0; kk < BK; ++kk){
      float4 a4 = *(const float4*)&As[kk][ty*4];
      float4 b4 = *(const float4*)&Bs[kk][tx*4];
      float a[4] = {a4.x,a4.y,a4.z,a4.w};
      float b[4] = {b4.x,b4.y,b4.z,b4.w};
      #pragma unroll
      for (int i = 0; i < 4; ++i)
        #pragma unroll
        for (int j = 0; j < 4; ++j)
          c[i][j] = fmaf(a[i], b[j], c[i][j]);
    }
    __syncthreads();
  }
  #pragma unroll
  for (int i = 0; i < 4; ++i){
    int row = m0 + ty*4 + i;
    if (row < M){
      float4 r = make_float4(c[i][0], c[i][1], c[i][2], c[i][3]);
      *(float4*)(Cc + (size_t)row*Nc + n0 + tx*4) = r;
    }
  }
}

// ---------------- per-node alpha_s / alpha_d ----------------
template<int HC, int C>
__global__ __launch_bounds__(256)
void k_alpha(const float* __restrict__ h, const float* __restrict__ asr,
             const float* __restrict__ adt, float* __restrict__ as4,
             float* __restrict__ ad4, int N){
  int wid  = (blockIdx.x*blockDim.x + threadIdx.x) >> 6;
  int lane = threadIdx.x & 63;
  if (wid >= N) return;
  const float* hr = h + (size_t)wid * HC;
  float ps[4] = {0,0,0,0}, pd[4] = {0,0,0,0};
  #pragma unroll
  for (int q = 0; q < HC/64; ++q){
    int comp = lane + 64*q;
    float v = hr[comp];
    const int hh = (64*q) / C;           // head is lane-independent
    ps[hh] += v * asr[comp];
    pd[hh] += v * adt[comp];
  }
  #pragma unroll
  for (int off = 32; off > 0; off >>= 1){
    #pragma unroll
    for (int hh = 0; hh < 4; ++hh){
      ps[hh] += __shfl_xor(ps[hh], off, WAVE);
      pd[hh] += __shfl_xor(pd[hh], off, WAVE);
    }
  }
  if (lane == 0){
    *(float4*)(as4 + (size_t)wid*4) = make_float4(ps[0],ps[1],ps[2],ps[3]);
    *(float4*)(ad4 + (size_t)wid*4) = make_float4(pd[0],pd[1],pd[2],pd[3]);
  }
}

// ---------------- GAT aggregation: one wave per destination node ----------------
__device__ __forceinline__ float sel4(const float w[4], int m){
  float r = w[0];
  r = (m == 1) ? w[1] : r;
  r = (m == 2) ? w[2] : r;
  r = (m == 3) ? w[3] : r;
  return r;
}

template<int HC, int C>
__global__ __launch_bounds__(256)
void k_agg(const int* __restrict__ rp, const int* __restrict__ es,
           const float* __restrict__ as4, const float* __restrict__ ad4,
           const float* __restrict__ h, const float* __restrict__ bias,
           float* __restrict__ out, int N){
  constexpr int KQ = HC / 256;            // float4s per lane
  int wid  = (blockIdx.x*blockDim.x + threadIdx.x) >> 6;
  int lane = threadIdx.x & 63;
  if (wid >= N) return;
  int beg = rp[wid], end = rp[wid+1];

  const float4 adv = *(const float4*)(ad4 + (size_t)wid*4);
  float ad[4] = {adv.x, adv.y, adv.z, adv.w};

  // phase A: online softmax stats per head
  float m[4]  = {-1e30f,-1e30f,-1e30f,-1e30f};
  float sm[4] = {0.f,0.f,0.f,0.f};
  for (int i = beg + lane; i < end; i += WAVE){
    int s = es[i];
    const float4 av = *(const float4*)(as4 + (size_t)s*4);
    float a[4] = {av.x,av.y,av.z,av.w};
    #pragma unroll
    for (int hh = 0; hh < 4; ++hh){
      float e = a[hh] + ad[hh];
      e = (e >= 0.f) ? e : 0.2f*e;
      float mn = fmaxf(m[hh], e);
      sm[hh] = sm[hh]*__expf(m[hh]-mn) + __expf(e-mn);
      m[hh] = mn;
    }
  }
  #pragma unroll
  for (int off = 32; off > 0; off >>= 1){
    #pragma unroll
    for (int hh = 0; hh < 4; ++hh){
      float mo = __shfl_xor(m[hh],  off, WAVE);
      float so = __shfl_xor(sm[hh], off, WAVE);
      float mn = fmaxf(m[hh], mo);
      sm[hh] = sm[hh]*__expf(m[hh]-mn) + so*__expf(mo-mn);
      m[hh] = mn;
    }
  }
  float invd[4];
  #pragma unroll
  for (int hh = 0; hh < 4; ++hh) invd[hh] = 1.f/(sm[hh] + 1e-16f);

  // phase B: weighted gather of h[src]
  float4 acc[KQ];
  #pragma unroll
  for (int k = 0; k < KQ; ++k) acc[k] = make_float4(0,0,0,0);
  int myh[KQ];
  #pragma unroll
  for (int k = 0; k < KQ; ++k) myh[k] = (4*(lane + 64*k)) / C;

  for (int cb = beg; cb < end; cb += WAVE){
    int nn = min(WAVE, end - cb);
    int sidx = 0;
    float w4[4] = {0,0,0,0};
    if (cb + lane < end){
      sidx = es[cb + lane];
      const float4 av = *(const float4*)(as4 + (size_t)sidx*4);
      float a[4] = {av.x,av.y,av.z,av.w};
      #pragma unroll
      for (int hh = 0; hh < 4; ++hh){
        float e = a[hh] + ad[hh];
        e = (e >= 0.f) ? e : 0.2f*e;
        w4[hh] = __expf(e - m[hh]) * invd[hh];
      }
    }
    int j = 0;
    // 4-edge groups: 4*KQ row loads in flight per iteration
    for (; j + 4 <= nn; j += 4){
      int s0 = __shfl(sidx, j+0, WAVE), s1 = __shfl(sidx, j+1, WAVE);
      int s2 = __shfl(sidx, j+2, WAVE), s3 = __shfl(sidx, j+3, WAVE);
      float wb0[4], wb1[4], wb2[4], wb3[4];
      #pragma unroll
      for (int hh = 0; hh < 4; ++hh){
        wb0[hh] = __shfl(w4[hh], j+0, WAVE);
        wb1[hh] = __shfl(w4[hh], j+1, WAVE);
        wb2[hh] = __shfl(w4[hh], j+2, WAVE);
        wb3[hh] = __shfl(w4[hh], j+3, WAVE);
      }
      const float4* r0 = (const float4*)(h + (size_t)s0*HC);
      const float4* r1 = (const float4*)(h + (size_t)s1*HC);
      const float4* r2 = (const float4*)(h + (size_t)s2*HC);
      const float4* r3 = (const float4*)(h + (size_t)s3*HC);
      #pragma unroll
      for (int k = 0; k < KQ; ++k){
        int col = lane + 64*k;
        float4 v0 = r0[col], v1 = r1[col], v2 = r2[col], v3 = r3[col];
        float u0 = sel4(wb0, myh[k]), u1 = sel4(wb1, myh[k]);
        float u2 = sel4(wb2, myh[k]), u3 = sel4(wb3, myh[k]);
        acc[k].x = fmaf(u0, v0.x, fmaf(u1, v1.x, fmaf(u2, v2.x, fmaf(u3, v3.x, acc[k].x))));
        acc[k].y = fmaf(u0, v0.y, fmaf(u1, v1.y, fmaf(u2, v2.y, fmaf(u3, v3.y, acc[k].y))));
        acc[k].z = fmaf(u0, v0.z, fmaf(u1, v1.z, fmaf(u2, v2.z, fmaf(u3, v3.z, acc[k].z))));
        acc[k].w = fmaf(u0, v0.w, fmaf(u1, v1.w, fmaf(u2, v2.w, fmaf(u3, v3.w, acc[k].w))));
      }
    }
    for (; j < nn; ++j){
      int s = __shfl(sidx, j, WAVE);
      float wb[4];
      #pragma unroll
      for (int hh = 0; hh < 4; ++hh) wb[hh] = __shfl(w4[hh], j, WAVE);
      const float4* hr = (const float4*)(h + (size_t)s * HC);
      #pragma unroll
      for (int k = 0; k < KQ; ++k){
        float4 v = hr[lane + 64*k];
        float w = sel4(wb, myh[k]);
        acc[k].x = fmaf(w, v.x, acc[k].x); acc[k].y = fmaf(w, v.y, acc[k].y);
        acc[k].z = fmaf(w, v.z, acc[k].z); acc[k].w = fmaf(w, v.w, acc[k].w);
      }
    }
  }

  const float4* bp = (const float4*)bias;
  float4* op = (float4*)(out + (size_t)wid*HC);
  #pragma unroll
  for (int k = 0; k < KQ; ++k){
    float4 bv = bp[lane + 64*k];
    float4 r;
    r.x = acc[k].x + bv.x; r.y = acc[k].y + bv.y;
    r.z = acc[k].z + bv.z; r.w = acc[k].w + bv.w;
    r.x = r.x > 0.f ? r.x : expm1f(r.x);
    r.y = r.y > 0.f ? r.y : expm1f(r.y);
    r.z = r.z > 0.f ? r.z : expm1f(r.z);
    r.w = r.w > 0.f ? r.w : expm1f(r.w);
    op[lane + 64*k] = r;
  }
}

// ---------------- pooling + FC ----------------
__global__ void k_pool_partial(const float* __restrict__ h, const int* __restrict__ bs,
                               float* __restrict__ psum, float* __restrict__ pmax){
  int b = blockIdx.x, ch = blockIdx.y;
  int f = threadIdx.x;                    // 512 feats
  int s = bs[b], e = bs[b+1];
  long long len = e - s;
  int i0 = s + (int)(len * ch / 8);
  int i1 = s + (int)(len * (ch+1) / 8);
  float sm = 0.f, mx = -3.0e38f;
  for (int i = i0; i < i1; ++i){
    float v = h[(size_t)i*512 + f];
    sm += v; mx = fmaxf(mx, v);
  }
  int idx = (b*8 + ch)*512 + f;
  psum[idx] = sm; pmax[idx] = mx;
}

__global__ void k_pool_final(const float* __restrict__ psum, const float* __restrict__ pmax,
                             const int* __restrict__ bs, float* __restrict__ g){
  int b = blockIdx.x, f = threadIdx.x;
  float sm = 0.f, mx = -3.0e38f;
  for (int c = 0; c < 8; ++c){
    int idx = (b*8 + c)*512 + f;
    sm += psum[idx]; mx = fmaxf(mx, pmax[idx]);
  }
  int cnt = bs[b+1] - bs[b];
  g[b*1024 + f] = sm / fmaxf((float)cnt, 1.f);
  g[b*1024 + 512 + f] = (mx > -1e37f) ? mx : 0.f;
}

// split-k FC: grid (32 batch, 8 out-groups of 64), 256 threads = 64 outputs x 4 k-chunks
__global__ __launch_bounds__(256)
void k_fc(const float* __restrict__ g, const float* __restrict__ fcW,
          const float* __restrict__ fcb, float* __restrict__ out){
  __shared__ float gs[1024];
  __shared__ float red[4][64];
  int b = blockIdx.x, t = threadIdx.x;
  int o0 = blockIdx.y * 64;
  for (int i = t; i < 1024; i += 256) gs[i] = g[b*1024 + i];
  __syncthreads();
  int ol = t & 63, q = t >> 6;
  const float* wp = fcW + (size_t)(q*256)*512 + o0 + ol;
  float acc = 0.f;
  #pragma unroll 8
  for (int k = 0; k < 256; ++k)
    acc = fmaf(gs[q*256 + k], wp[(size_t)k*512], acc);
  red[q][ol] = acc;
  __syncthreads();
  if (t < 64){
    float r = red[0][t] + red[1][t] + red[2][t] + red[3][t] + fcb[o0 + t];
    out[b*512 + o0 + t] = r;
  }
}

// ---------------- launcher ----------------
extern "C" void kernel_launch(void* const* d_in, const int* in_sizes, int n_in,
                              void* d_out, int out_size, void* d_ws, size_t ws_size,
                              hipStream_t stream){
  (void)n_in; (void)out_size; (void)ws_size;
  const float* x     = (const float*)d_in[0];
  const int*   ei    = (const int*)d_in[1];
  const int*   batch = (const int*)d_in[2];
  const float* W[4]   = {(const float*)d_in[3],(const float*)d_in[7],(const float*)d_in[11],(const float*)d_in[15]};
  const float* asr[4] = {(const float*)d_in[4],(const float*)d_in[8],(const float*)d_in[12],(const float*)d_in[16]};
  const float* adt[4] = {(const float*)d_in[5],(const float*)d_in[9],(const float*)d_in[13],(const float*)d_in[17]};
  const float* bb[4]  = {(const float*)d_in[6],(const float*)d_in[10],(const float*)d_in[14],(const float*)d_in[18]};
  const float* fcW = (const float*)d_in[19];
  const float* fcb = (const float*)d_in[20];

  const int N  = in_sizes[0] / 128;
  const int E  = in_sizes[1] / 2;
  const int EN = E + N;
  const int B  = 32;
  const int NB = (N + 1023) / 1024;

  char* p = (char*)d_ws;
  auto alloc = [&](size_t bytes){ void* r = (void*)p; p += (bytes + 255) & ~(size_t)255; return r; };
  float* bufA = (float*)alloc((size_t)N*512*4);
  float* bufB = (float*)alloc((size_t)N*512*4);
  float* as4  = (float*)alloc((size_t)N*4*4);
  float* ad4  = (float*)alloc((size_t)N*4*4);
  int*   cnt  = (int*)alloc((size_t)N*4);
  int*   rp   = (int*)alloc((size_t)(N+1)*4);
  int*   cur  = (int*)alloc((size_t)N*4);
  int*   es   = (int*)alloc((size_t)EN*4);
  int*   bs   = (int*)alloc((size_t)(B+1)*4);
  int*   bsum = (int*)alloc((size_t)64*4);
  float* gpo  = (float*)alloc((size_t)B*1024*4);
  float* psum = (float*)alloc((size_t)B*8*512*4);
  float* pmax = (float*)alloc((size_t)B*8*512*4);

  // CSR build (deterministic result; es order within a dst is atomic-ordered but sums are order-invariant)
  k_zero_i<<<(N+255)/256, 256, 0, stream>>>(cnt, N);
  k_count<<<(EN+255)/256, 256, 0, stream>>>(ei, E, N, cnt);
  k_scan1<<<NB, 1024, 0, stream>>>(cnt, rp, bsum, N);
  k_scan2<<<1, 64, 0, stream>>>(bsum, NB, rp, N);
  k_scan3<<<NB, 1024, 0, stream>>>(rp, bsum, N);
  k_copy_i<<<(N+255)/256, 256, 0, stream>>>(rp, cur, N);
  k_fill<<<(EN+255)/256, 256, 0, stream>>>(ei, E, N, cur, es);
  k_bounds<<<1, 64, 0, stream>>>(batch, N, B, bs);

  const int Kd[4]  = {128, 256, 256, 256};
  const int HCd[4] = {256, 256, 256, 512};
  const float* in_ptr = x;
  const int wgrid = (N + 3) / 4;     // 4 waves / block

  for (int L = 0; L < 4; ++L){
    dim3 gg((N + BM - 1)/BM, HCd[L]/BN);
    k_gemm<<<gg, 256, 0, stream>>>(in_ptr, W[L], bufB, N, Kd[L], HCd[L]);
    if (HCd[L] == 256){
      k_alpha<256,64><<<wgrid, 256, 0, stream>>>(bufB, asr[L], adt[L], as4, ad4, N);
      k_agg<256,64><<<wgrid, 256, 0, stream>>>(rp, es, as4, ad4, bufB, bb[L], bufA, N);
    } else {
      k_alpha<512,128><<<wgrid, 256, 0, stream>>>(bufB, asr[L], adt[L], as4, ad4, N);
      k_agg<512,128><<<wgrid, 256, 0, stream>>>(rp, es, as4, ad4, bufB, bb[L], bufA, N);
    }
    in_ptr = bufA;
  }

  dim3 pg(B, 8);
  k_pool_partial<<<pg, 512, 0, stream>>>(bufA, bs, psum, pmax);
  k_pool_final<<<B, 512, 0, stream>>>(psum, pmax, bs, gpo);
  dim3 fg(B, 8);
  k_fc<<<fg, 256, 0, stream>>>(gpo, fcW, fcb, (float*)d_out);
}

// Round 3
// 737.105 us; speedup vs baseline: 1.2959x; 1.1481x over previous
//
#include <hip/hip_runtime.h>
#include <math.h>

#define WAVE 64

typedef __attribute__((ext_vector_type(8))) short short8v;
typedef __attribute__((ext_vector_type(4))) float f32x4;

__device__ __forceinline__ unsigned short f2b(float x){
  unsigned u = __float_as_uint(x);
  unsigned r = u + 0x7fffu + ((u >> 16) & 1u);
  return (unsigned short)(r >> 16);
}
__device__ __forceinline__ float b2f(unsigned short h){
  return __uint_as_float(((unsigned)h) << 16);
}

// ---------------- CSR build ----------------
__global__ void k_zero_i(int* p, int n){
  int i = blockIdx.x*blockDim.x + threadIdx.x;
  if (i < n) p[i] = 0;
}

__global__ void k_count(const int* __restrict__ ei, int E, int N, int* __restrict__ cnt){
  int i = blockIdx.x*blockDim.x + threadIdx.x;
  if (i >= E + N) return;
  int d = (i < E) ? ei[E + i] : (i - E);
  atomicAdd(&cnt[d], 1);
}

__global__ __launch_bounds__(1024)
void k_scan1(const int* __restrict__ cnt, int* __restrict__ rp, int* __restrict__ bsum, int N){
  __shared__ int sd[1024];
  int t = threadIdx.x, i = blockIdx.x*1024 + t;
  int v = (i < N) ? cnt[i] : 0;
  sd[t] = v;
  __syncthreads();
  for (int off = 1; off < 1024; off <<= 1){
    int x = (t >= off) ? sd[t-off] : 0;
    __syncthreads();
    sd[t] += x;
    __syncthreads();
  }
  if (i < N) rp[i] = sd[t] - v;
  if (t == 1023) bsum[blockIdx.x] = sd[1023];
}

__global__ void k_scan2(int* __restrict__ bsum, int nb, int* __restrict__ rp, int N){
  int t = threadIdx.x;
  int orig = (t < nb) ? bsum[t] : 0;
  int v = orig;
  #pragma unroll
  for (int off = 1; off < 64; off <<= 1){
    int x = __shfl_up(v, off, WAVE);
    if (t >= off) v += x;
  }
  if (t < nb) bsum[t] = v - orig;
  if (t == 63) rp[N] = v;
}

__global__ __launch_bounds__(1024)
void k_scan3(int* __restrict__ rp, const int* __restrict__ bsum, int N){
  int i = blockIdx.x*1024 + threadIdx.x;
  if (i < N) rp[i] += bsum[blockIdx.x];
}

__global__ void k_copy_i(const int* __restrict__ a, int* __restrict__ b, int n){
  int i = blockIdx.x*blockDim.x + threadIdx.x;
  if (i < n) b[i] = a[i];
}

__global__ void k_fill(const int* __restrict__ ei, int E, int N,
                       int* __restrict__ cur, int* __restrict__ es){
  int i = blockIdx.x*blockDim.x + threadIdx.x;
  if (i >= E + N) return;
  int s, d;
  if (i < E){ s = ei[i]; d = ei[E + i]; } else { s = d = i - E; }
  int pos = atomicAdd(&cur[d], 1);
  es[pos] = s;
}

__global__ void k_bounds(const int* __restrict__ batch, int N, int B, int* __restrict__ bs){
  int b = blockIdx.x*blockDim.x + threadIdx.x;
  if (b > B) return;
  int lo = 0, hi = N;
  while (lo < hi){ int mid = (lo + hi) >> 1; if (batch[mid] < b) lo = mid + 1; else hi = mid; }
  bs[b] = lo;
}

// ---------------- f32 -> bf16 hi/lo conversion ----------------
__global__ __launch_bounds__(256)
void k_cvt(const float* __restrict__ in, unsigned short* __restrict__ hi,
           unsigned short* __restrict__ lo, int n4){
  int i = blockIdx.x*blockDim.x + threadIdx.x;
  if (i >= n4) return;
  float4 v = ((const float4*)in)[i];
  ushort4 h, l;
  h.x = f2b(v.x); l.x = f2b(v.x - b2f(h.x));
  h.y = f2b(v.y); l.y = f2b(v.y - b2f(h.y));
  h.z = f2b(v.z); l.z = f2b(v.z - b2f(h.z));
  h.w = f2b(v.w); l.w = f2b(v.w - b2f(h.w));
  ((ushort4*)hi)[i] = h;
  ((ushort4*)lo)[i] = l;
}

// W[K,Nc] -> W^T hi/lo [Nc,K]
__global__ __launch_bounds__(256)
void k_cvt_w(const float* __restrict__ W, unsigned short* __restrict__ th,
             unsigned short* __restrict__ tl, int K, int Nc){
  int i = blockIdx.x*blockDim.x + threadIdx.x;
  if (i >= K*Nc) return;
  int k = i / Nc, n = i - k*Nc;
  float a = W[i];
  unsigned short h = f2b(a);
  unsigned short l = f2b(a - b2f(h));
  th[(size_t)n*K + k] = h;
  tl[(size_t)n*K + k] = l;
}

// ---------------- split-bf16 MFMA GEMM: C[M,Nc] = A[M,K] @ W[K,Nc] ----------------
// A given as hi/lo bf16 [M,K]; W given as transposed hi/lo bf16 [Nc,K].
// 64x64 tile, 4 waves, each wave: 16-row strip x 64 cols, K-step 32.
__global__ __launch_bounds__(256)
void k_gemm_mfma(const unsigned short* __restrict__ Ah, const unsigned short* __restrict__ Al,
                 const unsigned short* __restrict__ Bh, const unsigned short* __restrict__ Bl,
                 float* __restrict__ Cc, int M, int K, int Nc){
  constexpr int LDP = 40;  // padded row stride (shorts): 80B -> <=2-way LDS banks
  __shared__ unsigned short sAh[64*LDP], sAl[64*LDP], sBh[64*LDP], sBl[64*LDP];
  const int tid = threadIdx.x;
  const int m0 = blockIdx.x*64, n0 = blockIdx.y*64;
  const int w = tid >> 6, l = tid & 63;
  const int sr = tid >> 2, sc = (tid & 3)*8;       // staging: row, col8
  f32x4 acc0 = {0.f,0.f,0.f,0.f}, acc1 = acc0, acc2 = acc0, acc3 = acc0;
  const int arow = m0 + sr;
  const bool aval = arow < M;
  const size_t aoff = (size_t)arow*K + sc;
  const size_t boff = (size_t)(n0 + sr)*K + sc;
  const int fa = (w*16 + (l & 15))*LDP + (l >> 4)*8;
  const int fb = (l & 15)*LDP + (l >> 4)*8;

  for (int k0 = 0; k0 < K; k0 += 32){
    uint4 z = make_uint4(0,0,0,0);
    uint4 va_h = z, va_l = z;
    if (aval){
      va_h = *(const uint4*)(Ah + aoff + k0);
      va_l = *(const uint4*)(Al + aoff + k0);
    }
    uint4 vb_h = *(const uint4*)(Bh + boff + k0);
    uint4 vb_l = *(const uint4*)(Bl + boff + k0);
    __syncthreads();               // previous iteration's frag reads done
    *(uint4*)&sAh[sr*LDP + sc] = va_h;
    *(uint4*)&sAl[sr*LDP + sc] = va_l;
    *(uint4*)&sBh[sr*LDP + sc] = vb_h;
    *(uint4*)&sBl[sr*LDP + sc] = vb_l;
    __syncthreads();

    short8v a_h = *(const short8v*)&sAh[fa];
    short8v a_l = *(const short8v*)&sAl[fa];

    short8v b_h, b_l;
    b_h = *(const short8v*)&sBh[fb];
    b_l = *(const short8v*)&sBl[fb];
    acc0 = __builtin_amdgcn_mfma_f32_16x16x32_bf16(a_h, b_h, acc0, 0, 0, 0);
    acc0 = __builtin_amdgcn_mfma_f32_16x16x32_bf16(a_h, b_l, acc0, 0, 0, 0);
    acc0 = __builtin_amdgcn_mfma_f32_16x16x32_bf16(a_l, b_h, acc0, 0, 0, 0);

    b_h = *(const short8v*)&sBh[fb + 16*LDP];
    b_l = *(const short8v*)&sBl[fb + 16*LDP];
    acc1 = __builtin_amdgcn_mfma_f32_16x16x32_bf16(a_h, b_h, acc1, 0, 0, 0);
    acc1 = __builtin_amdgcn_mfma_f32_16x16x32_bf16(a_h, b_l, acc1, 0, 0, 0);
    acc1 = __builtin_amdgcn_mfma_f32_16x16x32_bf16(a_l, b_h, acc1, 0, 0, 0);

    b_h = *(const short8v*)&sBh[fb + 32*LDP];
    b_l = *(const short8v*)&sBl[fb + 32*LDP];
    acc2 = __builtin_amdgcn_mfma_f32_16x16x32_bf16(a_h, b_h, acc2, 0, 0, 0);
    acc2 = __builtin_amdgcn_mfma_f32_16x16x32_bf16(a_h, b_l, acc2, 0, 0, 0);
    acc2 = __builtin_amdgcn_mfma_f32_16x16x32_bf16(a_l, b_h, acc2, 0, 0, 0);

    b_h = *(const short8v*)&sBh[fb + 48*LDP];
    b_l = *(const short8v*)&sBl[fb + 48*LDP];
    acc3 = __builtin_amdgcn_mfma_f32_16x16x32_bf16(a_h, b_h, acc3, 0, 0, 0);
    acc3 = __builtin_amdgcn_mfma_f32_16x16x32_bf16(a_h, b_l, acc3, 0, 0, 0);
    acc3 = __builtin_amdgcn_mfma_f32_16x16x32_bf16(a_l, b_h, acc3, 0, 0, 0);
    __syncthreads();
  }

  // C/D layout: col = lane&15, row = (lane>>4)*4 + j   [verified m89]
  const int rb = m0 + w*16 + (l >> 4)*4;
  const int cb = n0 + (l & 15);
  #pragma unroll
  for (int j = 0; j < 4; ++j){
    int row = rb + j;
    if (row < M){
      float* cp = Cc + (size_t)row*Nc + cb;
      cp[0]  = acc0[j];
      cp[16] = acc1[j];
      cp[32] = acc2[j];
      cp[48] = acc3[j];
    }
  }
}

// ---------------- per-node alpha_s / alpha_d ----------------
template<int HC, int C>
__global__ __launch_bounds__(256)
void k_alpha(const float* __restrict__ h, const float* __restrict__ asr,
             const float* __restrict__ adt, float* __restrict__ as4,
             float* __restrict__ ad4, int N){
  int wid  = (blockIdx.x*blockDim.x + threadIdx.x) >> 6;
  int lane = threadIdx.x & 63;
  if (wid >= N) return;
  const float* hr = h + (size_t)wid * HC;
  float ps0=0,ps1=0,ps2=0,ps3=0, pd0=0,pd1=0,pd2=0,pd3=0;
  #pragma unroll
  for (int q = 0; q < HC/64; ++q){
    int comp = lane + 64*q;
    float v = hr[comp];
    float s = v * asr[comp];
    float d = v * adt[comp];
    const int hh = (64*q) / C;
    if (hh == 0){ ps0 += s; pd0 += d; }
    else if (hh == 1){ ps1 += s; pd1 += d; }
    else if (hh == 2){ ps2 += s; pd2 += d; }
    else { ps3 += s; pd3 += d; }
  }
  #pragma unroll
  for (int off = 32; off > 0; off >>= 1){
    ps0 += __shfl_xor(ps0, off, WAVE); pd0 += __shfl_xor(pd0, off, WAVE);
    ps1 += __shfl_xor(ps1, off, WAVE); pd1 += __shfl_xor(pd1, off, WAVE);
    ps2 += __shfl_xor(ps2, off, WAVE); pd2 += __shfl_xor(pd2, off, WAVE);
    ps3 += __shfl_xor(ps3, off, WAVE); pd3 += __shfl_xor(pd3, off, WAVE);
  }
  if (lane == 0){
    *(float4*)(as4 + (size_t)wid*4) = make_float4(ps0,ps1,ps2,ps3);
    *(float4*)(ad4 + (size_t)wid*4) = make_float4(pd0,pd1,pd2,pd3);
  }
}

// ---------------- GAT aggregation: one wave per destination node ----------------
// All-scalar state (NO per-thread arrays -> avoid promote-alloca to LDS).
template<int HC, int C>
__global__ __launch_bounds__(256)
void k_agg(const int* __restrict__ rp, const int* __restrict__ es,
           const float* __restrict__ as4, const float* __restrict__ ad4,
           const float* __restrict__ h, const float* __restrict__ bias,
           float* __restrict__ out, int N){
  constexpr int KQ = HC / 256;
  int wid  = (blockIdx.x*blockDim.x + threadIdx.x) >> 6;
  int lane = threadIdx.x & 63;
  if (wid >= N) return;
  int beg = rp[wid], end = rp[wid+1];

  const float4 adv = *(const float4*)(ad4 + (size_t)wid*4);
  const float ad0 = adv.x, ad1 = adv.y, ad2 = adv.z, ad3 = adv.w;

  // phase A: online softmax stats per head (scalars)
  float m0=-1e30f, m1=-1e30f, m2=-1e30f, m3=-1e30f;
  float s0=0.f, s1=0.f, s2=0.f, s3=0.f;
  for (int i = beg + lane; i < end; i += WAVE){
    int s = es[i];
    const float4 av = *(const float4*)(as4 + (size_t)s*4);
    float e, mn;
    e = av.x + ad0; e = (e >= 0.f) ? e : 0.2f*e;
    mn = fmaxf(m0, e); s0 = s0*__expf(m0-mn) + __expf(e-mn); m0 = mn;
    e = av.y + ad1; e = (e >= 0.f) ? e : 0.2f*e;
    mn = fmaxf(m1, e); s1 = s1*__expf(m1-mn) + __expf(e-mn); m1 = mn;
    e = av.z + ad2; e = (e >= 0.f) ? e : 0.2f*e;
    mn = fmaxf(m2, e); s2 = s2*__expf(m2-mn) + __expf(e-mn); m2 = mn;
    e = av.w + ad3; e = (e >= 0.f) ? e : 0.2f*e;
    mn = fmaxf(m3, e); s3 = s3*__expf(m3-mn) + __expf(e-mn); m3 = mn;
  }
  #pragma unroll
  for (int off = 32; off > 0; off >>= 1){
    float mo, so, mn;
    mo = __shfl_xor(m0, off, WAVE); so = __shfl_xor(s0, off, WAVE);
    mn = fmaxf(m0, mo); s0 = s0*__expf(m0-mn) + so*__expf(mo-mn); m0 = mn;
    mo = __shfl_xor(m1, off, WAVE); so = __shfl_xor(s1, off, WAVE);
    mn = fmaxf(m1, mo); s1 = s1*__expf(m1-mn) + so*__expf(mo-mn); m1 = mn;
    mo = __shfl_xor(m2, off, WAVE); so = __shfl_xor(s2, off, WAVE);
    mn = fmaxf(m2, mo); s2 = s2*__expf(m2-mn) + so*__expf(mo-mn); m2 = mn;
    mo = __shfl_xor(m3, off, WAVE); so = __shfl_xor(s3, off, WAVE);
    mn = fmaxf(m3, mo); s3 = s3*__expf(m3-mn) + so*__expf(mo-mn); m3 = mn;
  }
  const float i0 = 1.f/(s0 + 1e-16f), i1 = 1.f/(s1 + 1e-16f);
  const float i2 = 1.f/(s2 + 1e-16f), i3 = 1.f/(s3 + 1e-16f);

  // head index per accumulator quad (compile-time pattern)
  const int myh0 = (KQ == 1) ? (lane >> 4) : (lane >> 5);        // C=64: 0..3 ; C=128: 0..1

  float4 acc0 = make_float4(0,0,0,0), acc1 = make_float4(0,0,0,0);

  for (int cb = beg; cb < end; cb += WAVE){
    int nn = min(WAVE, end - cb);
    int sidx = 0;
    float w0 = 0.f, w1 = 0.f, w2 = 0.f, w3 = 0.f;
    if (cb + lane < end){
      sidx = es[cb + lane];
      const float4 av = *(const float4*)(as4 + (size_t)sidx*4);
      float e;
      e = av.x + ad0; e = (e >= 0.f) ? e : 0.2f*e; w0 = __expf(e - m0)*i0;
      e = av.y + ad1; e = (e >= 0.f) ? e : 0.2f*e; w1 = __expf(e - m1)*i1;
      e = av.z + ad2; e = (e >= 0.f) ? e : 0.2f*e; w2 = __expf(e - m2)*i2;
      e = av.w + ad3; e = (e >= 0.f) ? e : 0.2f*e; w3 = __expf(e - m3)*i3;
    }

    int j = 0;
    for (; j + 4 <= nn; j += 4){
      int sj0 = __shfl(sidx, j+0, WAVE), sj1 = __shfl(sidx, j+1, WAVE);
      int sj2 = __shfl(sidx, j+2, WAVE), sj3 = __shfl(sidx, j+3, WAVE);
      float uA0, uA1, uA2, uA3, uB0, uB1, uB2, uB3;
      {
        float e0 = __shfl(w0, j+0, WAVE), e1 = __shfl(w1, j+0, WAVE);
        float e2 = __shfl(w2, j+0, WAVE), e3 = __shfl(w3, j+0, WAVE);
        if (KQ == 1){ uA0 = (myh0==0)?e0:(myh0==1)?e1:(myh0==2)?e2:e3; uB0 = 0.f; }
        else        { uA0 = myh0 ? e1 : e0; uB0 = myh0 ? e3 : e2; }
      }
      {
        float e0 = __shfl(w0, j+1, WAVE), e1 = __shfl(w1, j+1, WAVE);
        float e2 = __shfl(w2, j+1, WAVE), e3 = __shfl(w3, j+1, WAVE);
        if (KQ == 1){ uA1 = (myh0==0)?e0:(myh0==1)?e1:(myh0==2)?e2:e3; uB1 = 0.f; }
        else        { uA1 = myh0 ? e1 : e0; uB1 = myh0 ? e3 : e2; }
      }
      {
        float e0 = __shfl(w0, j+2, WAVE), e1 = __shfl(w1, j+2, WAVE);
        float e2 = __shfl(w2, j+2, WAVE), e3 = __shfl(w3, j+2, WAVE);
        if (KQ == 1){ uA2 = (myh0==0)?e0:(myh0==1)?e1:(myh0==2)?e2:e3; uB2 = 0.f; }
        else        { uA2 = myh0 ? e1 : e0; uB2 = myh0 ? e3 : e2; }
      }
      {
        float e0 = __shfl(w0, j+3, WAVE), e1 = __shfl(w1, j+3, WAVE);
        float e2 = __shfl(w2, j+3, WAVE), e3 = __shfl(w3, j+3, WAVE);
        if (KQ == 1){ uA3 = (myh0==0)?e0:(myh0==1)?e1:(myh0==2)?e2:e3; uB3 = 0.f; }
        else        { uA3 = myh0 ? e1 : e0; uB3 = myh0 ? e3 : e2; }
      }
      const float4* r0 = (const float4*)(h + (size_t)sj0*HC);
      const float4* r1 = (const float4*)(h + (size_t)sj1*HC);
      const float4* r2 = (const float4*)(h + (size_t)sj2*HC);
      const float4* r3 = (const float4*)(h + (size_t)sj3*HC);
      float4 v0 = r0[lane], v1 = r1[lane], v2 = r2[lane], v3 = r3[lane];
      acc0.x = fmaf(uA0, v0.x, fmaf(uA1, v1.x, fmaf(uA2, v2.x, fmaf(uA3, v3.x, acc0.x))));
      acc0.y = fmaf(uA0, v0.y, fmaf(uA1, v1.y, fmaf(uA2, v2.y, fmaf(uA3, v3.y, acc0.y))));
      acc0.z = fmaf(uA0, v0.z, fmaf(uA1, v1.z, fmaf(uA2, v2.z, fmaf(uA3, v3.z, acc0.z))));
      acc0.w = fmaf(uA0, v0.w, fmaf(uA1, v1.w, fmaf(uA2, v2.w, fmaf(uA3, v3.w, acc0.w))));
      if (KQ == 2){
        float4 u0 = r0[lane+64], u1 = r1[lane+64], u2 = r2[lane+64], u3 = r3[lane+64];
        acc1.x = fmaf(uB0, u0.x, fmaf(uB1, u1.x, fmaf(uB2, u2.x, fmaf(uB3, u3.x, acc1.x))));
        acc1.y = fmaf(uB0, u0.y, fmaf(uB1, u1.y, fmaf(uB2, u2.y, fmaf(uB3, u3.y, acc1.y))));
        acc1.z = fmaf(uB0, u0.z, fmaf(uB1, u1.z, fmaf(uB2, u2.z, fmaf(uB3, u3.z, acc1.z))));
        acc1.w = fmaf(uB0, u0.w, fmaf(uB1, u1.w, fmaf(uB2, u2.w, fmaf(uB3, u3.w, acc1.w))));
      }
    }
    for (; j < nn; ++j){
      int sj = __shfl(sidx, j, WAVE);
      float e0 = __shfl(w0, j, WAVE), e1 = __shfl(w1, j, WAVE);
      float e2 = __shfl(w2, j, WAVE), e3 = __shfl(w3, j, WAVE);
      float uA, uB = 0.f;
      if (KQ == 1){ uA = (myh0==0)?e0:(myh0==1)?e1:(myh0==2)?e2:e3; }
      else        { uA = myh0 ? e1 : e0; uB = myh0 ? e3 : e2; }
      const float4* hr = (const float4*)(h + (size_t)sj*HC);
      float4 v = hr[lane];
      acc0.x = fmaf(uA, v.x, acc0.x); acc0.y = fmaf(uA, v.y, acc0.y);
      acc0.z = fmaf(uA, v.z, acc0.z); acc0.w = fmaf(uA, v.w, acc0.w);
      if (KQ == 2){
        float4 u = hr[lane+64];
        acc1.x = fmaf(uB, u.x, acc1.x); acc1.y = fmaf(uB, u.y, acc1.y);
        acc1.z = fmaf(uB, u.z, acc1.z); acc1.w = fmaf(uB, u.w, acc1.w);
      }
    }
  }

  const float4* bp = (const float4*)bias;
  float4* op = (float4*)(out + (size_t)wid*HC);
  {
    float4 bv = bp[lane];
    float4 r;
    r.x = acc0.x + bv.x; r.y = acc0.y + bv.y;
    r.z = acc0.z + bv.z; r.w = acc0.w + bv.w;
    r.x = r.x > 0.f ? r.x : expm1f(r.x);
    r.y = r.y > 0.f ? r.y : expm1f(r.y);
    r.z = r.z > 0.f ? r.z : expm1f(r.z);
    r.w = r.w > 0.f ? r.w : expm1f(r.w);
    op[lane] = r;
  }
  if (KQ == 2){
    float4 bv = bp[lane+64];
    float4 r;
    r.x = acc1.x + bv.x; r.y = acc1.y + bv.y;
    r.z = acc1.z + bv.z; r.w = acc1.w + bv.w;
    r.x = r.x > 0.f ? r.x : expm1f(r.x);
    r.y = r.y > 0.f ? r.y : expm1f(r.y);
    r.z = r.z > 0.f ? r.z : expm1f(r.z);
    r.w = r.w > 0.f ? r.w : expm1f(r.w);
    op[lane+64] = r;
  }
}

// ---------------- pooling + FC ----------------
__global__ void k_pool_partial(const float* __restrict__ h, const int* __restrict__ bs,
                               float* __restrict__ psum, float* __restrict__ pmax){
  int b = blockIdx.x, ch = blockIdx.y;
  int f = threadIdx.x;
  int s = bs[b], e = bs[b+1];
  long long len = e - s;
  int i0 = s + (int)(len * ch / 8);
  int i1 = s + (int)(len * (ch+1) / 8);
  float sm = 0.f, mx = -3.0e38f;
  for (int i = i0; i < i1; ++i){
    float v = h[(size_t)i*512 + f];
    sm += v; mx = fmaxf(mx, v);
  }
  int idx = (b*8 + ch)*512 + f;
  psum[idx] = sm; pmax[idx] = mx;
}

__global__ void k_pool_final(const float* __restrict__ psum, const float* __restrict__ pmax,
                             const int* __restrict__ bs, float* __restrict__ g){
  int b = blockIdx.x, f = threadIdx.x;
  float sm = 0.f, mx = -3.0e38f;
  for (int c = 0; c < 8; ++c){
    int idx = (b*8 + c)*512 + f;
    sm += psum[idx]; mx = fmaxf(mx, pmax[idx]);
  }
  int cnt = bs[b+1] - bs[b];
  g[b*1024 + f] = sm / fmaxf((float)cnt, 1.f);
  g[b*1024 + 512 + f] = (mx > -1e37f) ? mx : 0.f;
}

__global__ __launch_bounds__(256)
void k_fc(const float* __restrict__ g, const float* __restrict__ fcW,
          const float* __restrict__ fcb, float* __restrict__ out){
  __shared__ float gs[1024];
  __shared__ float red[4][64];
  int b = blockIdx.x, t = threadIdx.x;
  int o0 = blockIdx.y * 64;
  for (int i = t; i < 1024; i += 256) gs[i] = g[b*1024 + i];
  __syncthreads();
  int ol = t & 63, q = t >> 6;
  const float* wp = fcW + (size_t)(q*256)*512 + o0 + ol;
  float acc = 0.f;
  #pragma unroll 8
  for (int k = 0; k < 256; ++k)
    acc = fmaf(gs[q*256 + k], wp[(size_t)k*512], acc);
  red[q][ol] = acc;
  __syncthreads();
  if (t < 64){
    float r = red[0][t] + red[1][t] + red[2][t] + red[3][t] + fcb[o0 + t];
    out[b*512 + o0 + t] = r;
  }
}

// ---------------- launcher ----------------
extern "C" void kernel_launch(void* const* d_in, const int* in_sizes, int n_in,
                              void* d_out, int out_size, void* d_ws, size_t ws_size,
                              hipStream_t stream){
  (void)n_in; (void)out_size; (void)ws_size;
  const float* x     = (const float*)d_in[0];
  const int*   ei    = (const int*)d_in[1];
  const int*   batch = (const int*)d_in[2];
  const float* W[4]   = {(const float*)d_in[3],(const float*)d_in[7],(const float*)d_in[11],(const float*)d_in[15]};
  const float* asr[4] = {(const float*)d_in[4],(const float*)d_in[8],(const float*)d_in[12],(const float*)d_in[16]};
  const float* adt[4] = {(const float*)d_in[5],(const float*)d_in[9],(const float*)d_in[13],(const float*)d_in[17]};
  const float* bb[4]  = {(const float*)d_in[6],(const float*)d_in[10],(const float*)d_in[14],(const float*)d_in[18]};
  const float* fcW = (const float*)d_in[19];
  const float* fcb = (const float*)d_in[20];

  const int N  = in_sizes[0] / 128;
  const int E  = in_sizes[1] / 2;
  const int EN = E + N;
  const int B  = 32;
  const int NB = (N + 1023) / 1024;

  char* p = (char*)d_ws;
  auto alloc = [&](size_t bytes){ void* r = (void*)p; p += (bytes + 255) & ~(size_t)255; return r; };
  float* bufA = (float*)alloc((size_t)N*512*4);
  float* bufB = (float*)alloc((size_t)N*512*4);
  unsigned short* Ah = (unsigned short*)alloc((size_t)N*256*2);
  unsigned short* Al = (unsigned short*)alloc((size_t)N*256*2);
  unsigned short* Wh = (unsigned short*)alloc((size_t)512*256*2);
  unsigned short* Wl = (unsigned short*)alloc((size_t)512*256*2);
  float* as4  = (float*)alloc((size_t)N*4*4);
  float* ad4  = (float*)alloc((size_t)N*4*4);
  int*   cnt  = (int*)alloc((size_t)N*4);
  int*   rp   = (int*)alloc((size_t)(N+1)*4);
  int*   cur  = (int*)alloc((size_t)N*4);
  int*   es   = (int*)alloc((size_t)EN*4);
  int*   bs   = (int*)alloc((size_t)(B+1)*4);
  int*   bsum = (int*)alloc((size_t)64*4);
  float* gpo  = (float*)alloc((size_t)B*1024*4);
  float* psum = (float*)alloc((size_t)B*8*512*4);
  float* pmax = (float*)alloc((size_t)B*8*512*4);

  // CSR build
  k_zero_i<<<(N+255)/256, 256, 0, stream>>>(cnt, N);
  k_count<<<(EN+255)/256, 256, 0, stream>>>(ei, E, N, cnt);
  k_scan1<<<NB, 1024, 0, stream>>>(cnt, rp, bsum, N);
  k_scan2<<<1, 64, 0, stream>>>(bsum, NB, rp, N);
  k_scan3<<<NB, 1024, 0, stream>>>(rp, bsum, N);
  k_copy_i<<<(N+255)/256, 256, 0, stream>>>(rp, cur, N);
  k_fill<<<(EN+255)/256, 256, 0, stream>>>(ei, E, N, cur, es);
  k_bounds<<<1, 64, 0, stream>>>(batch, N, B, bs);

  const int Kd[4]  = {128, 256, 256, 256};
  const int HCd[4] = {256, 256, 256, 512};
  const float* in_ptr = x;
  const int wgrid = (N + 3) / 4;

  for (int L = 0; L < 4; ++L){
    const int K = Kd[L], Nc = HCd[L];
    k_cvt_w<<<(K*Nc + 255)/256, 256, 0, stream>>>(W[L], Wh, Wl, K, Nc);
    k_cvt<<<((N*K/4) + 255)/256, 256, 0, stream>>>(in_ptr, Ah, Al, N*K/4);
    dim3 gg((N + 63)/64, Nc/64);
    k_gemm_mfma<<<gg, 256, 0, stream>>>(Ah, Al, Wh, Wl, bufB, N, K, Nc);
    if (Nc == 256){
      k_alpha<256,64><<<wgrid, 256, 0, stream>>>(bufB, asr[L], adt[L], as4, ad4, N);
      k_agg<256,64><<<wgrid, 256, 0, stream>>>(rp, es, as4, ad4, bufB, bb[L], bufA, N);
    } else {
      k_alpha<512,128><<<wgrid, 256, 0, stream>>>(bufB, asr[L], adt[L], as4, ad4, N);
      k_agg<512,128><<<wgrid, 256, 0, stream>>>(rp, es, as4, ad4, bufB, bb[L], bufA, N);
    }
    in_ptr = bufA;
  }

  dim3 pg(B, 8);
  k_pool_partial<<<pg, 512, 0, stream>>>(bufA, bs, psum, pmax);
  k_pool_final<<<B, 512, 0, stream>>>(psum, pmax, bs, gpo);
  dim3 fg(B, 8);
  k_fc<<<fg, 256, 0, stream>>>(gpo, fcW, fcb, (float*)d_out);
}

// Round 4
// 571.013 us; speedup vs baseline: 1.6728x; 1.2909x over previous
//
#include <hip/hip_runtime.h>
#include <math.h>

#define WAVE 64

typedef __attribute__((ext_vector_type(8))) short short8v;
typedef __attribute__((ext_vector_type(4))) float f32x4;
typedef _Float16 h16x4 __attribute__((ext_vector_type(4)));
typedef _Float16 h16x8 __attribute__((ext_vector_type(8)));

__device__ __forceinline__ unsigned short f2b(float x){
  unsigned u = __float_as_uint(x);
  unsigned r = u + 0x7fffu + ((u >> 16) & 1u);
  return (unsigned short)(r >> 16);
}
__device__ __forceinline__ float b2f(unsigned short h){
  return __uint_as_float(((unsigned)h) << 16);
}
// scalar 4-way select by runtime index (cndmask chain; NO arrays -> no promote-alloca)
__device__ __forceinline__ float selh(float e0, float e1, float e2, float e3, int m){
  float r = (m == 1) ? e1 : e0;
  r = (m == 2) ? e2 : r;
  r = (m == 3) ? e3 : r;
  return r;
}

// ---------------- CSR build ----------------
__global__ void k_zero_i(int* p, int n){
  int i = blockIdx.x*blockDim.x + threadIdx.x;
  if (i < n) p[i] = 0;
}

__global__ void k_count(const int* __restrict__ ei, int E, int N, int* __restrict__ cnt){
  int i = blockIdx.x*blockDim.x + threadIdx.x;
  if (i >= E + N) return;
  int d = (i < E) ? ei[E + i] : (i - E);
  atomicAdd(&cnt[d], 1);
}

__global__ __launch_bounds__(1024)
void k_scan1(const int* __restrict__ cnt, int* __restrict__ rp, int* __restrict__ bsum, int N){
  __shared__ int sd[1024];
  int t = threadIdx.x, i = blockIdx.x*1024 + t;
  int v = (i < N) ? cnt[i] : 0;
  sd[t] = v;
  __syncthreads();
  for (int off = 1; off < 1024; off <<= 1){
    int x = (t >= off) ? sd[t-off] : 0;
    __syncthreads();
    sd[t] += x;
    __syncthreads();
  }
  if (i < N) rp[i] = sd[t] - v;
  if (t == 1023) bsum[blockIdx.x] = sd[1023];
}

__global__ void k_scan2(int* __restrict__ bsum, int nb, int* __restrict__ rp, int N){
  int t = threadIdx.x;
  int orig = (t < nb) ? bsum[t] : 0;
  int v = orig;
  #pragma unroll
  for (int off = 1; off < 64; off <<= 1){
    int x = __shfl_up(v, off, WAVE);
    if (t >= off) v += x;
  }
  if (t < nb) bsum[t] = v - orig;
  if (t == 63) rp[N] = v;
}

__global__ __launch_bounds__(1024)
void k_scan3(int* __restrict__ rp, const int* __restrict__ bsum, int N){
  int i = blockIdx.x*1024 + threadIdx.x;
  if (i < N) rp[i] += bsum[blockIdx.x];
}

__global__ void k_copy_i(const int* __restrict__ a, int* __restrict__ b, int n){
  int i = blockIdx.x*blockDim.x + threadIdx.x;
  if (i < n) b[i] = a[i];
}

__global__ void k_fill(const int* __restrict__ ei, int E, int N,
                       int* __restrict__ cur, int* __restrict__ es){
  int i = blockIdx.x*blockDim.x + threadIdx.x;
  if (i >= E + N) return;
  int s, d;
  if (i < E){ s = ei[i]; d = ei[E + i]; } else { s = d = i - E; }
  int pos = atomicAdd(&cur[d], 1);
  es[pos] = s;
}

__global__ void k_bounds(const int* __restrict__ batch, int N, int B, int* __restrict__ bs){
  int b = blockIdx.x*blockDim.x + threadIdx.x;
  if (b > B) return;
  int lo = 0, hi = N;
  while (lo < hi){ int mid = (lo + hi) >> 1; if (batch[mid] < b) lo = mid + 1; else hi = mid; }
  bs[b] = lo;
}

// ---------------- f32 -> bf16 hi/lo conversion (layer-1 input only) ----------------
__global__ __launch_bounds__(256)
void k_cvt(const float* __restrict__ in, unsigned short* __restrict__ hi,
           unsigned short* __restrict__ lo, int n4){
  int i = blockIdx.x*blockDim.x + threadIdx.x;
  if (i >= n4) return;
  float4 v = ((const float4*)in)[i];
  ushort4 h, l;
  h.x = f2b(v.x); l.x = f2b(v.x - b2f(h.x));
  h.y = f2b(v.y); l.y = f2b(v.y - b2f(h.y));
  h.z = f2b(v.z); l.z = f2b(v.z - b2f(h.z));
  h.w = f2b(v.w); l.w = f2b(v.w - b2f(h.w));
  ((ushort4*)hi)[i] = h;
  ((ushort4*)lo)[i] = l;
}

// W[K,Nc] -> W^T hi/lo [Nc,K]
__global__ __launch_bounds__(256)
void k_cvt_w(const float* __restrict__ W, unsigned short* __restrict__ th,
             unsigned short* __restrict__ tl, int K, int Nc){
  int i = blockIdx.x*blockDim.x + threadIdx.x;
  if (i >= K*Nc) return;
  int k = i / Nc, n = i - k*Nc;
  float a = W[i];
  unsigned short h = f2b(a);
  unsigned short l = f2b(a - b2f(h));
  th[(size_t)n*K + k] = h;
  tl[(size_t)n*K + k] = l;
}

// ---------------- split-bf16 MFMA GEMM ----------------
// C[M,Nc] = A[M,K] @ W[K,Nc]; A hi/lo bf16 [M,K]; W^T hi/lo bf16 [Nc,K].
// Writes f32 C and (optional) fp16 copy Ch.
__global__ __launch_bounds__(256)
void k_gemm_mfma(const unsigned short* __restrict__ Ah, const unsigned short* __restrict__ Al,
                 const unsigned short* __restrict__ Bh, const unsigned short* __restrict__ Bl,
                 float* __restrict__ Cc, _Float16* __restrict__ Ch,
                 int M, int K, int Nc){
  constexpr int LDP = 40;
  __shared__ unsigned short sAh[64*LDP], sAl[64*LDP], sBh[64*LDP], sBl[64*LDP];
  const int tid = threadIdx.x;
  const int m0 = blockIdx.x*64, n0 = blockIdx.y*64;
  const int w = tid >> 6, l = tid & 63;
  const int sr = tid >> 2, sc = (tid & 3)*8;
  f32x4 acc0 = {0.f,0.f,0.f,0.f}, acc1 = acc0, acc2 = acc0, acc3 = acc0;
  const int arow = m0 + sr;
  const bool aval = arow < M;
  const size_t aoff = (size_t)arow*K + sc;
  const size_t boff = (size_t)(n0 + sr)*K + sc;
  const int fa = (w*16 + (l & 15))*LDP + (l >> 4)*8;
  const int fb = (l & 15)*LDP + (l >> 4)*8;

  for (int k0 = 0; k0 < K; k0 += 32){
    uint4 z = make_uint4(0,0,0,0);
    uint4 va_h = z, va_l = z;
    if (aval){
      va_h = *(const uint4*)(Ah + aoff + k0);
      va_l = *(const uint4*)(Al + aoff + k0);
    }
    uint4 vb_h = *(const uint4*)(Bh + boff + k0);
    uint4 vb_l = *(const uint4*)(Bl + boff + k0);
    __syncthreads();
    *(uint4*)&sAh[sr*LDP + sc] = va_h;
    *(uint4*)&sAl[sr*LDP + sc] = va_l;
    *(uint4*)&sBh[sr*LDP + sc] = vb_h;
    *(uint4*)&sBl[sr*LDP + sc] = vb_l;
    __syncthreads();

    short8v a_h = *(const short8v*)&sAh[fa];
    short8v a_l = *(const short8v*)&sAl[fa];

    short8v b_h, b_l;
    b_h = *(const short8v*)&sBh[fb];
    b_l = *(const short8v*)&sBl[fb];
    acc0 = __builtin_amdgcn_mfma_f32_16x16x32_bf16(a_h, b_h, acc0, 0, 0, 0);
    acc0 = __builtin_amdgcn_mfma_f32_16x16x32_bf16(a_h, b_l, acc0, 0, 0, 0);
    acc0 = __builtin_amdgcn_mfma_f32_16x16x32_bf16(a_l, b_h, acc0, 0, 0, 0);

    b_h = *(const short8v*)&sBh[fb + 16*LDP];
    b_l = *(const short8v*)&sBl[fb + 16*LDP];
    acc1 = __builtin_amdgcn_mfma_f32_16x16x32_bf16(a_h, b_h, acc1, 0, 0, 0);
    acc1 = __builtin_amdgcn_mfma_f32_16x16x32_bf16(a_h, b_l, acc1, 0, 0, 0);
    acc1 = __builtin_amdgcn_mfma_f32_16x16x32_bf16(a_l, b_h, acc1, 0, 0, 0);

    b_h = *(const short8v*)&sBh[fb + 32*LDP];
    b_l = *(const short8v*)&sBl[fb + 32*LDP];
    acc2 = __builtin_amdgcn_mfma_f32_16x16x32_bf16(a_h, b_h, acc2, 0, 0, 0);
    acc2 = __builtin_amdgcn_mfma_f32_16x16x32_bf16(a_h, b_l, acc2, 0, 0, 0);
    acc2 = __builtin_amdgcn_mfma_f32_16x16x32_bf16(a_l, b_h, acc2, 0, 0, 0);

    b_h = *(const short8v*)&sBh[fb + 48*LDP];
    b_l = *(const short8v*)&sBl[fb + 48*LDP];
    acc3 = __builtin_amdgcn_mfma_f32_16x16x32_bf16(a_h, b_h, acc3, 0, 0, 0);
    acc3 = __builtin_amdgcn_mfma_f32_16x16x32_bf16(a_h, b_l, acc3, 0, 0, 0);
    acc3 = __builtin_amdgcn_mfma_f32_16x16x32_bf16(a_l, b_h, acc3, 0, 0, 0);
    __syncthreads();
  }

  const int rb = m0 + w*16 + (l >> 4)*4;
  const int cb = n0 + (l & 15);
  #pragma unroll
  for (int j = 0; j < 4; ++j){
    int row = rb + j;
    if (row < M){
      float* cp = Cc + (size_t)row*Nc + cb;
      cp[0]  = acc0[j];
      cp[16] = acc1[j];
      cp[32] = acc2[j];
      cp[48] = acc3[j];
      if (Ch){
        _Float16* hp = Ch + (size_t)row*Nc + cb;
        hp[0]  = (_Float16)acc0[j];
        hp[16] = (_Float16)acc1[j];
        hp[32] = (_Float16)acc2[j];
        hp[48] = (_Float16)acc3[j];
      }
    }
  }
}

// ---------------- per-node alpha_s / alpha_d (reads f32 h) ----------------
template<int HC, int C>
__global__ __launch_bounds__(256)
void k_alpha(const float* __restrict__ h, const float* __restrict__ asr,
             const float* __restrict__ adt, float* __restrict__ as4,
             float* __restrict__ ad4, int N){
  int wid  = (blockIdx.x*blockDim.x + threadIdx.x) >> 6;
  int lane = threadIdx.x & 63;
  if (wid >= N) return;
  const float* hr = h + (size_t)wid * HC;
  float ps0=0,ps1=0,ps2=0,ps3=0, pd0=0,pd1=0,pd2=0,pd3=0;
  #pragma unroll
  for (int q = 0; q < HC/64; ++q){
    int comp = lane + 64*q;
    float v = hr[comp];
    float s = v * asr[comp];
    float d = v * adt[comp];
    const int hh = (64*q) / C;
    if (hh == 0){ ps0 += s; pd0 += d; }
    else if (hh == 1){ ps1 += s; pd1 += d; }
    else if (hh == 2){ ps2 += s; pd2 += d; }
    else { ps3 += s; pd3 += d; }
  }
  #pragma unroll
  for (int off = 32; off > 0; off >>= 1){
    ps0 += __shfl_xor(ps0, off, WAVE); pd0 += __shfl_xor(pd0, off, WAVE);
    ps1 += __shfl_xor(ps1, off, WAVE); pd1 += __shfl_xor(pd1, off, WAVE);
    ps2 += __shfl_xor(ps2, off, WAVE); pd2 += __shfl_xor(pd2, off, WAVE);
    ps3 += __shfl_xor(ps3, off, WAVE); pd3 += __shfl_xor(pd3, off, WAVE);
  }
  if (lane == 0){
    *(float4*)(as4 + (size_t)wid*4) = make_float4(ps0,ps1,ps2,ps3);
    *(float4*)(ad4 + (size_t)wid*4) = make_float4(pd0,pd1,pd2,pd3);
  }
}

// ---------------- f32-gather agg (layer 1 only, HC=256) ----------------
// Output: bf16 hi/lo split of elu(out) directly (feeds next GEMM).
__global__ __launch_bounds__(256)
void k_agg_f32(const int* __restrict__ rp, const int* __restrict__ es,
               const float* __restrict__ as4, const float* __restrict__ ad4,
               const float* __restrict__ h, const float* __restrict__ bias,
               unsigned short* __restrict__ oAh, unsigned short* __restrict__ oAl, int N){
  constexpr int HC = 256;
  int wid  = (blockIdx.x*blockDim.x + threadIdx.x) >> 6;
  int lane = threadIdx.x & 63;
  if (wid >= N) return;
  int beg = rp[wid], end = rp[wid+1];

  const float4 adv = *(const float4*)(ad4 + (size_t)wid*4);
  const float ad0 = adv.x, ad1 = adv.y, ad2 = adv.z, ad3 = adv.w;

  float m0=-1e30f, m1=-1e30f, m2=-1e30f, m3=-1e30f;
  float s0=0.f, s1=0.f, s2=0.f, s3=0.f;
  for (int i = beg + lane; i < end; i += WAVE){
    int s = es[i];
    const float4 av = *(const float4*)(as4 + (size_t)s*4);
    float e, mn;
    e = av.x + ad0; e = (e >= 0.f) ? e : 0.2f*e;
    mn = fmaxf(m0, e); s0 = s0*__expf(m0-mn) + __expf(e-mn); m0 = mn;
    e = av.y + ad1; e = (e >= 0.f) ? e : 0.2f*e;
    mn = fmaxf(m1, e); s1 = s1*__expf(m1-mn) + __expf(e-mn); m1 = mn;
    e = av.z + ad2; e = (e >= 0.f) ? e : 0.2f*e;
    mn = fmaxf(m2, e); s2 = s2*__expf(m2-mn) + __expf(e-mn); m2 = mn;
    e = av.w + ad3; e = (e >= 0.f) ? e : 0.2f*e;
    mn = fmaxf(m3, e); s3 = s3*__expf(m3-mn) + __expf(e-mn); m3 = mn;
  }
  #pragma unroll
  for (int off = 32; off > 0; off >>= 1){
    float mo, so, mn;
    mo = __shfl_xor(m0, off, WAVE); so = __shfl_xor(s0, off, WAVE);
    mn = fmaxf(m0, mo); s0 = s0*__expf(m0-mn) + so*__expf(mo-mn); m0 = mn;
    mo = __shfl_xor(m1, off, WAVE); so = __shfl_xor(s1, off, WAVE);
    mn = fmaxf(m1, mo); s1 = s1*__expf(m1-mn) + so*__expf(mo-mn); m1 = mn;
    mo = __shfl_xor(m2, off, WAVE); so = __shfl_xor(s2, off, WAVE);
    mn = fmaxf(m2, mo); s2 = s2*__expf(m2-mn) + so*__expf(mo-mn); m2 = mn;
    mo = __shfl_xor(m3, off, WAVE); so = __shfl_xor(s3, off, WAVE);
    mn = fmaxf(m3, mo); s3 = s3*__expf(m3-mn) + so*__expf(mo-mn); m3 = mn;
  }
  const float i0 = 1.f/(s0 + 1e-16f), i1 = 1.f/(s1 + 1e-16f);
  const float i2 = 1.f/(s2 + 1e-16f), i3 = 1.f/(s3 + 1e-16f);
  const int myh = lane >> 4;                 // col = lane*4+c, head = col/64

  float4 acc0 = make_float4(0,0,0,0);

  for (int cb = beg; cb < end; cb += WAVE){
    int nn = min(WAVE, end - cb);
    int sidx = 0;
    float w0 = 0.f, w1 = 0.f, w2 = 0.f, w3 = 0.f;
    if (cb + lane < end){
      sidx = es[cb + lane];
      const float4 av = *(const float4*)(as4 + (size_t)sidx*4);
      float e;
      e = av.x + ad0; e = (e >= 0.f) ? e : 0.2f*e; w0 = __expf(e - m0)*i0;
      e = av.y + ad1; e = (e >= 0.f) ? e : 0.2f*e; w1 = __expf(e - m1)*i1;
      e = av.z + ad2; e = (e >= 0.f) ? e : 0.2f*e; w2 = __expf(e - m2)*i2;
      e = av.w + ad3; e = (e >= 0.f) ? e : 0.2f*e; w3 = __expf(e - m3)*i3;
    }

    int j = 0;
    for (; j + 4 <= nn; j += 4){
      int sj0 = __shfl(sidx, j+0, WAVE), sj1 = __shfl(sidx, j+1, WAVE);
      int sj2 = __shfl(sidx, j+2, WAVE), sj3 = __shfl(sidx, j+3, WAVE);
      float u0 = selh(__shfl(w0,j+0,WAVE), __shfl(w1,j+0,WAVE), __shfl(w2,j+0,WAVE), __shfl(w3,j+0,WAVE), myh);
      float u1 = selh(__shfl(w0,j+1,WAVE), __shfl(w1,j+1,WAVE), __shfl(w2,j+1,WAVE), __shfl(w3,j+1,WAVE), myh);
      float u2 = selh(__shfl(w0,j+2,WAVE), __shfl(w1,j+2,WAVE), __shfl(w2,j+2,WAVE), __shfl(w3,j+2,WAVE), myh);
      float u3 = selh(__shfl(w0,j+3,WAVE), __shfl(w1,j+3,WAVE), __shfl(w2,j+3,WAVE), __shfl(w3,j+3,WAVE), myh);
      float4 v0 = ((const float4*)(h + (size_t)sj0*HC))[lane];
      float4 v1 = ((const float4*)(h + (size_t)sj1*HC))[lane];
      float4 v2 = ((const float4*)(h + (size_t)sj2*HC))[lane];
      float4 v3 = ((const float4*)(h + (size_t)sj3*HC))[lane];
      acc0.x = fmaf(u0, v0.x, fmaf(u1, v1.x, fmaf(u2, v2.x, fmaf(u3, v3.x, acc0.x))));
      acc0.y = fmaf(u0, v0.y, fmaf(u1, v1.y, fmaf(u2, v2.y, fmaf(u3, v3.y, acc0.y))));
      acc0.z = fmaf(u0, v0.z, fmaf(u1, v1.z, fmaf(u2, v2.z, fmaf(u3, v3.z, acc0.z))));
      acc0.w = fmaf(u0, v0.w, fmaf(u1, v1.w, fmaf(u2, v2.w, fmaf(u3, v3.w, acc0.w))));
    }
    for (; j < nn; ++j){
      int sj = __shfl(sidx, j, WAVE);
      float u = selh(__shfl(w0,j,WAVE), __shfl(w1,j,WAVE), __shfl(w2,j,WAVE), __shfl(w3,j,WAVE), myh);
      float4 v = ((const float4*)(h + (size_t)sj*HC))[lane];
      acc0.x = fmaf(u, v.x, acc0.x); acc0.y = fmaf(u, v.y, acc0.y);
      acc0.z = fmaf(u, v.z, acc0.z); acc0.w = fmaf(u, v.w, acc0.w);
    }
  }

  const float4 bv = ((const float4*)bias)[lane];
  float4 r;
  r.x = acc0.x + bv.x; r.y = acc0.y + bv.y;
  r.z = acc0.z + bv.z; r.w = acc0.w + bv.w;
  r.x = r.x > 0.f ? r.x : expm1f(r.x);
  r.y = r.y > 0.f ? r.y : expm1f(r.y);
  r.z = r.z > 0.f ? r.z : expm1f(r.z);
  r.w = r.w > 0.f ? r.w : expm1f(r.w);
  ushort4 H, L;
  H.x = f2b(r.x); L.x = f2b(r.x - b2f(H.x));
  H.y = f2b(r.y); L.y = f2b(r.y - b2f(H.y));
  H.z = f2b(r.z); L.z = f2b(r.z - b2f(H.z));
  H.w = f2b(r.w); L.w = f2b(r.w - b2f(H.w));
  *(ushort4*)(oAh + (size_t)wid*HC + lane*4) = H;
  *(ushort4*)(oAl + (size_t)wid*HC + lane*4) = L;
}

// ---------------- fp16-gather agg (layers 2..4) ----------------
// WF32=1: write f32 elu(out) (final layer, feeds pooling)
// WF32=0: write bf16 hi/lo split of elu(out) (feeds next GEMM)
template<int HC, int WF32>
__global__ __launch_bounds__(256)
void k_agg_h(const int* __restrict__ rp, const int* __restrict__ es,
             const float* __restrict__ as4, const float* __restrict__ ad4,
             const _Float16* __restrict__ h, const float* __restrict__ bias,
             float* __restrict__ outF,
             unsigned short* __restrict__ oAh, unsigned short* __restrict__ oAl, int N){
  constexpr int VEC = HC / 64;           // halves per lane (4 or 8)
  int wid  = (blockIdx.x*blockDim.x + threadIdx.x) >> 6;
  int lane = threadIdx.x & 63;
  if (wid >= N) return;
  int beg = rp[wid], end = rp[wid+1];

  const float4 adv = *(const float4*)(ad4 + (size_t)wid*4);
  const float ad0 = adv.x, ad1 = adv.y, ad2 = adv.z, ad3 = adv.w;

  float m0=-1e30f, m1=-1e30f, m2=-1e30f, m3=-1e30f;
  float s0=0.f, s1=0.f, s2=0.f, s3=0.f;
  for (int i = beg + lane; i < end; i += WAVE){
    int s = es[i];
    const float4 av = *(const float4*)(as4 + (size_t)s*4);
    float e, mn;
    e = av.x + ad0; e = (e >= 0.f) ? e : 0.2f*e;
    mn = fmaxf(m0, e); s0 = s0*__expf(m0-mn) + __expf(e-mn); m0 = mn;
    e = av.y + ad1; e = (e >= 0.f) ? e : 0.2f*e;
    mn = fmaxf(m1, e); s1 = s1*__expf(m1-mn) + __expf(e-mn); m1 = mn;
    e = av.z + ad2; e = (e >= 0.f) ? e : 0.2f*e;
    mn = fmaxf(m2, e); s2 = s2*__expf(m2-mn) + __expf(e-mn); m2 = mn;
    e = av.w + ad3; e = (e >= 0.f) ? e : 0.2f*e;
    mn = fmaxf(m3, e); s3 = s3*__expf(m3-mn) + __expf(e-mn); m3 = mn;
  }
  #pragma unroll
  for (int off = 32; off > 0; off >>= 1){
    float mo, so, mn;
    mo = __shfl_xor(m0, off, WAVE); so = __shfl_xor(s0, off, WAVE);
    mn = fmaxf(m0, mo); s0 = s0*__expf(m0-mn) + so*__expf(mo-mn); m0 = mn;
    mo = __shfl_xor(m1, off, WAVE); so = __shfl_xor(s1, off, WAVE);
    mn = fmaxf(m1, mo); s1 = s1*__expf(m1-mn) + so*__expf(mo-mn); m1 = mn;
    mo = __shfl_xor(m2, off, WAVE); so = __shfl_xor(s2, off, WAVE);
    mn = fmaxf(m2, mo); s2 = s2*__expf(m2-mn) + so*__expf(mo-mn); m2 = mn;
    mo = __shfl_xor(m3, off, WAVE); so = __shfl_xor(s3, off, WAVE);
    mn = fmaxf(m3, mo); s3 = s3*__expf(m3-mn) + so*__expf(mo-mn); m3 = mn;
  }
  const float i0 = 1.f/(s0 + 1e-16f), i1 = 1.f/(s1 + 1e-16f);
  const float i2 = 1.f/(s2 + 1e-16f), i3 = 1.f/(s3 + 1e-16f);
  const int myh = lane >> 4;               // col = lane*VEC + c; head = col/(HC/4) = lane>>4

  float ac[VEC] = {};                      // static indices only (unrolled)

  for (int cb = beg; cb < end; cb += WAVE){
    int nn = min(WAVE, end - cb);
    int sidx = 0;
    float w0 = 0.f, w1 = 0.f, w2 = 0.f, w3 = 0.f;
    if (cb + lane < end){
      sidx = es[cb + lane];
      const float4 av = *(const float4*)(as4 + (size_t)sidx*4);
      float e;
      e = av.x + ad0; e = (e >= 0.f) ? e : 0.2f*e; w0 = __expf(e - m0)*i0;
      e = av.y + ad1; e = (e >= 0.f) ? e : 0.2f*e; w1 = __expf(e - m1)*i1;
      e = av.z + ad2; e = (e >= 0.f) ? e : 0.2f*e; w2 = __expf(e - m2)*i2;
      e = av.w + ad3; e = (e >= 0.f) ? e : 0.2f*e; w3 = __expf(e - m3)*i3;
    }

    int j = 0;
    for (; j + 4 <= nn; j += 4){
      int sj0 = __shfl(sidx, j+0, WAVE), sj1 = __shfl(sidx, j+1, WAVE);
      int sj2 = __shfl(sidx, j+2, WAVE), sj3 = __shfl(sidx, j+3, WAVE);
      float u0 = selh(__shfl(w0,j+0,WAVE), __shfl(w1,j+0,WAVE), __shfl(w2,j+0,WAVE), __shfl(w3,j+0,WAVE), myh);
      float u1 = selh(__shfl(w0,j+1,WAVE), __shfl(w1,j+1,WAVE), __shfl(w2,j+1,WAVE), __shfl(w3,j+1,WAVE), myh);
      float u2 = selh(__shfl(w0,j+2,WAVE), __shfl(w1,j+2,WAVE), __shfl(w2,j+2,WAVE), __shfl(w3,j+2,WAVE), myh);
      float u3 = selh(__shfl(w0,j+3,WAVE), __shfl(w1,j+3,WAVE), __shfl(w2,j+3,WAVE), __shfl(w3,j+3,WAVE), myh);
      if (VEC == 4){
        h16x4 v0 = *(const h16x4*)(h + (size_t)sj0*HC + lane*4);
        h16x4 v1 = *(const h16x4*)(h + (size_t)sj1*HC + lane*4);
        h16x4 v2 = *(const h16x4*)(h + (size_t)sj2*HC + lane*4);
        h16x4 v3 = *(const h16x4*)(h + (size_t)sj3*HC + lane*4);
        #pragma unroll
        for (int c = 0; c < 4; ++c)
          ac[c] = fmaf(u0,(float)v0[c], fmaf(u1,(float)v1[c], fmaf(u2,(float)v2[c], fmaf(u3,(float)v3[c], ac[c]))));
      } else {
        h16x8 v0 = *(const h16x8*)(h + (size_t)sj0*HC + lane*8);
        h16x8 v1 = *(const h16x8*)(h + (size_t)sj1*HC + lane*8);
        h16x8 v2 = *(const h16x8*)(h + (size_t)sj2*HC + lane*8);
        h16x8 v3 = *(const h16x8*)(h + (size_t)sj3*HC + lane*8);
        #pragma unroll
        for (int c = 0; c < VEC; ++c)
          ac[c] = fmaf(u0,(float)v0[c], fmaf(u1,(float)v1[c], fmaf(u2,(float)v2[c], fmaf(u3,(float)v3[c], ac[c]))));
      }
    }
    for (; j < nn; ++j){
      int sj = __shfl(sidx, j, WAVE);
      float u = selh(__shfl(w0,j,WAVE), __shfl(w1,j,WAVE), __shfl(w2,j,WAVE), __shfl(w3,j,WAVE), myh);
      if (VEC == 4){
        h16x4 v = *(const h16x4*)(h + (size_t)sj*HC + lane*4);
        #pragma unroll
        for (int c = 0; c < 4; ++c) ac[c] = fmaf(u, (float)v[c], ac[c]);
      } else {
        h16x8 v = *(const h16x8*)(h + (size_t)sj*HC + lane*8);
        #pragma unroll
        for (int c = 0; c < VEC; ++c) ac[c] = fmaf(u, (float)v[c], ac[c]);
      }
    }
  }

  // epilogue: bias + ELU
  float r0=0,r1=0,r2=0,r3=0,r4=0,r5=0,r6=0,r7=0;
  {
    const float* bp = bias + lane*VEC;
    #pragma unroll
    for (int c = 0; c < VEC; ++c){
      float r = ac[c] + bp[c];
      r = r > 0.f ? r : expm1f(r);
      if (c==0) r0=r; else if (c==1) r1=r; else if (c==2) r2=r; else if (c==3) r3=r;
      else if (c==4) r4=r; else if (c==5) r5=r; else if (c==6) r6=r; else r7=r;
    }
  }
  if (WF32){
    float* op = outF + (size_t)wid*HC + lane*VEC;
    *(float4*)op = make_float4(r0,r1,r2,r3);
    if (VEC == 8) *(float4*)(op+4) = make_float4(r4,r5,r6,r7);
  } else {
    ushort4 H, L;
    H.x = f2b(r0); L.x = f2b(r0 - b2f(H.x));
    H.y = f2b(r1); L.y = f2b(r1 - b2f(H.y));
    H.z = f2b(r2); L.z = f2b(r2 - b2f(H.z));
    H.w = f2b(r3); L.w = f2b(r3 - b2f(H.w));
    *(ushort4*)(oAh + (size_t)wid*HC + lane*VEC) = H;
    *(ushort4*)(oAl + (size_t)wid*HC + lane*VEC) = L;
    if (VEC == 8){
      ushort4 H2, L2;
      H2.x = f2b(r4); L2.x = f2b(r4 - b2f(H2.x));
      H2.y = f2b(r5); L2.y = f2b(r5 - b2f(H2.y));
      H2.z = f2b(r6); L2.z = f2b(r6 - b2f(H2.z));
      H2.w = f2b(r7); L2.w = f2b(r7 - b2f(H2.w));
      *(ushort4*)(oAh + (size_t)wid*HC + lane*VEC + 4) = H2;
      *(ushort4*)(oAl + (size_t)wid*HC + lane*VEC + 4) = L2;
    }
  }
}

// ---------------- pooling + FC ----------------
__global__ void k_pool_partial(const float* __restrict__ h, const int* __restrict__ bs,
                               float* __restrict__ psum, float* __restrict__ pmax){
  int b = blockIdx.x, ch = blockIdx.y;
  int f = threadIdx.x;
  int s = bs[b], e = bs[b+1];
  long long len = e - s;
  int i0 = s + (int)(len * ch / 8);
  int i1 = s + (int)(len * (ch+1) / 8);
  float sm = 0.f, mx = -3.0e38f;
  for (int i = i0; i < i1; ++i){
    float v = h[(size_t)i*512 + f];
    sm += v; mx = fmaxf(mx, v);
  }
  int idx = (b*8 + ch)*512 + f;
  psum[idx] = sm; pmax[idx] = mx;
}

__global__ void k_pool_final(const float* __restrict__ psum, const float* __restrict__ pmax,
                             const int* __restrict__ bs, float* __restrict__ g){
  int b = blockIdx.x, f = threadIdx.x;
  float sm = 0.f, mx = -3.0e38f;
  for (int c = 0; c < 8; ++c){
    int idx = (b*8 + c)*512 + f;
    sm += psum[idx]; mx = fmaxf(mx, pmax[idx]);
  }
  int cnt = bs[b+1] - bs[b];
  g[b*1024 + f] = sm / fmaxf((float)cnt, 1.f);
  g[b*1024 + 512 + f] = (mx > -1e37f) ? mx : 0.f;
}

__global__ __launch_bounds__(256)
void k_fc(const float* __restrict__ g, const float* __restrict__ fcW,
          const float* __restrict__ fcb, float* __restrict__ out){
  __shared__ float gs[1024];
  __shared__ float red[4][64];
  int b = blockIdx.x, t = threadIdx.x;
  int o0 = blockIdx.y * 64;
  for (int i = t; i < 1024; i += 256) gs[i] = g[b*1024 + i];
  __syncthreads();
  int ol = t & 63, q = t >> 6;
  const float* wp = fcW + (size_t)(q*256)*512 + o0 + ol;
  float acc = 0.f;
  #pragma unroll 8
  for (int k = 0; k < 256; ++k)
    acc = fmaf(gs[q*256 + k], wp[(size_t)k*512], acc);
  red[q][ol] = acc;
  __syncthreads();
  if (t < 64){
    float r = red[0][t] + red[1][t] + red[2][t] + red[3][t] + fcb[o0 + t];
    out[b*512 + o0 + t] = r;
  }
}

// ---------------- launcher ----------------
extern "C" void kernel_launch(void* const* d_in, const int* in_sizes, int n_in,
                              void* d_out, int out_size, void* d_ws, size_t ws_size,
                              hipStream_t stream){
  (void)n_in; (void)out_size; (void)ws_size;
  const float* x     = (const float*)d_in[0];
  const int*   ei    = (const int*)d_in[1];
  const int*   batch = (const int*)d_in[2];
  const float* W[4]   = {(const float*)d_in[3],(const float*)d_in[7],(const float*)d_in[11],(const float*)d_in[15]};
  const float* asr[4] = {(const float*)d_in[4],(const float*)d_in[8],(const float*)d_in[12],(const float*)d_in[16]};
  const float* adt[4] = {(const float*)d_in[5],(const float*)d_in[9],(const float*)d_in[13],(const float*)d_in[17]};
  const float* bb[4]  = {(const float*)d_in[6],(const float*)d_in[10],(const float*)d_in[14],(const float*)d_in[18]};
  const float* fcW = (const float*)d_in[19];
  const float* fcb = (const float*)d_in[20];

  const int N  = in_sizes[0] / 128;
  const int E  = in_sizes[1] / 2;
  const int EN = E + N;
  const int B  = 32;
  const int NB = (N + 1023) / 1024;

  char* p = (char*)d_ws;
  auto alloc = [&](size_t bytes){ void* r = (void*)p; p += (bytes + 255) & ~(size_t)255; return r; };
  float* bufA = (float*)alloc((size_t)N*512*4);            // final f32 h (pooling input)
  float* bufB = (float*)alloc((size_t)N*512*4);            // GEMM f32 out (alpha input)
  _Float16* bufH = (_Float16*)alloc((size_t)N*512*2);      // GEMM fp16 out (gather input)
  unsigned short* Ah = (unsigned short*)alloc((size_t)N*256*2);
  unsigned short* Al = (unsigned short*)alloc((size_t)N*256*2);
  unsigned short* Wh = (unsigned short*)alloc((size_t)512*256*2);
  unsigned short* Wl = (unsigned short*)alloc((size_t)512*256*2);
  float* as4  = (float*)alloc((size_t)N*4*4);
  float* ad4  = (float*)alloc((size_t)N*4*4);
  int*   cnt  = (int*)alloc((size_t)N*4);
  int*   rp   = (int*)alloc((size_t)(N+1)*4);
  int*   cur  = (int*)alloc((size_t)N*4);
  int*   es   = (int*)alloc((size_t)EN*4);
  int*   bs   = (int*)alloc((size_t)(B+1)*4);
  int*   bsum = (int*)alloc((size_t)64*4);
  float* gpo  = (float*)alloc((size_t)B*1024*4);
  float* psum = (float*)alloc((size_t)B*8*512*4);
  float* pmax = (float*)alloc((size_t)B*8*512*4);

  // CSR build
  k_zero_i<<<(N+255)/256, 256, 0, stream>>>(cnt, N);
  k_count<<<(EN+255)/256, 256, 0, stream>>>(ei, E, N, cnt);
  k_scan1<<<NB, 1024, 0, stream>>>(cnt, rp, bsum, N);
  k_scan2<<<1, 64, 0, stream>>>(bsum, NB, rp, N);
  k_scan3<<<NB, 1024, 0, stream>>>(rp, bsum, N);
  k_copy_i<<<(N+255)/256, 256, 0, stream>>>(rp, cur, N);
  k_fill<<<(EN+255)/256, 256, 0, stream>>>(ei, E, N, cur, es);
  k_bounds<<<1, 64, 0, stream>>>(batch, N, B, bs);

  const int wgrid = (N + 3) / 4;

  // layer-1 input -> bf16 split
  k_cvt<<<((N*128/4) + 255)/256, 256, 0, stream>>>(x, Ah, Al, N*128/4);

  // L1: f32 gather
  k_cvt_w<<<(128*256 + 255)/256, 256, 0, stream>>>(W[0], Wh, Wl, 128, 256);
  {
    dim3 gg((N + 63)/64, 256/64);
    k_gemm_mfma<<<gg, 256, 0, stream>>>(Ah, Al, Wh, Wl, bufB, (_Float16*)nullptr, N, 128, 256);
  }
  k_alpha<256,64><<<wgrid, 256, 0, stream>>>(bufB, asr[0], adt[0], as4, ad4, N);
  k_agg_f32<<<wgrid, 256, 0, stream>>>(rp, es, as4, ad4, bufB, bb[0], Ah, Al, N);

  // L2, L3: fp16 gather, bf16-split output
  for (int L = 1; L <= 2; ++L){
    k_cvt_w<<<(256*256 + 255)/256, 256, 0, stream>>>(W[L], Wh, Wl, 256, 256);
    dim3 gg((N + 63)/64, 256/64);
    k_gemm_mfma<<<gg, 256, 0, stream>>>(Ah, Al, Wh, Wl, bufB, bufH, N, 256, 256);
    k_alpha<256,64><<<wgrid, 256, 0, stream>>>(bufB, asr[L], adt[L], as4, ad4, N);
    k_agg_h<256,0><<<wgrid, 256, 0, stream>>>(rp, es, as4, ad4, bufH, bb[L], (float*)nullptr, Ah, Al, N);
  }

  // L4: fp16 gather, f32 output for pooling
  k_cvt_w<<<(256*512 + 255)/256, 256, 0, stream>>>(W[3], Wh, Wl, 256, 512);
  {
    dim3 gg((N + 63)/64, 512/64);
    k_gemm_mfma<<<gg, 256, 0, stream>>>(Ah, Al, Wh, Wl, bufB, bufH, N, 256, 512);
  }
  k_alpha<512,128><<<wgrid, 256, 0, stream>>>(bufB, asr[3], adt[3], as4, ad4, N);
  k_agg_h<512,1><<<wgrid, 256, 0, stream>>>(rp, es, as4, ad4, bufH, bb[3], bufA, (unsigned short*)nullptr, (unsigned short*)nullptr, N);

  dim3 pg(B, 8);
  k_pool_partial<<<pg, 512, 0, stream>>>(bufA, bs, psum, pmax);
  k_pool_final<<<B, 512, 0, stream>>>(psum, pmax, bs, gpo);
  dim3 fg(B, 8);
  k_fc<<<fg, 256, 0, stream>>>(gpo, fcW, fcb, (float*)d_out);
}

// Round 5
// 512.263 us; speedup vs baseline: 1.8647x; 1.1147x over previous
//
#include <hip/hip_runtime.h>
#include <math.h>

#define WAVE 64

typedef __attribute__((ext_vector_type(8))) short short8v;
typedef __attribute__((ext_vector_type(4))) float f32x4;
typedef _Float16 h16x4 __attribute__((ext_vector_type(4)));
typedef _Float16 h16x8 __attribute__((ext_vector_type(8)));

__device__ __forceinline__ unsigned short f2b(float x){
  unsigned u = __float_as_uint(x);
  unsigned r = u + 0x7fffu + ((u >> 16) & 1u);
  return (unsigned short)(r >> 16);
}
__device__ __forceinline__ float b2f(unsigned short h){
  return __uint_as_float(((unsigned)h) << 16);
}
__device__ __forceinline__ float selh(float e0, float e1, float e2, float e3, int m){
  float r = (m == 1) ? e1 : e0;
  r = (m == 2) ? e2 : r;
  r = (m == 3) ? e3 : r;
  return r;
}

// ---------------- CSR build ----------------
__global__ void k_zero_i(int* p, int n){
  int i = blockIdx.x*blockDim.x + threadIdx.x;
  if (i < n) p[i] = 0;
}

__global__ void k_zero_f(float* p, int n){
  int i = blockIdx.x*blockDim.x + threadIdx.x;
  if (i < n) p[i] = 0.f;
}

__global__ void k_count(const int* __restrict__ ei, int E, int N, int* __restrict__ cnt){
  int i = blockIdx.x*blockDim.x + threadIdx.x;
  if (i >= E + N) return;
  int d = (i < E) ? ei[E + i] : (i - E);
  atomicAdd(&cnt[d], 1);
}

__global__ __launch_bounds__(1024)
void k_scan1(const int* __restrict__ cnt, int* __restrict__ rp, int* __restrict__ bsum, int N){
  __shared__ int sd[1024];
  int t = threadIdx.x, i = blockIdx.x*1024 + t;
  int v = (i < N) ? cnt[i] : 0;
  sd[t] = v;
  __syncthreads();
  for (int off = 1; off < 1024; off <<= 1){
    int x = (t >= off) ? sd[t-off] : 0;
    __syncthreads();
    sd[t] += x;
    __syncthreads();
  }
  if (i < N) rp[i] = sd[t] - v;
  if (t == 1023) bsum[blockIdx.x] = sd[1023];
}

__global__ void k_scan2(int* __restrict__ bsum, int nb, int* __restrict__ rp, int N){
  int t = threadIdx.x;
  int orig = (t < nb) ? bsum[t] : 0;
  int v = orig;
  #pragma unroll
  for (int off = 1; off < 64; off <<= 1){
    int x = __shfl_up(v, off, WAVE);
    if (t >= off) v += x;
  }
  if (t < nb) bsum[t] = v - orig;
  if (t == 63) rp[N] = v;
}

__global__ __launch_bounds__(1024)
void k_scan3(int* __restrict__ rp, const int* __restrict__ bsum, int N){
  int i = blockIdx.x*1024 + threadIdx.x;
  if (i < N) rp[i] += bsum[blockIdx.x];
}

__global__ void k_copy_i(const int* __restrict__ a, int* __restrict__ b, int n){
  int i = blockIdx.x*blockDim.x + threadIdx.x;
  if (i < n) b[i] = a[i];
}

__global__ void k_fill(const int* __restrict__ ei, int E, int N,
                       int* __restrict__ cur, int* __restrict__ es){
  int i = blockIdx.x*blockDim.x + threadIdx.x;
  if (i >= E + N) return;
  int s, d;
  if (i < E){ s = ei[i]; d = ei[E + i]; } else { s = d = i - E; }
  int pos = atomicAdd(&cur[d], 1);
  es[pos] = s;
}

__global__ void k_bounds(const int* __restrict__ batch, int N, int B, int* __restrict__ bs){
  int b = blockIdx.x*blockDim.x + threadIdx.x;
  if (b > B) return;
  int lo = 0, hi = N;
  while (lo < hi){ int mid = (lo + hi) >> 1; if (batch[mid] < b) lo = mid + 1; else hi = mid; }
  bs[b] = lo;
}

// ---------------- f32 -> bf16 hi/lo (layer-1 input only) ----------------
__global__ __launch_bounds__(256)
void k_cvt(const float* __restrict__ in, unsigned short* __restrict__ hi,
           unsigned short* __restrict__ lo, int n4){
  int i = blockIdx.x*blockDim.x + threadIdx.x;
  if (i >= n4) return;
  float4 v = ((const float4*)in)[i];
  ushort4 h, l;
  h.x = f2b(v.x); l.x = f2b(v.x - b2f(h.x));
  h.y = f2b(v.y); l.y = f2b(v.y - b2f(h.y));
  h.z = f2b(v.z); l.z = f2b(v.z - b2f(h.z));
  h.w = f2b(v.w); l.w = f2b(v.w - b2f(h.w));
  ((ushort4*)hi)[i] = h;
  ((ushort4*)lo)[i] = l;
}

// W[K,Nc] -> W^T hi/lo [Nc,K]
__global__ __launch_bounds__(256)
void k_cvt_w(const float* __restrict__ W, unsigned short* __restrict__ th,
             unsigned short* __restrict__ tl, int K, int Nc){
  int i = blockIdx.x*blockDim.x + threadIdx.x;
  if (i >= K*Nc) return;
  int k = i / Nc, n = i - k*Nc;
  float a = W[i];
  unsigned short h = f2b(a);
  unsigned short l = f2b(a - b2f(h));
  th[(size_t)n*K + k] = h;
  tl[(size_t)n*K + k] = l;
}

// ---------------- split-bf16 MFMA GEMM, fused alpha ----------------
// h = A@W (f32 accum, via 3-term split-bf16 MFMA). Writes fp16 h only.
// alpha_s/alpha_d per (row, head) computed from f32 acc in epilogue ->
// cross-lane reduce -> atomicAdd into as4/ad4 (zeroed before launch).
// Each blockIdx.y covers one 64-col slab => exactly one head (64 | CHEAD).
template<int CHEAD>
__global__ __launch_bounds__(256)
void k_gemm_fused(const unsigned short* __restrict__ Ah, const unsigned short* __restrict__ Al,
                  const unsigned short* __restrict__ Bh, const unsigned short* __restrict__ Bl,
                  _Float16* __restrict__ Ch,
                  const float* __restrict__ asr, const float* __restrict__ adt,
                  float* __restrict__ as4, float* __restrict__ ad4,
                  int M, int K, int Nc){
  constexpr int LDP = 40;  // padded row stride (shorts) -> <=2-way LDS banks
  __shared__ unsigned short sAh[64*LDP], sAl[64*LDP], sBh[64*LDP], sBl[64*LDP];
  const int tid = threadIdx.x;
  const int m0 = blockIdx.x*64, n0 = blockIdx.y*64;
  const int w = tid >> 6, l = tid & 63;
  const int sr = tid >> 2, sc = (tid & 3)*8;
  f32x4 acc0 = {0.f,0.f,0.f,0.f}, acc1 = acc0, acc2 = acc0, acc3 = acc0;
  const int arow = m0 + sr;
  const bool aval = arow < M;
  const size_t aoff = (size_t)arow*K + sc;
  const size_t boff = (size_t)(n0 + sr)*K + sc;
  const int fa = (w*16 + (l & 15))*LDP + (l >> 4)*8;
  const int fb = (l & 15)*LDP + (l >> 4)*8;

  for (int k0 = 0; k0 < K; k0 += 32){
    uint4 z = make_uint4(0,0,0,0);
    uint4 va_h = z, va_l = z;
    if (aval){
      va_h = *(const uint4*)(Ah + aoff + k0);
      va_l = *(const uint4*)(Al + aoff + k0);
    }
    uint4 vb_h = *(const uint4*)(Bh + boff + k0);
    uint4 vb_l = *(const uint4*)(Bl + boff + k0);
    __syncthreads();
    *(uint4*)&sAh[sr*LDP + sc] = va_h;
    *(uint4*)&sAl[sr*LDP + sc] = va_l;
    *(uint4*)&sBh[sr*LDP + sc] = vb_h;
    *(uint4*)&sBl[sr*LDP + sc] = vb_l;
    __syncthreads();

    short8v a_h = *(const short8v*)&sAh[fa];
    short8v a_l = *(const short8v*)&sAl[fa];

    short8v b_h, b_l;
    b_h = *(const short8v*)&sBh[fb];
    b_l = *(const short8v*)&sBl[fb];
    acc0 = __builtin_amdgcn_mfma_f32_16x16x32_bf16(a_h, b_h, acc0, 0, 0, 0);
    acc0 = __builtin_amdgcn_mfma_f32_16x16x32_bf16(a_h, b_l, acc0, 0, 0, 0);
    acc0 = __builtin_amdgcn_mfma_f32_16x16x32_bf16(a_l, b_h, acc0, 0, 0, 0);

    b_h = *(const short8v*)&sBh[fb + 16*LDP];
    b_l = *(const short8v*)&sBl[fb + 16*LDP];
    acc1 = __builtin_amdgcn_mfma_f32_16x16x32_bf16(a_h, b_h, acc1, 0, 0, 0);
    acc1 = __builtin_amdgcn_mfma_f32_16x16x32_bf16(a_h, b_l, acc1, 0, 0, 0);
    acc1 = __builtin_amdgcn_mfma_f32_16x16x32_bf16(a_l, b_h, acc1, 0, 0, 0);

    b_h = *(const short8v*)&sBh[fb + 32*LDP];
    b_l = *(const short8v*)&sBl[fb + 32*LDP];
    acc2 = __builtin_amdgcn_mfma_f32_16x16x32_bf16(a_h, b_h, acc2, 0, 0, 0);
    acc2 = __builtin_amdgcn_mfma_f32_16x16x32_bf16(a_h, b_l, acc2, 0, 0, 0);
    acc2 = __builtin_amdgcn_mfma_f32_16x16x32_bf16(a_l, b_h, acc2, 0, 0, 0);

    b_h = *(const short8v*)&sBh[fb + 48*LDP];
    b_l = *(const short8v*)&sBl[fb + 48*LDP];
    acc3 = __builtin_amdgcn_mfma_f32_16x16x32_bf16(a_h, b_h, acc3, 0, 0, 0);
    acc3 = __builtin_amdgcn_mfma_f32_16x16x32_bf16(a_h, b_l, acc3, 0, 0, 0);
    acc3 = __builtin_amdgcn_mfma_f32_16x16x32_bf16(a_l, b_h, acc3, 0, 0, 0);
    __syncthreads();
  }

  // C/D layout: col = lane&15, row = (lane>>4)*4 + j
  const int rb = m0 + w*16 + (l >> 4)*4;
  const int cb = n0 + (l & 15);

  // fp16 h write
  #pragma unroll
  for (int j = 0; j < 4; ++j){
    int row = rb + j;
    if (row < M){
      _Float16* hp = Ch + (size_t)row*Nc + cb;
      hp[0]  = (_Float16)acc0[j];
      hp[16] = (_Float16)acc1[j];
      hp[32] = (_Float16)acc2[j];
      hp[48] = (_Float16)acc3[j];
    }
  }

  // fused alpha: per-row dot with a_src/a_dst over this 64-col slab
  const int hy = n0 / CHEAD;
  const float ca0 = asr[cb], ca1 = asr[cb+16], ca2 = asr[cb+32], ca3 = asr[cb+48];
  const float cd0 = adt[cb], cd1 = adt[cb+16], cd2 = adt[cb+32], cd3 = adt[cb+48];
  #pragma unroll
  for (int j = 0; j < 4; ++j){
    float ps = ca0*acc0[j] + ca1*acc1[j] + ca2*acc2[j] + ca3*acc3[j];
    float pd = cd0*acc0[j] + cd1*acc1[j] + cd2*acc2[j] + cd3*acc3[j];
    ps += __shfl_xor(ps, 1, WAVE);  pd += __shfl_xor(pd, 1, WAVE);
    ps += __shfl_xor(ps, 2, WAVE);  pd += __shfl_xor(pd, 2, WAVE);
    ps += __shfl_xor(ps, 4, WAVE);  pd += __shfl_xor(pd, 4, WAVE);
    ps += __shfl_xor(ps, 8, WAVE);  pd += __shfl_xor(pd, 8, WAVE);
    int row = rb + j;
    if ((l & 15) == 0 && row < M){
      atomicAdd(&as4[(size_t)row*4 + hy], ps);
      atomicAdd(&ad4[(size_t)row*4 + hy], pd);
    }
  }
}

// ---------------- fp16-gather agg (all layers) ----------------
// WF32=1: write f32 elu(out) (final layer, feeds pooling)
// WF32=0: write bf16 hi/lo split of elu(out) (feeds next GEMM)
template<int HC, int WF32>
__global__ __launch_bounds__(256)
void k_agg_h(const int* __restrict__ rp, const int* __restrict__ es,
             const float* __restrict__ as4, const float* __restrict__ ad4,
             const _Float16* __restrict__ h, const float* __restrict__ bias,
             float* __restrict__ outF,
             unsigned short* __restrict__ oAh, unsigned short* __restrict__ oAl, int N){
  constexpr int VEC = HC / 64;           // halves per lane (4 or 8)
  int wid  = (blockIdx.x*blockDim.x + threadIdx.x) >> 6;
  int lane = threadIdx.x & 63;
  if (wid >= N) return;
  int beg = rp[wid], end = rp[wid+1];

  const float4 adv = *(const float4*)(ad4 + (size_t)wid*4);
  const float ad0 = adv.x, ad1 = adv.y, ad2 = adv.z, ad3 = adv.w;

  float m0=-1e30f, m1=-1e30f, m2=-1e30f, m3=-1e30f;
  float s0=0.f, s1=0.f, s2=0.f, s3=0.f;
  for (int i = beg + lane; i < end; i += WAVE){
    int s = es[i];
    const float4 av = *(const float4*)(as4 + (size_t)s*4);
    float e, mn;
    e = av.x + ad0; e = (e >= 0.f) ? e : 0.2f*e;
    mn = fmaxf(m0, e); s0 = s0*__expf(m0-mn) + __expf(e-mn); m0 = mn;
    e = av.y + ad1; e = (e >= 0.f) ? e : 0.2f*e;
    mn = fmaxf(m1, e); s1 = s1*__expf(m1-mn) + __expf(e-mn); m1 = mn;
    e = av.z + ad2; e = (e >= 0.f) ? e : 0.2f*e;
    mn = fmaxf(m2, e); s2 = s2*__expf(m2-mn) + __expf(e-mn); m2 = mn;
    e = av.w + ad3; e = (e >= 0.f) ? e : 0.2f*e;
    mn = fmaxf(m3, e); s3 = s3*__expf(m3-mn) + __expf(e-mn); m3 = mn;
  }
  #pragma unroll
  for (int off = 32; off > 0; off >>= 1){
    float mo, so, mn;
    mo = __shfl_xor(m0, off, WAVE); so = __shfl_xor(s0, off, WAVE);
    mn = fmaxf(m0, mo); s0 = s0*__expf(m0-mn) + so*__expf(mo-mn); m0 = mn;
    mo = __shfl_xor(m1, off, WAVE); so = __shfl_xor(s1, off, WAVE);
    mn = fmaxf(m1, mo); s1 = s1*__expf(m1-mn) + so*__expf(mo-mn); m1 = mn;
    mo = __shfl_xor(m2, off, WAVE); so = __shfl_xor(s2, off, WAVE);
    mn = fmaxf(m2, mo); s2 = s2*__expf(m2-mn) + so*__expf(mo-mn); m2 = mn;
    mo = __shfl_xor(m3, off, WAVE); so = __shfl_xor(s3, off, WAVE);
    mn = fmaxf(m3, mo); s3 = s3*__expf(m3-mn) + so*__expf(mo-mn); m3 = mn;
  }
  const float i0 = 1.f/(s0 + 1e-16f), i1 = 1.f/(s1 + 1e-16f);
  const float i2 = 1.f/(s2 + 1e-16f), i3 = 1.f/(s3 + 1e-16f);
  const int myh = lane >> 4;

  float ac[VEC] = {};

  for (int cb = beg; cb < end; cb += WAVE){
    int nn = min(WAVE, end - cb);
    int sidx = 0;
    float w0 = 0.f, w1 = 0.f, w2 = 0.f, w3 = 0.f;
    if (cb + lane < end){
      sidx = es[cb + lane];
      const float4 av = *(const float4*)(as4 + (size_t)sidx*4);
      float e;
      e = av.x + ad0; e = (e >= 0.f) ? e : 0.2f*e; w0 = __expf(e - m0)*i0;
      e = av.y + ad1; e = (e >= 0.f) ? e : 0.2f*e; w1 = __expf(e - m1)*i1;
      e = av.z + ad2; e = (e >= 0.f) ? e : 0.2f*e; w2 = __expf(e - m2)*i2;
      e = av.w + ad3; e = (e >= 0.f) ? e : 0.2f*e; w3 = __expf(e - m3)*i3;
    }

    int j = 0;
    for (; j + 4 <= nn; j += 4){
      int sj0 = __shfl(sidx, j+0, WAVE), sj1 = __shfl(sidx, j+1, WAVE);
      int sj2 = __shfl(sidx, j+2, WAVE), sj3 = __shfl(sidx, j+3, WAVE);
      float u0 = selh(__shfl(w0,j+0,WAVE), __shfl(w1,j+0,WAVE), __shfl(w2,j+0,WAVE), __shfl(w3,j+0,WAVE), myh);
      float u1 = selh(__shfl(w0,j+1,WAVE), __shfl(w1,j+1,WAVE), __shfl(w2,j+1,WAVE), __shfl(w3,j+1,WAVE), myh);
      float u2 = selh(__shfl(w0,j+2,WAVE), __shfl(w1,j+2,WAVE), __shfl(w2,j+2,WAVE), __shfl(w3,j+2,WAVE), myh);
      float u3 = selh(__shfl(w0,j+3,WAVE), __shfl(w1,j+3,WAVE), __shfl(w2,j+3,WAVE), __shfl(w3,j+3,WAVE), myh);
      if (VEC == 4){
        h16x4 v0 = *(const h16x4*)(h + (size_t)sj0*HC + lane*4);
        h16x4 v1 = *(const h16x4*)(h + (size_t)sj1*HC + lane*4);
        h16x4 v2 = *(const h16x4*)(h + (size_t)sj2*HC + lane*4);
        h16x4 v3 = *(const h16x4*)(h + (size_t)sj3*HC + lane*4);
        #pragma unroll
        for (int c = 0; c < 4; ++c)
          ac[c] = fmaf(u0,(float)v0[c], fmaf(u1,(float)v1[c], fmaf(u2,(float)v2[c], fmaf(u3,(float)v3[c], ac[c]))));
      } else {
        h16x8 v0 = *(const h16x8*)(h + (size_t)sj0*HC + lane*8);
        h16x8 v1 = *(const h16x8*)(h + (size_t)sj1*HC + lane*8);
        h16x8 v2 = *(const h16x8*)(h + (size_t)sj2*HC + lane*8);
        h16x8 v3 = *(const h16x8*)(h + (size_t)sj3*HC + lane*8);
        #pragma unroll
        for (int c = 0; c < VEC; ++c)
          ac[c] = fmaf(u0,(float)v0[c], fmaf(u1,(float)v1[c], fmaf(u2,(float)v2[c], fmaf(u3,(float)v3[c], ac[c]))));
      }
    }
    for (; j < nn; ++j){
      int sj = __shfl(sidx, j, WAVE);
      float u = selh(__shfl(w0,j,WAVE), __shfl(w1,j,WAVE), __shfl(w2,j,WAVE), __shfl(w3,j,WAVE), myh);
      if (VEC == 4){
        h16x4 v = *(const h16x4*)(h + (size_t)sj*HC + lane*4);
        #pragma unroll
        for (int c = 0; c < 4; ++c) ac[c] = fmaf(u, (float)v[c], ac[c]);
      } else {
        h16x8 v = *(const h16x8*)(h + (size_t)sj*HC + lane*8);
        #pragma unroll
        for (int c = 0; c < VEC; ++c) ac[c] = fmaf(u, (float)v[c], ac[c]);
      }
    }
  }

  float r0=0,r1=0,r2=0,r3=0,r4=0,r5=0,r6=0,r7=0;
  {
    const float* bp = bias + lane*VEC;
    #pragma unroll
    for (int c = 0; c < VEC; ++c){
      float r = ac[c] + bp[c];
      r = r > 0.f ? r : expm1f(r);
      if (c==0) r0=r; else if (c==1) r1=r; else if (c==2) r2=r; else if (c==3) r3=r;
      else if (c==4) r4=r; else if (c==5) r5=r; else if (c==6) r6=r; else r7=r;
    }
  }
  if (WF32){
    float* op = outF + (size_t)wid*HC + lane*VEC;
    *(float4*)op = make_float4(r0,r1,r2,r3);
    if (VEC == 8) *(float4*)(op+4) = make_float4(r4,r5,r6,r7);
  } else {
    ushort4 H, L;
    H.x = f2b(r0); L.x = f2b(r0 - b2f(H.x));
    H.y = f2b(r1); L.y = f2b(r1 - b2f(H.y));
    H.z = f2b(r2); L.z = f2b(r2 - b2f(H.z));
    H.w = f2b(r3); L.w = f2b(r3 - b2f(H.w));
    *(ushort4*)(oAh + (size_t)wid*HC + lane*VEC) = H;
    *(ushort4*)(oAl + (size_t)wid*HC + lane*VEC) = L;
    if (VEC == 8){
      ushort4 H2, L2;
      H2.x = f2b(r4); L2.x = f2b(r4 - b2f(H2.x));
      H2.y = f2b(r5); L2.y = f2b(r5 - b2f(H2.y));
      H2.z = f2b(r6); L2.z = f2b(r6 - b2f(H2.z));
      H2.w = f2b(r7); L2.w = f2b(r7 - b2f(H2.w));
      *(ushort4*)(oAh + (size_t)wid*HC + lane*VEC + 4) = H2;
      *(ushort4*)(oAl + (size_t)wid*HC + lane*VEC + 4) = L2;
    }
  }
}

// ---------------- pooling + FC ----------------
__global__ void k_pool_partial(const float* __restrict__ h, const int* __restrict__ bs,
                               float* __restrict__ psum, float* __restrict__ pmax){
  int b = blockIdx.x, ch = blockIdx.y;
  int f = threadIdx.x;
  int s = bs[b], e = bs[b+1];
  long long len = e - s;
  int i0 = s + (int)(len * ch / 8);
  int i1 = s + (int)(len * (ch+1) / 8);
  float sm = 0.f, mx = -3.0e38f;
  for (int i = i0; i < i1; ++i){
    float v = h[(size_t)i*512 + f];
    sm += v; mx = fmaxf(mx, v);
  }
  int idx = (b*8 + ch)*512 + f;
  psum[idx] = sm; pmax[idx] = mx;
}

__global__ void k_pool_final(const float* __restrict__ psum, const float* __restrict__ pmax,
                             const int* __restrict__ bs, float* __restrict__ g){
  int b = blockIdx.x, f = threadIdx.x;
  float sm = 0.f, mx = -3.0e38f;
  for (int c = 0; c < 8; ++c){
    int idx = (b*8 + c)*512 + f;
    sm += psum[idx]; mx = fmaxf(mx, pmax[idx]);
  }
  int cnt = bs[b+1] - bs[b];
  g[b*1024 + f] = sm / fmaxf((float)cnt, 1.f);
  g[b*1024 + 512 + f] = (mx > -1e37f) ? mx : 0.f;
}

__global__ __launch_bounds__(256)
void k_fc(const float* __restrict__ g, const float* __restrict__ fcW,
          const float* __restrict__ fcb, float* __restrict__ out){
  __shared__ float gs[1024];
  __shared__ float red[4][64];
  int b = blockIdx.x, t = threadIdx.x;
  int o0 = blockIdx.y * 64;
  for (int i = t; i < 1024; i += 256) gs[i] = g[b*1024 + i];
  __syncthreads();
  int ol = t & 63, q = t >> 6;
  const float* wp = fcW + (size_t)(q*256)*512 + o0 + ol;
  float acc = 0.f;
  #pragma unroll 8
  for (int k = 0; k < 256; ++k)
    acc = fmaf(gs[q*256 + k], wp[(size_t)k*512], acc);
  red[q][ol] = acc;
  __syncthreads();
  if (t < 64){
    float r = red[0][t] + red[1][t] + red[2][t] + red[3][t] + fcb[o0 + t];
    out[b*512 + o0 + t] = r;
  }
}

// ---------------- launcher ----------------
extern "C" void kernel_launch(void* const* d_in, const int* in_sizes, int n_in,
                              void* d_out, int out_size, void* d_ws, size_t ws_size,
                              hipStream_t stream){
  (void)n_in; (void)out_size; (void)ws_size;
  const float* x     = (const float*)d_in[0];
  const int*   ei    = (const int*)d_in[1];
  const int*   batch = (const int*)d_in[2];
  const float* W[4]   = {(const float*)d_in[3],(const float*)d_in[7],(const float*)d_in[11],(const float*)d_in[15]};
  const float* asr[4] = {(const float*)d_in[4],(const float*)d_in[8],(const float*)d_in[12],(const float*)d_in[16]};
  const float* adt[4] = {(const float*)d_in[5],(const float*)d_in[9],(const float*)d_in[13],(const float*)d_in[17]};
  const float* bb[4]  = {(const float*)d_in[6],(const float*)d_in[10],(const float*)d_in[14],(const float*)d_in[18]};
  const float* fcW = (const float*)d_in[19];
  const float* fcb = (const float*)d_in[20];

  const int N  = in_sizes[0] / 128;
  const int E  = in_sizes[1] / 2;
  const int EN = E + N;
  const int B  = 32;
  const int NB = (N + 1023) / 1024;

  char* p = (char*)d_ws;
  auto alloc = [&](size_t bytes){ void* r = (void*)p; p += (bytes + 255) & ~(size_t)255; return r; };
  float* bufA = (float*)alloc((size_t)N*512*4);            // final f32 h (pooling input)
  _Float16* bufH = (_Float16*)alloc((size_t)N*512*2);      // GEMM fp16 out (gather input)
  unsigned short* Ah = (unsigned short*)alloc((size_t)N*256*2);
  unsigned short* Al = (unsigned short*)alloc((size_t)N*256*2);
  unsigned short* Wh = (unsigned short*)alloc((size_t)512*256*2);
  unsigned short* Wl = (unsigned short*)alloc((size_t)512*256*2);
  float* a2   = (float*)alloc((size_t)N*8*4);              // as4 | ad4
  float* as4 = a2;
  float* ad4 = a2 + (size_t)N*4;
  int*   cnt  = (int*)alloc((size_t)N*4);
  int*   rp   = (int*)alloc((size_t)(N+1)*4);
  int*   cur  = (int*)alloc((size_t)N*4);
  int*   es   = (int*)alloc((size_t)EN*4);
  int*   bs   = (int*)alloc((size_t)(B+1)*4);
  int*   bsum = (int*)alloc((size_t)64*4);
  float* gpo  = (float*)alloc((size_t)B*1024*4);
  float* psum = (float*)alloc((size_t)B*8*512*4);
  float* pmax = (float*)alloc((size_t)B*8*512*4);

  // CSR build
  k_zero_i<<<(N+255)/256, 256, 0, stream>>>(cnt, N);
  k_count<<<(EN+255)/256, 256, 0, stream>>>(ei, E, N, cnt);
  k_scan1<<<NB, 1024, 0, stream>>>(cnt, rp, bsum, N);
  k_scan2<<<1, 64, 0, stream>>>(bsum, NB, rp, N);
  k_scan3<<<NB, 1024, 0, stream>>>(rp, bsum, N);
  k_copy_i<<<(N+255)/256, 256, 0, stream>>>(rp, cur, N);
  k_fill<<<(EN+255)/256, 256, 0, stream>>>(ei, E, N, cur, es);
  k_bounds<<<1, 64, 0, stream>>>(batch, N, B, bs);

  const int wgrid = (N + 3) / 4;

  // layer-1 input -> bf16 split
  k_cvt<<<((N*128/4) + 255)/256, 256, 0, stream>>>(x, Ah, Al, N*128/4);

  const int Kd[4]  = {128, 256, 256, 256};
  const int HCd[4] = {256, 256, 256, 512};

  for (int L = 0; L < 4; ++L){
    const int K = Kd[L], Nc = HCd[L];
    k_zero_f<<<(N*8 + 255)/256, 256, 0, stream>>>(a2, N*8);
    k_cvt_w<<<(K*Nc + 255)/256, 256, 0, stream>>>(W[L], Wh, Wl, K, Nc);
    dim3 gg((N + 63)/64, Nc/64);
    if (Nc == 256)
      k_gemm_fused<64><<<gg, 256, 0, stream>>>(Ah, Al, Wh, Wl, bufH, asr[L], adt[L], as4, ad4, N, K, Nc);
    else
      k_gemm_fused<128><<<gg, 256, 0, stream>>>(Ah, Al, Wh, Wl, bufH, asr[L], adt[L], as4, ad4, N, K, Nc);
    if (L < 3)
      k_agg_h<256,0><<<wgrid, 256, 0, stream>>>(rp, es, as4, ad4, bufH, bb[L], (float*)nullptr, Ah, Al, N);
    else
      k_agg_h<512,1><<<wgrid, 256, 0, stream>>>(rp, es, as4, ad4, bufH, bb[L], bufA, (unsigned short*)nullptr, (unsigned short*)nullptr, N);
  }

  dim3 pg(B, 8);
  k_pool_partial<<<pg, 512, 0, stream>>>(bufA, bs, psum, pmax);
  k_pool_final<<<B, 512, 0, stream>>>(psum, pmax, bs, gpo);
  dim3 fg(B, 8);
  k_fc<<<fg, 256, 0, stream>>>(gpo, fcW, fcb, (float*)d_out);
}

// Round 6
// 509.561 us; speedup vs baseline: 1.8746x; 1.0053x over previous
//
#include <hip/hip_runtime.h>
#include <math.h>

#define WAVE 64

typedef __attribute__((ext_vector_type(8))) short short8v;
typedef __attribute__((ext_vector_type(4))) float f32x4;
typedef _Float16 h16x4 __attribute__((ext_vector_type(4)));
typedef _Float16 h16x8 __attribute__((ext_vector_type(8)));

__device__ __forceinline__ unsigned short f2b(float x){
  unsigned u = __float_as_uint(x);
  unsigned r = u + 0x7fffu + ((u >> 16) & 1u);
  return (unsigned short)(r >> 16);
}
__device__ __forceinline__ float b2f(unsigned short h){
  return __uint_as_float(((unsigned)h) << 16);
}
__device__ __forceinline__ float selh(float e0, float e1, float e2, float e3, int m){
  float r = (m == 1) ? e1 : e0;
  r = (m == 2) ? e2 : r;
  r = (m == 3) ? e3 : r;
  return r;
}

// ---------------- CSR build ----------------
__global__ void k_zero_i(int* p, int n){
  int i = blockIdx.x*blockDim.x + threadIdx.x;
  if (i < n) p[i] = 0;
}

__global__ void k_zero_f(float* p, int n){
  int i = blockIdx.x*blockDim.x + threadIdx.x;
  if (i < n) p[i] = 0.f;
}

__global__ void k_count(const int* __restrict__ ei, int E, int N, int* __restrict__ cnt){
  int i = blockIdx.x*blockDim.x + threadIdx.x;
  if (i >= E + N) return;
  int d = (i < E) ? ei[E + i] : (i - E);
  atomicAdd(&cnt[d], 1);
}

__global__ __launch_bounds__(1024)
void k_scan1(const int* __restrict__ cnt, int* __restrict__ rp, int* __restrict__ bsum, int N){
  __shared__ int sd[1024];
  int t = threadIdx.x, i = blockIdx.x*1024 + t;
  int v = (i < N) ? cnt[i] : 0;
  sd[t] = v;
  __syncthreads();
  for (int off = 1; off < 1024; off <<= 1){
    int x = (t >= off) ? sd[t-off] : 0;
    __syncthreads();
    sd[t] += x;
    __syncthreads();
  }
  if (i < N) rp[i] = sd[t] - v;
  if (t == 1023) bsum[blockIdx.x] = sd[1023];
}

__global__ void k_scan2(int* __restrict__ bsum, int nb, int* __restrict__ rp, int N){
  int t = threadIdx.x;
  int orig = (t < nb) ? bsum[t] : 0;
  int v = orig;
  #pragma unroll
  for (int off = 1; off < 64; off <<= 1){
    int x = __shfl_up(v, off, WAVE);
    if (t >= off) v += x;
  }
  if (t < nb) bsum[t] = v - orig;
  if (t == 63) rp[N] = v;
}

__global__ __launch_bounds__(1024)
void k_scan3(int* __restrict__ rp, const int* __restrict__ bsum, int N){
  int i = blockIdx.x*1024 + threadIdx.x;
  if (i < N) rp[i] += bsum[blockIdx.x];
}

__global__ void k_copy_i(const int* __restrict__ a, int* __restrict__ b, int n){
  int i = blockIdx.x*blockDim.x + threadIdx.x;
  if (i < n) b[i] = a[i];
}

__global__ void k_fill(const int* __restrict__ ei, int E, int N,
                       int* __restrict__ cur, int* __restrict__ es){
  int i = blockIdx.x*blockDim.x + threadIdx.x;
  if (i >= E + N) return;
  int s, d;
  if (i < E){ s = ei[i]; d = ei[E + i]; } else { s = d = i - E; }
  int pos = atomicAdd(&cur[d], 1);
  es[pos] = s;
}

__global__ void k_bounds(const int* __restrict__ batch, int N, int B, int* __restrict__ bs){
  int b = blockIdx.x*blockDim.x + threadIdx.x;
  if (b > B) return;
  int lo = 0, hi = N;
  while (lo < hi){ int mid = (lo + hi) >> 1; if (batch[mid] < b) lo = mid + 1; else hi = mid; }
  bs[b] = lo;
}

// ---------------- f32 -> bf16 hi/lo (layer-1 input only) ----------------
__global__ __launch_bounds__(256)
void k_cvt(const float* __restrict__ in, unsigned short* __restrict__ hi,
           unsigned short* __restrict__ lo, int n4){
  int i = blockIdx.x*blockDim.x + threadIdx.x;
  if (i >= n4) return;
  float4 v = ((const float4*)in)[i];
  ushort4 h, l;
  h.x = f2b(v.x); l.x = f2b(v.x - b2f(h.x));
  h.y = f2b(v.y); l.y = f2b(v.y - b2f(h.y));
  h.z = f2b(v.z); l.z = f2b(v.z - b2f(h.z));
  h.w = f2b(v.w); l.w = f2b(v.w - b2f(h.w));
  ((ushort4*)hi)[i] = h;
  ((ushort4*)lo)[i] = l;
}

// W[K,Nc] -> W^T hi/lo [Nc,K]
__global__ __launch_bounds__(256)
void k_cvt_w(const float* __restrict__ W, unsigned short* __restrict__ th,
             unsigned short* __restrict__ tl, int K, int Nc){
  int i = blockIdx.x*blockDim.x + threadIdx.x;
  if (i >= K*Nc) return;
  int k = i / Nc, n = i - k*Nc;
  float a = W[i];
  unsigned short h = f2b(a);
  unsigned short l = f2b(a - b2f(h));
  th[(size_t)n*K + k] = h;
  tl[(size_t)n*K + k] = l;
}

// ---------------- split-bf16 MFMA GEMM (128x128 tile, 8 waves), fused alpha ----------------
// h = A@W (f32 accum via 3-term split-bf16 MFMA). Writes fp16 h only.
// Each wave: 32 rows x 64 cols (2x4 fragments of 16x16), so each wave's col
// slab lies in exactly one head (64 | CHEAD). alpha via cross-lane reduce +
// atomicAdd into zeroed as4/ad4.
template<int CHEAD>
__global__ __launch_bounds__(512)
void k_gemm_fused(const unsigned short* __restrict__ Ah, const unsigned short* __restrict__ Al,
                  const unsigned short* __restrict__ Bh, const unsigned short* __restrict__ Bl,
                  _Float16* __restrict__ Ch,
                  const float* __restrict__ asr, const float* __restrict__ adt,
                  float* __restrict__ as4, float* __restrict__ ad4,
                  int M, int K, int Nc){
  constexpr int LDP = 40;  // padded row stride (shorts): 20 dwords -> <=2-way banks (free)
  __shared__ unsigned short sAh[128*LDP], sAl[128*LDP], sBh[128*LDP], sBl[128*LDP];
  const int tid = threadIdx.x;
  const int m0 = blockIdx.x*128, n0 = blockIdx.y*128;
  const int w = tid >> 6, l = tid & 63;
  const int wr = w >> 1, wc = w & 1;          // 4M x 2N waves
  const int sr = tid >> 2, sc = (tid & 3)*8;  // staging: 128 rows x 4 thr/row x 8 shorts

  f32x4 acc00={0.f,0.f,0.f,0.f}, acc01=acc00, acc02=acc00, acc03=acc00;
  f32x4 acc10=acc00, acc11=acc00, acc12=acc00, acc13=acc00;

  const int arow = m0 + sr;
  const bool aval = arow < M;
  const size_t aoff = (size_t)arow*K + sc;
  const size_t boff = (size_t)(n0 + sr)*K + sc;

  const int fa0 = (wr*32 + (l & 15))*LDP + (l >> 4)*8;
  const int fa1 = fa0 + 16*LDP;
  const int fb0 = (wc*64 + (l & 15))*LDP + (l >> 4)*8;

  for (int k0 = 0; k0 < K; k0 += 32){
    uint4 z = make_uint4(0,0,0,0);
    uint4 va_h = z, va_l = z;
    if (aval){
      va_h = *(const uint4*)(Ah + aoff + k0);
      va_l = *(const uint4*)(Al + aoff + k0);
    }
    uint4 vb_h = *(const uint4*)(Bh + boff + k0);
    uint4 vb_l = *(const uint4*)(Bl + boff + k0);
    __syncthreads();               // previous iteration's frag reads done
    *(uint4*)&sAh[sr*LDP + sc] = va_h;
    *(uint4*)&sAl[sr*LDP + sc] = va_l;
    *(uint4*)&sBh[sr*LDP + sc] = vb_h;
    *(uint4*)&sBl[sr*LDP + sc] = vb_l;
    __syncthreads();

    short8v a_h0 = *(const short8v*)&sAh[fa0];
    short8v a_l0 = *(const short8v*)&sAl[fa0];
    short8v a_h1 = *(const short8v*)&sAh[fa1];
    short8v a_l1 = *(const short8v*)&sAl[fa1];

    short8v b_h, b_l;
    b_h = *(const short8v*)&sBh[fb0];
    b_l = *(const short8v*)&sBl[fb0];
    acc00 = __builtin_amdgcn_mfma_f32_16x16x32_bf16(a_h0, b_h, acc00, 0, 0, 0);
    acc00 = __builtin_amdgcn_mfma_f32_16x16x32_bf16(a_h0, b_l, acc00, 0, 0, 0);
    acc00 = __builtin_amdgcn_mfma_f32_16x16x32_bf16(a_l0, b_h, acc00, 0, 0, 0);
    acc10 = __builtin_amdgcn_mfma_f32_16x16x32_bf16(a_h1, b_h, acc10, 0, 0, 0);
    acc10 = __builtin_amdgcn_mfma_f32_16x16x32_bf16(a_h1, b_l, acc10, 0, 0, 0);
    acc10 = __builtin_amdgcn_mfma_f32_16x16x32_bf16(a_l1, b_h, acc10, 0, 0, 0);

    b_h = *(const short8v*)&sBh[fb0 + 16*LDP];
    b_l = *(const short8v*)&sBl[fb0 + 16*LDP];
    acc01 = __builtin_amdgcn_mfma_f32_16x16x32_bf16(a_h0, b_h, acc01, 0, 0, 0);
    acc01 = __builtin_amdgcn_mfma_f32_16x16x32_bf16(a_h0, b_l, acc01, 0, 0, 0);
    acc01 = __builtin_amdgcn_mfma_f32_16x16x32_bf16(a_l0, b_h, acc01, 0, 0, 0);
    acc11 = __builtin_amdgcn_mfma_f32_16x16x32_bf16(a_h1, b_h, acc11, 0, 0, 0);
    acc11 = __builtin_amdgcn_mfma_f32_16x16x32_bf16(a_h1, b_l, acc11, 0, 0, 0);
    acc11 = __builtin_amdgcn_mfma_f32_16x16x32_bf16(a_l1, b_h, acc11, 0, 0, 0);

    b_h = *(const short8v*)&sBh[fb0 + 32*LDP];
    b_l = *(const short8v*)&sBl[fb0 + 32*LDP];
    acc02 = __builtin_amdgcn_mfma_f32_16x16x32_bf16(a_h0, b_h, acc02, 0, 0, 0);
    acc02 = __builtin_amdgcn_mfma_f32_16x16x32_bf16(a_h0, b_l, acc02, 0, 0, 0);
    acc02 = __builtin_amdgcn_mfma_f32_16x16x32_bf16(a_l0, b_h, acc02, 0, 0, 0);
    acc12 = __builtin_amdgcn_mfma_f32_16x16x32_bf16(a_h1, b_h, acc12, 0, 0, 0);
    acc12 = __builtin_amdgcn_mfma_f32_16x16x32_bf16(a_h1, b_l, acc12, 0, 0, 0);
    acc12 = __builtin_amdgcn_mfma_f32_16x16x32_bf16(a_l1, b_h, acc12, 0, 0, 0);

    b_h = *(const short8v*)&sBh[fb0 + 48*LDP];
    b_l = *(const short8v*)&sBl[fb0 + 48*LDP];
    acc03 = __builtin_amdgcn_mfma_f32_16x16x32_bf16(a_h0, b_h, acc03, 0, 0, 0);
    acc03 = __builtin_amdgcn_mfma_f32_16x16x32_bf16(a_h0, b_l, acc03, 0, 0, 0);
    acc03 = __builtin_amdgcn_mfma_f32_16x16x32_bf16(a_l0, b_h, acc03, 0, 0, 0);
    acc13 = __builtin_amdgcn_mfma_f32_16x16x32_bf16(a_h1, b_h, acc13, 0, 0, 0);
    acc13 = __builtin_amdgcn_mfma_f32_16x16x32_bf16(a_h1, b_l, acc13, 0, 0, 0);
    acc13 = __builtin_amdgcn_mfma_f32_16x16x32_bf16(a_l1, b_h, acc13, 0, 0, 0);
  }

  // C/D layout per 16x16 frag: col = lane&15, row = (lane>>4)*4 + j
  const int colb = n0 + wc*64 + (l & 15);
  const int hy = (n0 + wc*64) / CHEAD;
  const float ca0 = asr[colb], ca1 = asr[colb+16], ca2 = asr[colb+32], ca3 = asr[colb+48];
  const float cd0 = adt[colb], cd1 = adt[colb+16], cd2 = adt[colb+32], cd3 = adt[colb+48];

  // m = 0 fragment rows
  {
    const int rb = m0 + wr*32 + (l >> 4)*4;
    #pragma unroll
    for (int j = 0; j < 4; ++j){
      int row = rb + j;
      if (row < M){
        _Float16* hp = Ch + (size_t)row*Nc + colb;
        hp[0]  = (_Float16)acc00[j];
        hp[16] = (_Float16)acc01[j];
        hp[32] = (_Float16)acc02[j];
        hp[48] = (_Float16)acc03[j];
      }
      float ps = ca0*acc00[j] + ca1*acc01[j] + ca2*acc02[j] + ca3*acc03[j];
      float pd = cd0*acc00[j] + cd1*acc01[j] + cd2*acc02[j] + cd3*acc03[j];
      ps += __shfl_xor(ps, 1, WAVE);  pd += __shfl_xor(pd, 1, WAVE);
      ps += __shfl_xor(ps, 2, WAVE);  pd += __shfl_xor(pd, 2, WAVE);
      ps += __shfl_xor(ps, 4, WAVE);  pd += __shfl_xor(pd, 4, WAVE);
      ps += __shfl_xor(ps, 8, WAVE);  pd += __shfl_xor(pd, 8, WAVE);
      if ((l & 15) == 0 && row < M){
        atomicAdd(&as4[(size_t)row*4 + hy], ps);
        atomicAdd(&ad4[(size_t)row*4 + hy], pd);
      }
    }
  }
  // m = 1 fragment rows
  {
    const int rb = m0 + wr*32 + 16 + (l >> 4)*4;
    #pragma unroll
    for (int j = 0; j < 4; ++j){
      int row = rb + j;
      if (row < M){
        _Float16* hp = Ch + (size_t)row*Nc + colb;
        hp[0]  = (_Float16)acc10[j];
        hp[16] = (_Float16)acc11[j];
        hp[32] = (_Float16)acc12[j];
        hp[48] = (_Float16)acc13[j];
      }
      float ps = ca0*acc10[j] + ca1*acc11[j] + ca2*acc12[j] + ca3*acc13[j];
      float pd = cd0*acc10[j] + cd1*acc11[j] + cd2*acc12[j] + cd3*acc13[j];
      ps += __shfl_xor(ps, 1, WAVE);  pd += __shfl_xor(pd, 1, WAVE);
      ps += __shfl_xor(ps, 2, WAVE);  pd += __shfl_xor(pd, 2, WAVE);
      ps += __shfl_xor(ps, 4, WAVE);  pd += __shfl_xor(pd, 4, WAVE);
      ps += __shfl_xor(ps, 8, WAVE);  pd += __shfl_xor(pd, 8, WAVE);
      if ((l & 15) == 0 && row < M){
        atomicAdd(&as4[(size_t)row*4 + hy], ps);
        atomicAdd(&ad4[(size_t)row*4 + hy], pd);
      }
    }
  }
}

// ---------------- fp16-gather agg (all layers) ----------------
// WF32=1: write f32 elu(out) (final layer, feeds pooling)
// WF32=0: write bf16 hi/lo split of elu(out) (feeds next GEMM)
template<int HC, int WF32>
__global__ __launch_bounds__(256)
void k_agg_h(const int* __restrict__ rp, const int* __restrict__ es,
             const float* __restrict__ as4, const float* __restrict__ ad4,
             const _Float16* __restrict__ h, const float* __restrict__ bias,
             float* __restrict__ outF,
             unsigned short* __restrict__ oAh, unsigned short* __restrict__ oAl, int N){
  constexpr int VEC = HC / 64;           // halves per lane (4 or 8)
  int wid  = (blockIdx.x*blockDim.x + threadIdx.x) >> 6;
  int lane = threadIdx.x & 63;
  if (wid >= N) return;
  int beg = rp[wid], end = rp[wid+1];

  const float4 adv = *(const float4*)(ad4 + (size_t)wid*4);
  const float ad0 = adv.x, ad1 = adv.y, ad2 = adv.z, ad3 = adv.w;

  float m0=-1e30f, m1=-1e30f, m2=-1e30f, m3=-1e30f;
  float s0=0.f, s1=0.f, s2=0.f, s3=0.f;
  for (int i = beg + lane; i < end; i += WAVE){
    int s = es[i];
    const float4 av = *(const float4*)(as4 + (size_t)s*4);
    float e, mn;
    e = av.x + ad0; e = (e >= 0.f) ? e : 0.2f*e;
    mn = fmaxf(m0, e); s0 = s0*__expf(m0-mn) + __expf(e-mn); m0 = mn;
    e = av.y + ad1; e = (e >= 0.f) ? e : 0.2f*e;
    mn = fmaxf(m1, e); s1 = s1*__expf(m1-mn) + __expf(e-mn); m1 = mn;
    e = av.z + ad2; e = (e >= 0.f) ? e : 0.2f*e;
    mn = fmaxf(m2, e); s2 = s2*__expf(m2-mn) + __expf(e-mn); m2 = mn;
    e = av.w + ad3; e = (e >= 0.f) ? e : 0.2f*e;
    mn = fmaxf(m3, e); s3 = s3*__expf(m3-mn) + __expf(e-mn); m3 = mn;
  }
  #pragma unroll
  for (int off = 32; off > 0; off >>= 1){
    float mo, so, mn;
    mo = __shfl_xor(m0, off, WAVE); so = __shfl_xor(s0, off, WAVE);
    mn = fmaxf(m0, mo); s0 = s0*__expf(m0-mn) + so*__expf(mo-mn); m0 = mn;
    mo = __shfl_xor(m1, off, WAVE); so = __shfl_xor(s1, off, WAVE);
    mn = fmaxf(m1, mo); s1 = s1*__expf(m1-mn) + so*__expf(mo-mn); m1 = mn;
    mo = __shfl_xor(m2, off, WAVE); so = __shfl_xor(s2, off, WAVE);
    mn = fmaxf(m2, mo); s2 = s2*__expf(m2-mn) + so*__expf(mo-mn); m2 = mn;
    mo = __shfl_xor(m3, off, WAVE); so = __shfl_xor(s3, off, WAVE);
    mn = fmaxf(m3, mo); s3 = s3*__expf(m3-mn) + so*__expf(mo-mn); m3 = mn;
  }
  const float i0 = 1.f/(s0 + 1e-16f), i1 = 1.f/(s1 + 1e-16f);
  const float i2 = 1.f/(s2 + 1e-16f), i3 = 1.f/(s3 + 1e-16f);
  const int myh = lane >> 4;

  float ac[VEC] = {};

  for (int cb = beg; cb < end; cb += WAVE){
    int nn = min(WAVE, end - cb);
    int sidx = 0;
    float w0 = 0.f, w1 = 0.f, w2 = 0.f, w3 = 0.f;
    if (cb + lane < end){
      sidx = es[cb + lane];
      const float4 av = *(const float4*)(as4 + (size_t)sidx*4);
      float e;
      e = av.x + ad0; e = (e >= 0.f) ? e : 0.2f*e; w0 = __expf(e - m0)*i0;
      e = av.y + ad1; e = (e >= 0.f) ? e : 0.2f*e; w1 = __expf(e - m1)*i1;
      e = av.z + ad2; e = (e >= 0.f) ? e : 0.2f*e; w2 = __expf(e - m2)*i2;
      e = av.w + ad3; e = (e >= 0.f) ? e : 0.2f*e; w3 = __expf(e - m3)*i3;
    }

    int j = 0;
    for (; j + 4 <= nn; j += 4){
      int sj0 = __shfl(sidx, j+0, WAVE), sj1 = __shfl(sidx, j+1, WAVE);
      int sj2 = __shfl(sidx, j+2, WAVE), sj3 = __shfl(sidx, j+3, WAVE);
      float u0 = selh(__shfl(w0,j+0,WAVE), __shfl(w1,j+0,WAVE), __shfl(w2,j+0,WAVE), __shfl(w3,j+0,WAVE), myh);
      float u1 = selh(__shfl(w0,j+1,WAVE), __shfl(w1,j+1,WAVE), __shfl(w2,j+1,WAVE), __shfl(w3,j+1,WAVE), myh);
      float u2 = selh(__shfl(w0,j+2,WAVE), __shfl(w1,j+2,WAVE), __shfl(w2,j+2,WAVE), __shfl(w3,j+2,WAVE), myh);
      float u3 = selh(__shfl(w0,j+3,WAVE), __shfl(w1,j+3,WAVE), __shfl(w2,j+3,WAVE), __shfl(w3,j+3,WAVE), myh);
      if (VEC == 4){
        h16x4 v0 = *(const h16x4*)(h + (size_t)sj0*HC + lane*4);
        h16x4 v1 = *(const h16x4*)(h + (size_t)sj1*HC + lane*4);
        h16x4 v2 = *(const h16x4*)(h + (size_t)sj2*HC + lane*4);
        h16x4 v3 = *(const h16x4*)(h + (size_t)sj3*HC + lane*4);
        #pragma unroll
        for (int c = 0; c < 4; ++c)
          ac[c] = fmaf(u0,(float)v0[c], fmaf(u1,(float)v1[c], fmaf(u2,(float)v2[c], fmaf(u3,(float)v3[c], ac[c]))));
      } else {
        h16x8 v0 = *(const h16x8*)(h + (size_t)sj0*HC + lane*8);
        h16x8 v1 = *(const h16x8*)(h + (size_t)sj1*HC + lane*8);
        h16x8 v2 = *(const h16x8*)(h + (size_t)sj2*HC + lane*8);
        h16x8 v3 = *(const h16x8*)(h + (size_t)sj3*HC + lane*8);
        #pragma unroll
        for (int c = 0; c < VEC; ++c)
          ac[c] = fmaf(u0,(float)v0[c], fmaf(u1,(float)v1[c], fmaf(u2,(float)v2[c], fmaf(u3,(float)v3[c], ac[c]))));
      }
    }
    for (; j < nn; ++j){
      int sj = __shfl(sidx, j, WAVE);
      float u = selh(__shfl(w0,j,WAVE), __shfl(w1,j,WAVE), __shfl(w2,j,WAVE), __shfl(w3,j,WAVE), myh);
      if (VEC == 4){
        h16x4 v = *(const h16x4*)(h + (size_t)sj*HC + lane*4);
        #pragma unroll
        for (int c = 0; c < 4; ++c) ac[c] = fmaf(u, (float)v[c], ac[c]);
      } else {
        h16x8 v = *(const h16x8*)(h + (size_t)sj*HC + lane*8);
        #pragma unroll
        for (int c = 0; c < VEC; ++c) ac[c] = fmaf(u, (float)v[c], ac[c]);
      }
    }
  }

  float r0=0,r1=0,r2=0,r3=0,r4=0,r5=0,r6=0,r7=0;
  {
    const float* bp = bias + lane*VEC;
    #pragma unroll
    for (int c = 0; c < VEC; ++c){
      float r = ac[c] + bp[c];
      r = r > 0.f ? r : expm1f(r);
      if (c==0) r0=r; else if (c==1) r1=r; else if (c==2) r2=r; else if (c==3) r3=r;
      else if (c==4) r4=r; else if (c==5) r5=r; else if (c==6) r6=r; else r7=r;
    }
  }
  if (WF32){
    float* op = outF + (size_t)wid*HC + lane*VEC;
    *(float4*)op = make_float4(r0,r1,r2,r3);
    if (VEC == 8) *(float4*)(op+4) = make_float4(r4,r5,r6,r7);
  } else {
    ushort4 H, L;
    H.x = f2b(r0); L.x = f2b(r0 - b2f(H.x));
    H.y = f2b(r1); L.y = f2b(r1 - b2f(H.y));
    H.z = f2b(r2); L.z = f2b(r2 - b2f(H.z));
    H.w = f2b(r3); L.w = f2b(r3 - b2f(H.w));
    *(ushort4*)(oAh + (size_t)wid*HC + lane*VEC) = H;
    *(ushort4*)(oAl + (size_t)wid*HC + lane*VEC) = L;
    if (VEC == 8){
      ushort4 H2, L2;
      H2.x = f2b(r4); L2.x = f2b(r4 - b2f(H2.x));
      H2.y = f2b(r5); L2.y = f2b(r5 - b2f(H2.y));
      H2.z = f2b(r6); L2.z = f2b(r6 - b2f(H2.z));
      H2.w = f2b(r7); L2.w = f2b(r7 - b2f(H2.w));
      *(ushort4*)(oAh + (size_t)wid*HC + lane*VEC + 4) = H2;
      *(ushort4*)(oAl + (size_t)wid*HC + lane*VEC + 4) = L2;
    }
  }
}

// ---------------- pooling + FC ----------------
__global__ void k_pool_partial(const float* __restrict__ h, const int* __restrict__ bs,
                               float* __restrict__ psum, float* __restrict__ pmax){
  int b = blockIdx.x, ch = blockIdx.y;
  int f = threadIdx.x;
  int s = bs[b], e = bs[b+1];
  long long len = e - s;
  int i0 = s + (int)(len * ch / 8);
  int i1 = s + (int)(len * (ch+1) / 8);
  float sm = 0.f, mx = -3.0e38f;
  for (int i = i0; i < i1; ++i){
    float v = h[(size_t)i*512 + f];
    sm += v; mx = fmaxf(mx, v);
  }
  int idx = (b*8 + ch)*512 + f;
  psum[idx] = sm; pmax[idx] = mx;
}

__global__ void k_pool_final(const float* __restrict__ psum, const float* __restrict__ pmax,
                             const int* __restrict__ bs, float* __restrict__ g){
  int b = blockIdx.x, f = threadIdx.x;
  float sm = 0.f, mx = -3.0e38f;
  for (int c = 0; c < 8; ++c){
    int idx = (b*8 + c)*512 + f;
    sm += psum[idx]; mx = fmaxf(mx, pmax[idx]);
  }
  int cnt = bs[b+1] - bs[b];
  g[b*1024 + f] = sm / fmaxf((float)cnt, 1.f);
  g[b*1024 + 512 + f] = (mx > -1e37f) ? mx : 0.f;
}

__global__ __launch_bounds__(256)
void k_fc(const float* __restrict__ g, const float* __restrict__ fcW,
          const float* __restrict__ fcb, float* __restrict__ out){
  __shared__ float gs[1024];
  __shared__ float red[4][64];
  int b = blockIdx.x, t = threadIdx.x;
  int o0 = blockIdx.y * 64;
  for (int i = t; i < 1024; i += 256) gs[i] = g[b*1024 + i];
  __syncthreads();
  int ol = t & 63, q = t >> 6;
  const float* wp = fcW + (size_t)(q*256)*512 + o0 + ol;
  float acc = 0.f;
  #pragma unroll 8
  for (int k = 0; k < 256; ++k)
    acc = fmaf(gs[q*256 + k], wp[(size_t)k*512], acc);
  red[q][ol] = acc;
  __syncthreads();
  if (t < 64){
    float r = red[0][t] + red[1][t] + red[2][t] + red[3][t] + fcb[o0 + t];
    out[b*512 + o0 + t] = r;
  }
}

// ---------------- launcher ----------------
extern "C" void kernel_launch(void* const* d_in, const int* in_sizes, int n_in,
                              void* d_out, int out_size, void* d_ws, size_t ws_size,
                              hipStream_t stream){
  (void)n_in; (void)out_size; (void)ws_size;
  const float* x     = (const float*)d_in[0];
  const int*   ei    = (const int*)d_in[1];
  const int*   batch = (const int*)d_in[2];
  const float* W[4]   = {(const float*)d_in[3],(const float*)d_in[7],(const float*)d_in[11],(const float*)d_in[15]};
  const float* asr[4] = {(const float*)d_in[4],(const float*)d_in[8],(const float*)d_in[12],(const float*)d_in[16]};
  const float* adt[4] = {(const float*)d_in[5],(const float*)d_in[9],(const float*)d_in[13],(const float*)d_in[17]};
  const float* bb[4]  = {(const float*)d_in[6],(const float*)d_in[10],(const float*)d_in[14],(const float*)d_in[18]};
  const float* fcW = (const float*)d_in[19];
  const float* fcb = (const float*)d_in[20];

  const int N  = in_sizes[0] / 128;
  const int E  = in_sizes[1] / 2;
  const int EN = E + N;
  const int B  = 32;
  const int NB = (N + 1023) / 1024;

  char* p = (char*)d_ws;
  auto alloc = [&](size_t bytes){ void* r = (void*)p; p += (bytes + 255) & ~(size_t)255; return r; };
  float* bufA = (float*)alloc((size_t)N*512*4);            // final f32 h (pooling input)
  _Float16* bufH = (_Float16*)alloc((size_t)N*512*2);      // GEMM fp16 out (gather input)
  unsigned short* Ah = (unsigned short*)alloc((size_t)N*256*2);
  unsigned short* Al = (unsigned short*)alloc((size_t)N*256*2);
  unsigned short* Wh = (unsigned short*)alloc((size_t)512*256*2);
  unsigned short* Wl = (unsigned short*)alloc((size_t)512*256*2);
  float* a2   = (float*)alloc((size_t)N*8*4);              // as4 | ad4
  float* as4 = a2;
  float* ad4 = a2 + (size_t)N*4;
  int*   cnt  = (int*)alloc((size_t)N*4);
  int*   rp   = (int*)alloc((size_t)(N+1)*4);
  int*   cur  = (int*)alloc((size_t)N*4);
  int*   es   = (int*)alloc((size_t)EN*4);
  int*   bs   = (int*)alloc((size_t)(B+1)*4);
  int*   bsum = (int*)alloc((size_t)64*4);
  float* gpo  = (float*)alloc((size_t)B*1024*4);
  float* psum = (float*)alloc((size_t)B*8*512*4);
  float* pmax = (float*)alloc((size_t)B*8*512*4);

  // CSR build
  k_zero_i<<<(N+255)/256, 256, 0, stream>>>(cnt, N);
  k_count<<<(EN+255)/256, 256, 0, stream>>>(ei, E, N, cnt);
  k_scan1<<<NB, 1024, 0, stream>>>(cnt, rp, bsum, N);
  k_scan2<<<1, 64, 0, stream>>>(bsum, NB, rp, N);
  k_scan3<<<NB, 1024, 0, stream>>>(rp, bsum, N);
  k_copy_i<<<(N+255)/256, 256, 0, stream>>>(rp, cur, N);
  k_fill<<<(EN+255)/256, 256, 0, stream>>>(ei, E, N, cur, es);
  k_bounds<<<1, 64, 0, stream>>>(batch, N, B, bs);

  const int wgrid = (N + 3) / 4;

  // layer-1 input -> bf16 split
  k_cvt<<<((N*128/4) + 255)/256, 256, 0, stream>>>(x, Ah, Al, N*128/4);

  const int Kd[4]  = {128, 256, 256, 256};
  const int HCd[4] = {256, 256, 256, 512};

  for (int L = 0; L < 4; ++L){
    const int K = Kd[L], Nc = HCd[L];
    k_zero_f<<<(N*8 + 255)/256, 256, 0, stream>>>(a2, N*8);
    k_cvt_w<<<(K*Nc + 255)/256, 256, 0, stream>>>(W[L], Wh, Wl, K, Nc);
    dim3 gg((N + 127)/128, Nc/128);
    if (Nc == 256)
      k_gemm_fused<64><<<gg, 512, 0, stream>>>(Ah, Al, Wh, Wl, bufH, asr[L], adt[L], as4, ad4, N, K, Nc);
    else
      k_gemm_fused<128><<<gg, 512, 0, stream>>>(Ah, Al, Wh, Wl, bufH, asr[L], adt[L], as4, ad4, N, K, Nc);
    if (L < 3)
      k_agg_h<256,0><<<wgrid, 256, 0, stream>>>(rp, es, as4, ad4, bufH, bb[L], (float*)nullptr, Ah, Al, N);
    else
      k_agg_h<512,1><<<wgrid, 256, 0, stream>>>(rp, es, as4, ad4, bufH, bb[L], bufA, (unsigned short*)nullptr, (unsigned short*)nullptr, N);
  }

  dim3 pg(B, 8);
  k_pool_partial<<<pg, 512, 0, stream>>>(bufA, bs, psum, pmax);
  k_pool_final<<<B, 512, 0, stream>>>(psum, pmax, bs, gpo);
  dim3 fg(B, 8);
  k_fc<<<fg, 256, 0, stream>>>(gpo, fcW, fcb, (float*)d_out);
}

// Round 7
// 490.796 us; speedup vs baseline: 1.9462x; 1.0382x over previous
//
#include <hip/hip_runtime.h>
#include <math.h>

#define WAVE 64

typedef __attribute__((ext_vector_type(4))) float f32x4;
typedef _Float16 h16x4 __attribute__((ext_vector_type(4)));
typedef _Float16 h16x8 __attribute__((ext_vector_type(8)));

__device__ __forceinline__ float selh(float e0, float e1, float e2, float e3, int m){
  float r = (m == 1) ? e1 : e0;
  r = (m == 2) ? e2 : r;
  r = (m == 3) ? e3 : r;
  return r;
}

// ---------------- CSR build ----------------
__global__ void k_zero_i(int* p, int n){
  int i = blockIdx.x*blockDim.x + threadIdx.x;
  if (i < n) p[i] = 0;
}

__global__ void k_zero_f(float* p, int n){
  int i = blockIdx.x*blockDim.x + threadIdx.x;
  if (i < n) p[i] = 0.f;
}

__global__ void k_count(const int* __restrict__ ei, int E, int N, int* __restrict__ cnt){
  int i = blockIdx.x*blockDim.x + threadIdx.x;
  if (i >= E + N) return;
  int d = (i < E) ? ei[E + i] : (i - E);
  atomicAdd(&cnt[d], 1);
}

__global__ __launch_bounds__(1024)
void k_scan1(const int* __restrict__ cnt, int* __restrict__ rp, int* __restrict__ bsum, int N){
  __shared__ int sd[1024];
  int t = threadIdx.x, i = blockIdx.x*1024 + t;
  int v = (i < N) ? cnt[i] : 0;
  sd[t] = v;
  __syncthreads();
  for (int off = 1; off < 1024; off <<= 1){
    int x = (t >= off) ? sd[t-off] : 0;
    __syncthreads();
    sd[t] += x;
    __syncthreads();
  }
  if (i < N) rp[i] = sd[t] - v;
  if (t == 1023) bsum[blockIdx.x] = sd[1023];
}

__global__ void k_scan2(int* __restrict__ bsum, int nb, int* __restrict__ rp, int N){
  int t = threadIdx.x;
  int orig = (t < nb) ? bsum[t] : 0;
  int v = orig;
  #pragma unroll
  for (int off = 1; off < 64; off <<= 1){
    int x = __shfl_up(v, off, WAVE);
    if (t >= off) v += x;
  }
  if (t < nb) bsum[t] = v - orig;
  if (t == 63) rp[N] = v;
}

__global__ __launch_bounds__(1024)
void k_scan3(int* __restrict__ rp, const int* __restrict__ bsum, int N){
  int i = blockIdx.x*1024 + threadIdx.x;
  if (i < N) rp[i] += bsum[blockIdx.x];
}

__global__ void k_copy_i(const int* __restrict__ a, int* __restrict__ b, int n){
  int i = blockIdx.x*blockDim.x + threadIdx.x;
  if (i < n) b[i] = a[i];
}

__global__ void k_fill(const int* __restrict__ ei, int E, int N,
                       int* __restrict__ cur, int* __restrict__ es){
  int i = blockIdx.x*blockDim.x + threadIdx.x;
  if (i >= E + N) return;
  int s, d;
  if (i < E){ s = ei[i]; d = ei[E + i]; } else { s = d = i - E; }
  int pos = atomicAdd(&cur[d], 1);
  es[pos] = s;
}

__global__ void k_bounds(const int* __restrict__ batch, int N, int B, int* __restrict__ bs){
  int b = blockIdx.x*blockDim.x + threadIdx.x;
  if (b > B) return;
  int lo = 0, hi = N;
  while (lo < hi){ int mid = (lo + hi) >> 1; if (batch[mid] < b) lo = mid + 1; else hi = mid; }
  bs[b] = lo;
}

// ---------------- f32 -> f16 (layer-1 input) ----------------
__global__ __launch_bounds__(256)
void k_cvt16(const float* __restrict__ in, _Float16* __restrict__ out, int n4){
  int i = blockIdx.x*blockDim.x + threadIdx.x;
  if (i >= n4) return;
  float4 v = ((const float4*)in)[i];
  h16x4 o;
  o[0] = (_Float16)v.x; o[1] = (_Float16)v.y;
  o[2] = (_Float16)v.z; o[3] = (_Float16)v.w;
  ((h16x4*)out)[i] = o;
}

// W[K,Nc] f32 -> W^T f16 [Nc,K]
__global__ __launch_bounds__(256)
void k_cvt_w16(const float* __restrict__ W, _Float16* __restrict__ wt, int K, int Nc){
  int i = blockIdx.x*blockDim.x + threadIdx.x;
  if (i >= K*Nc) return;
  int k = i / Nc, n = i - k*Nc;
  wt[(size_t)n*K + k] = (_Float16)W[i];
}

// ---------------- fp16 MFMA GEMM (128x128 tile, 8 waves), fused alpha ----------------
// h = A@W via mfma_f32_16x16x32_f16 (f32 accum). A f16 [M,K]; W^T f16 [Nc,K].
// Writes fp16 h. Each wave: 32 rows x 64 cols (2x4 16x16 frags); each wave's
// 64-col slab lies in one head (64 | CHEAD). alpha from f32 accumulators ->
// cross-lane reduce -> atomicAdd into zeroed as4/ad4.
template<int CHEAD>
__global__ __launch_bounds__(512)
void k_gemm_fused(const _Float16* __restrict__ Ax, const _Float16* __restrict__ Bw,
                  _Float16* __restrict__ Ch,
                  const float* __restrict__ asr, const float* __restrict__ adt,
                  float* __restrict__ as4, float* __restrict__ ad4,
                  int M, int K, int Nc){
  constexpr int LDP = 40;  // padded row stride (halves): 80 B -> <=2-way banks (free)
  __shared__ _Float16 sA[128*LDP], sB[128*LDP];
  const int tid = threadIdx.x;
  const int m0 = blockIdx.x*128, n0 = blockIdx.y*128;
  const int w = tid >> 6, l = tid & 63;
  const int wr = w >> 1, wc = w & 1;          // 4M x 2N waves
  const int sr = tid >> 2, sc = (tid & 3)*8;  // staging: 128 rows x 4 thr/row x 8 halves

  f32x4 acc00={0.f,0.f,0.f,0.f}, acc01=acc00, acc02=acc00, acc03=acc00;
  f32x4 acc10=acc00, acc11=acc00, acc12=acc00, acc13=acc00;

  const int arow = m0 + sr;
  const bool aval = arow < M;
  const size_t aoff = (size_t)arow*K + sc;
  const size_t boff = (size_t)(n0 + sr)*K + sc;

  const int fa0 = (wr*32 + (l & 15))*LDP + (l >> 4)*8;
  const int fa1 = fa0 + 16*LDP;
  const int fb0 = (wc*64 + (l & 15))*LDP + (l >> 4)*8;

  for (int k0 = 0; k0 < K; k0 += 32){
    uint4 va = make_uint4(0,0,0,0);
    if (aval) va = *(const uint4*)(Ax + aoff + k0);
    uint4 vb = *(const uint4*)(Bw + boff + k0);
    __syncthreads();               // previous iteration's frag reads done
    *(uint4*)&sA[sr*LDP + sc] = va;
    *(uint4*)&sB[sr*LDP + sc] = vb;
    __syncthreads();

    h16x8 a0 = *(const h16x8*)&sA[fa0];
    h16x8 a1 = *(const h16x8*)&sA[fa1];

    h16x8 b;
    b = *(const h16x8*)&sB[fb0];
    acc00 = __builtin_amdgcn_mfma_f32_16x16x32_f16(a0, b, acc00, 0, 0, 0);
    acc10 = __builtin_amdgcn_mfma_f32_16x16x32_f16(a1, b, acc10, 0, 0, 0);
    b = *(const h16x8*)&sB[fb0 + 16*LDP];
    acc01 = __builtin_amdgcn_mfma_f32_16x16x32_f16(a0, b, acc01, 0, 0, 0);
    acc11 = __builtin_amdgcn_mfma_f32_16x16x32_f16(a1, b, acc11, 0, 0, 0);
    b = *(const h16x8*)&sB[fb0 + 32*LDP];
    acc02 = __builtin_amdgcn_mfma_f32_16x16x32_f16(a0, b, acc02, 0, 0, 0);
    acc12 = __builtin_amdgcn_mfma_f32_16x16x32_f16(a1, b, acc12, 0, 0, 0);
    b = *(const h16x8*)&sB[fb0 + 48*LDP];
    acc03 = __builtin_amdgcn_mfma_f32_16x16x32_f16(a0, b, acc03, 0, 0, 0);
    acc13 = __builtin_amdgcn_mfma_f32_16x16x32_f16(a1, b, acc13, 0, 0, 0);
  }

  // C/D layout per 16x16 frag: col = lane&15, row = (lane>>4)*4 + j
  const int colb = n0 + wc*64 + (l & 15);
  const int hy = (n0 + wc*64) / CHEAD;
  const float ca0 = asr[colb], ca1 = asr[colb+16], ca2 = asr[colb+32], ca3 = asr[colb+48];
  const float cd0 = adt[colb], cd1 = adt[colb+16], cd2 = adt[colb+32], cd3 = adt[colb+48];

  // m = 0 fragment rows
  {
    const int rb = m0 + wr*32 + (l >> 4)*4;
    #pragma unroll
    for (int j = 0; j < 4; ++j){
      int row = rb + j;
      if (row < M){
        _Float16* hp = Ch + (size_t)row*Nc + colb;
        hp[0]  = (_Float16)acc00[j];
        hp[16] = (_Float16)acc01[j];
        hp[32] = (_Float16)acc02[j];
        hp[48] = (_Float16)acc03[j];
      }
      float ps = ca0*acc00[j] + ca1*acc01[j] + ca2*acc02[j] + ca3*acc03[j];
      float pd = cd0*acc00[j] + cd1*acc01[j] + cd2*acc02[j] + cd3*acc03[j];
      ps += __shfl_xor(ps, 1, WAVE);  pd += __shfl_xor(pd, 1, WAVE);
      ps += __shfl_xor(ps, 2, WAVE);  pd += __shfl_xor(pd, 2, WAVE);
      ps += __shfl_xor(ps, 4, WAVE);  pd += __shfl_xor(pd, 4, WAVE);
      ps += __shfl_xor(ps, 8, WAVE);  pd += __shfl_xor(pd, 8, WAVE);
      if ((l & 15) == 0 && row < M){
        atomicAdd(&as4[(size_t)row*4 + hy], ps);
        atomicAdd(&ad4[(size_t)row*4 + hy], pd);
      }
    }
  }
  // m = 1 fragment rows
  {
    const int rb = m0 + wr*32 + 16 + (l >> 4)*4;
    #pragma unroll
    for (int j = 0; j < 4; ++j){
      int row = rb + j;
      if (row < M){
        _Float16* hp = Ch + (size_t)row*Nc + colb;
        hp[0]  = (_Float16)acc10[j];
        hp[16] = (_Float16)acc11[j];
        hp[32] = (_Float16)acc12[j];
        hp[48] = (_Float16)acc13[j];
      }
      float ps = ca0*acc10[j] + ca1*acc11[j] + ca2*acc12[j] + ca3*acc13[j];
      float pd = cd0*acc10[j] + cd1*acc11[j] + cd2*acc12[j] + cd3*acc13[j];
      ps += __shfl_xor(ps, 1, WAVE);  pd += __shfl_xor(pd, 1, WAVE);
      ps += __shfl_xor(ps, 2, WAVE);  pd += __shfl_xor(pd, 2, WAVE);
      ps += __shfl_xor(ps, 4, WAVE);  pd += __shfl_xor(pd, 4, WAVE);
      ps += __shfl_xor(ps, 8, WAVE);  pd += __shfl_xor(pd, 8, WAVE);
      if ((l & 15) == 0 && row < M){
        atomicAdd(&as4[(size_t)row*4 + hy], ps);
        atomicAdd(&ad4[(size_t)row*4 + hy], pd);
      }
    }
  }
}

// ---------------- fp16-gather agg (all layers) ----------------
// WF32=1: write f32 elu(out) (final layer, feeds pooling)
// WF32=0: write f16 elu(out) (feeds next GEMM)
template<int HC, int WF32>
__global__ __launch_bounds__(256)
void k_agg_h(const int* __restrict__ rp, const int* __restrict__ es,
             const float* __restrict__ as4, const float* __restrict__ ad4,
             const _Float16* __restrict__ h, const float* __restrict__ bias,
             float* __restrict__ outF, _Float16* __restrict__ oH, int N){
  constexpr int VEC = HC / 64;           // halves per lane (4 or 8)
  int wid  = (blockIdx.x*blockDim.x + threadIdx.x) >> 6;
  int lane = threadIdx.x & 63;
  if (wid >= N) return;
  int beg = rp[wid], end = rp[wid+1];

  const float4 adv = *(const float4*)(ad4 + (size_t)wid*4);
  const float ad0 = adv.x, ad1 = adv.y, ad2 = adv.z, ad3 = adv.w;

  float m0=-1e30f, m1=-1e30f, m2=-1e30f, m3=-1e30f;
  float s0=0.f, s1=0.f, s2=0.f, s3=0.f;
  for (int i = beg + lane; i < end; i += WAVE){
    int s = es[i];
    const float4 av = *(const float4*)(as4 + (size_t)s*4);
    float e, mn;
    e = av.x + ad0; e = (e >= 0.f) ? e : 0.2f*e;
    mn = fmaxf(m0, e); s0 = s0*__expf(m0-mn) + __expf(e-mn); m0 = mn;
    e = av.y + ad1; e = (e >= 0.f) ? e : 0.2f*e;
    mn = fmaxf(m1, e); s1 = s1*__expf(m1-mn) + __expf(e-mn); m1 = mn;
    e = av.z + ad2; e = (e >= 0.f) ? e : 0.2f*e;
    mn = fmaxf(m2, e); s2 = s2*__expf(m2-mn) + __expf(e-mn); m2 = mn;
    e = av.w + ad3; e = (e >= 0.f) ? e : 0.2f*e;
    mn = fmaxf(m3, e); s3 = s3*__expf(m3-mn) + __expf(e-mn); m3 = mn;
  }
  #pragma unroll
  for (int off = 32; off > 0; off >>= 1){
    float mo, so, mn;
    mo = __shfl_xor(m0, off, WAVE); so = __shfl_xor(s0, off, WAVE);
    mn = fmaxf(m0, mo); s0 = s0*__expf(m0-mn) + so*__expf(mo-mn); m0 = mn;
    mo = __shfl_xor(m1, off, WAVE); so = __shfl_xor(s1, off, WAVE);
    mn = fmaxf(m1, mo); s1 = s1*__expf(m1-mn) + so*__expf(mo-mn); m1 = mn;
    mo = __shfl_xor(m2, off, WAVE); so = __shfl_xor(s2, off, WAVE);
    mn = fmaxf(m2, mo); s2 = s2*__expf(m2-mn) + so*__expf(mo-mn); m2 = mn;
    mo = __shfl_xor(m3, off, WAVE); so = __shfl_xor(s3, off, WAVE);
    mn = fmaxf(m3, mo); s3 = s3*__expf(m3-mn) + so*__expf(mo-mn); m3 = mn;
  }
  const float i0 = 1.f/(s0 + 1e-16f), i1 = 1.f/(s1 + 1e-16f);
  const float i2 = 1.f/(s2 + 1e-16f), i3 = 1.f/(s3 + 1e-16f);
  const int myh = lane >> 4;

  float ac[VEC] = {};

  for (int cb = beg; cb < end; cb += WAVE){
    int nn = min(WAVE, end - cb);
    int sidx = 0;
    float w0 = 0.f, w1 = 0.f, w2 = 0.f, w3 = 0.f;
    if (cb + lane < end){
      sidx = es[cb + lane];
      const float4 av = *(const float4*)(as4 + (size_t)sidx*4);
      float e;
      e = av.x + ad0; e = (e >= 0.f) ? e : 0.2f*e; w0 = __expf(e - m0)*i0;
      e = av.y + ad1; e = (e >= 0.f) ? e : 0.2f*e; w1 = __expf(e - m1)*i1;
      e = av.z + ad2; e = (e >= 0.f) ? e : 0.2f*e; w2 = __expf(e - m2)*i2;
      e = av.w + ad3; e = (e >= 0.f) ? e : 0.2f*e; w3 = __expf(e - m3)*i3;
    }

    int j = 0;
    for (; j + 4 <= nn; j += 4){
      int sj0 = __shfl(sidx, j+0, WAVE), sj1 = __shfl(sidx, j+1, WAVE);
      int sj2 = __shfl(sidx, j+2, WAVE), sj3 = __shfl(sidx, j+3, WAVE);
      float u0 = selh(__shfl(w0,j+0,WAVE), __shfl(w1,j+0,WAVE), __shfl(w2,j+0,WAVE), __shfl(w3,j+0,WAVE), myh);
      float u1 = selh(__shfl(w0,j+1,WAVE), __shfl(w1,j+1,WAVE), __shfl(w2,j+1,WAVE), __shfl(w3,j+1,WAVE), myh);
      float u2 = selh(__shfl(w0,j+2,WAVE), __shfl(w1,j+2,WAVE), __shfl(w2,j+2,WAVE), __shfl(w3,j+2,WAVE), myh);
      float u3 = selh(__shfl(w0,j+3,WAVE), __shfl(w1,j+3,WAVE), __shfl(w2,j+3,WAVE), __shfl(w3,j+3,WAVE), myh);
      if (VEC == 4){
        h16x4 v0 = *(const h16x4*)(h + (size_t)sj0*HC + lane*4);
        h16x4 v1 = *(const h16x4*)(h + (size_t)sj1*HC + lane*4);
        h16x4 v2 = *(const h16x4*)(h + (size_t)sj2*HC + lane*4);
        h16x4 v3 = *(const h16x4*)(h + (size_t)sj3*HC + lane*4);
        #pragma unroll
        for (int c = 0; c < 4; ++c)
          ac[c] = fmaf(u0,(float)v0[c], fmaf(u1,(float)v1[c], fmaf(u2,(float)v2[c], fmaf(u3,(float)v3[c], ac[c]))));
      } else {
        h16x8 v0 = *(const h16x8*)(h + (size_t)sj0*HC + lane*8);
        h16x8 v1 = *(const h16x8*)(h + (size_t)sj1*HC + lane*8);
        h16x8 v2 = *(const h16x8*)(h + (size_t)sj2*HC + lane*8);
        h16x8 v3 = *(const h16x8*)(h + (size_t)sj3*HC + lane*8);
        #pragma unroll
        for (int c = 0; c < VEC; ++c)
          ac[c] = fmaf(u0,(float)v0[c], fmaf(u1,(float)v1[c], fmaf(u2,(float)v2[c], fmaf(u3,(float)v3[c], ac[c]))));
      }
    }
    for (; j < nn; ++j){
      int sj = __shfl(sidx, j, WAVE);
      float u = selh(__shfl(w0,j,WAVE), __shfl(w1,j,WAVE), __shfl(w2,j,WAVE), __shfl(w3,j,WAVE), myh);
      if (VEC == 4){
        h16x4 v = *(const h16x4*)(h + (size_t)sj*HC + lane*4);
        #pragma unroll
        for (int c = 0; c < 4; ++c) ac[c] = fmaf(u, (float)v[c], ac[c]);
      } else {
        h16x8 v = *(const h16x8*)(h + (size_t)sj*HC + lane*8);
        #pragma unroll
        for (int c = 0; c < VEC; ++c) ac[c] = fmaf(u, (float)v[c], ac[c]);
      }
    }
  }

  float r0=0,r1=0,r2=0,r3=0,r4=0,r5=0,r6=0,r7=0;
  {
    const float* bp = bias + lane*VEC;
    #pragma unroll
    for (int c = 0; c < VEC; ++c){
      float r = ac[c] + bp[c];
      r = r > 0.f ? r : expm1f(r);
      if (c==0) r0=r; else if (c==1) r1=r; else if (c==2) r2=r; else if (c==3) r3=r;
      else if (c==4) r4=r; else if (c==5) r5=r; else if (c==6) r6=r; else r7=r;
    }
  }
  if (WF32){
    float* op = outF + (size_t)wid*HC + lane*VEC;
    *(float4*)op = make_float4(r0,r1,r2,r3);
    if (VEC == 8) *(float4*)(op+4) = make_float4(r4,r5,r6,r7);
  } else {
    h16x4 o;
    o[0] = (_Float16)r0; o[1] = (_Float16)r1;
    o[2] = (_Float16)r2; o[3] = (_Float16)r3;
    *(h16x4*)(oH + (size_t)wid*HC + lane*VEC) = o;
    if (VEC == 8){
      h16x4 o2;
      o2[0] = (_Float16)r4; o2[1] = (_Float16)r5;
      o2[2] = (_Float16)r6; o2[3] = (_Float16)r7;
      *(h16x4*)(oH + (size_t)wid*HC + lane*VEC + 4) = o2;
    }
  }
}

// ---------------- pooling + FC ----------------
__global__ void k_pool_partial(const float* __restrict__ h, const int* __restrict__ bs,
                               float* __restrict__ psum, float* __restrict__ pmax){
  int b = blockIdx.x, ch = blockIdx.y;
  int f = threadIdx.x;
  int s = bs[b], e = bs[b+1];
  long long len = e - s;
  int i0 = s + (int)(len * ch / 8);
  int i1 = s + (int)(len * (ch+1) / 8);
  float sm = 0.f, mx = -3.0e38f;
  for (int i = i0; i < i1; ++i){
    float v = h[(size_t)i*512 + f];
    sm += v; mx = fmaxf(mx, v);
  }
  int idx = (b*8 + ch)*512 + f;
  psum[idx] = sm; pmax[idx] = mx;
}

__global__ void k_pool_final(const float* __restrict__ psum, const float* __restrict__ pmax,
                             const int* __restrict__ bs, float* __restrict__ g){
  int b = blockIdx.x, f = threadIdx.x;
  float sm = 0.f, mx = -3.0e38f;
  for (int c = 0; c < 8; ++c){
    int idx = (b*8 + c)*512 + f;
    sm += psum[idx]; mx = fmaxf(mx, pmax[idx]);
  }
  int cnt = bs[b+1] - bs[b];
  g[b*1024 + f] = sm / fmaxf((float)cnt, 1.f);
  g[b*1024 + 512 + f] = (mx > -1e37f) ? mx : 0.f;
}

__global__ __launch_bounds__(256)
void k_fc(const float* __restrict__ g, const float* __restrict__ fcW,
          const float* __restrict__ fcb, float* __restrict__ out){
  __shared__ float gs[1024];
  __shared__ float red[4][64];
  int b = blockIdx.x, t = threadIdx.x;
  int o0 = blockIdx.y * 64;
  for (int i = t; i < 1024; i += 256) gs[i] = g[b*1024 + i];
  __syncthreads();
  int ol = t & 63, q = t >> 6;
  const float* wp = fcW + (size_t)(q*256)*512 + o0 + ol;
  float acc = 0.f;
  #pragma unroll 8
  for (int k = 0; k < 256; ++k)
    acc = fmaf(gs[q*256 + k], wp[(size_t)k*512], acc);
  red[q][ol] = acc;
  __syncthreads();
  if (t < 64){
    float r = red[0][t] + red[1][t] + red[2][t] + red[3][t] + fcb[o0 + t];
    out[b*512 + o0 + t] = r;
  }
}

// ---------------- launcher ----------------
extern "C" void kernel_launch(void* const* d_in, const int* in_sizes, int n_in,
                              void* d_out, int out_size, void* d_ws, size_t ws_size,
                              hipStream_t stream){
  (void)n_in; (void)out_size; (void)ws_size;
  const float* x     = (const float*)d_in[0];
  const int*   ei    = (const int*)d_in[1];
  const int*   batch = (const int*)d_in[2];
  const float* W[4]   = {(const float*)d_in[3],(const float*)d_in[7],(const float*)d_in[11],(const float*)d_in[15]};
  const float* asr[4] = {(const float*)d_in[4],(const float*)d_in[8],(const float*)d_in[12],(const float*)d_in[16]};
  const float* adt[4] = {(const float*)d_in[5],(const float*)d_in[9],(const float*)d_in[13],(const float*)d_in[17]};
  const float* bb[4]  = {(const float*)d_in[6],(const float*)d_in[10],(const float*)d_in[14],(const float*)d_in[18]};
  const float* fcW = (const float*)d_in[19];
  const float* fcb = (const float*)d_in[20];

  const int N  = in_sizes[0] / 128;
  const int E  = in_sizes[1] / 2;
  const int EN = E + N;
  const int B  = 32;
  const int NB = (N + 1023) / 1024;

  char* p = (char*)d_ws;
  auto alloc = [&](size_t bytes){ void* r = (void*)p; p += (bytes + 255) & ~(size_t)255; return r; };
  float* bufA = (float*)alloc((size_t)N*512*4);            // final f32 h (pooling input)
  _Float16* hA = (_Float16*)alloc((size_t)N*512*2);        // GEMM out (gather input)
  _Float16* hB = (_Float16*)alloc((size_t)N*512*2);        // agg out (next GEMM A)
  _Float16* Wh = (_Float16*)alloc((size_t)512*256*2);      // W^T f16
  float* a2   = (float*)alloc((size_t)N*8*4);              // as4 | ad4
  float* as4 = a2;
  float* ad4 = a2 + (size_t)N*4;
  int*   cnt  = (int*)alloc((size_t)N*4);
  int*   rp   = (int*)alloc((size_t)(N+1)*4);
  int*   cur  = (int*)alloc((size_t)N*4);
  int*   es   = (int*)alloc((size_t)EN*4);
  int*   bs   = (int*)alloc((size_t)(B+1)*4);
  int*   bsum = (int*)alloc((size_t)64*4);
  float* gpo  = (float*)alloc((size_t)B*1024*4);
  float* psum = (float*)alloc((size_t)B*8*512*4);
  float* pmax = (float*)alloc((size_t)B*8*512*4);

  // CSR build
  k_zero_i<<<(N+255)/256, 256, 0, stream>>>(cnt, N);
  k_count<<<(EN+255)/256, 256, 0, stream>>>(ei, E, N, cnt);
  k_scan1<<<NB, 1024, 0, stream>>>(cnt, rp, bsum, N);
  k_scan2<<<1, 64, 0, stream>>>(bsum, NB, rp, N);
  k_scan3<<<NB, 1024, 0, stream>>>(rp, bsum, N);
  k_copy_i<<<(N+255)/256, 256, 0, stream>>>(rp, cur, N);
  k_fill<<<(EN+255)/256, 256, 0, stream>>>(ei, E, N, cur, es);
  k_bounds<<<1, 64, 0, stream>>>(batch, N, B, bs);

  const int wgrid = (N + 3) / 4;

  // layer-1 input -> f16 into hB
  k_cvt16<<<((N*128/4) + 255)/256, 256, 0, stream>>>(x, hB, N*128/4);

  const int Kd[4]  = {128, 256, 256, 256};
  const int HCd[4] = {256, 256, 256, 512};

  for (int L = 0; L < 4; ++L){
    const int K = Kd[L], Nc = HCd[L];
    k_zero_f<<<(N*8 + 255)/256, 256, 0, stream>>>(a2, N*8);
    k_cvt_w16<<<(K*Nc + 255)/256, 256, 0, stream>>>(W[L], Wh, K, Nc);
    dim3 gg((N + 127)/128, Nc/128);
    if (Nc == 256)
      k_gemm_fused<64><<<gg, 512, 0, stream>>>(hB, Wh, hA, asr[L], adt[L], as4, ad4, N, K, Nc);
    else
      k_gemm_fused<128><<<gg, 512, 0, stream>>>(hB, Wh, hA, asr[L], adt[L], as4, ad4, N, K, Nc);
    if (L < 3)
      k_agg_h<256,0><<<wgrid, 256, 0, stream>>>(rp, es, as4, ad4, hA, bb[L], (float*)nullptr, hB, N);
    else
      k_agg_h<512,1><<<wgrid, 256, 0, stream>>>(rp, es, as4, ad4, hA, bb[L], bufA, (_Float16*)nullptr, N);
  }

  dim3 pg(B, 8);
  k_pool_partial<<<pg, 512, 0, stream>>>(bufA, bs, psum, pmax);
  k_pool_final<<<B, 512, 0, stream>>>(psum, pmax, bs, gpo);
  dim3 fg(B, 8);
  k_fc<<<fg, 256, 0, stream>>>(gpo, fcW, fcb, (float*)d_out);
}

// Round 8
// 447.815 us; speedup vs baseline: 2.1330x; 1.0960x over previous
//
#include <hip/hip_runtime.h>
#include <math.h>

#define WAVE 64

typedef __attribute__((ext_vector_type(4))) float f32x4;
typedef _Float16 h16x4 __attribute__((ext_vector_type(4)));
typedef _Float16 h16x8 __attribute__((ext_vector_type(8)));

__device__ __forceinline__ float selh(float e0, float e1, float e2, float e3, int m){
  float r = (m == 1) ? e1 : e0;
  r = (m == 2) ? e2 : r;
  r = (m == 3) ? e3 : r;
  return r;
}

// ---------------- CSR build ----------------
__global__ void k_zero_i(int* p, int n){
  int i = blockIdx.x*blockDim.x + threadIdx.x;
  if (i < n) p[i] = 0;
}

__global__ void k_count(const int* __restrict__ ei, int E, int N, int* __restrict__ cnt){
  int i = blockIdx.x*blockDim.x + threadIdx.x;
  if (i >= E + N) return;
  int d = (i < E) ? ei[E + i] : (i - E);
  atomicAdd(&cnt[d], 1);
}

__global__ __launch_bounds__(1024)
void k_scan1(const int* __restrict__ cnt, int* __restrict__ rp, int* __restrict__ bsum, int N){
  __shared__ int sd[1024];
  int t = threadIdx.x, i = blockIdx.x*1024 + t;
  int v = (i < N) ? cnt[i] : 0;
  sd[t] = v;
  __syncthreads();
  for (int off = 1; off < 1024; off <<= 1){
    int x = (t >= off) ? sd[t-off] : 0;
    __syncthreads();
    sd[t] += x;
    __syncthreads();
  }
  if (i < N) rp[i] = sd[t] - v;
  if (t == 1023) bsum[blockIdx.x] = sd[1023];
}

__global__ void k_scan2(int* __restrict__ bsum, int nb, int* __restrict__ rp, int N){
  int t = threadIdx.x;
  int orig = (t < nb) ? bsum[t] : 0;
  int v = orig;
  #pragma unroll
  for (int off = 1; off < 64; off <<= 1){
    int x = __shfl_up(v, off, WAVE);
    if (t >= off) v += x;
  }
  if (t < nb) bsum[t] = v - orig;
  if (t == 63) rp[N] = v;
}

// adds block offsets AND writes the fill cursor copy
__global__ __launch_bounds__(1024)
void k_scan3(int* __restrict__ rp, int* __restrict__ cur, const int* __restrict__ bsum, int N){
  int i = blockIdx.x*1024 + threadIdx.x;
  if (i < N){
    int v = rp[i] + bsum[blockIdx.x];
    rp[i] = v;
    cur[i] = v;
  }
}

__global__ void k_fill(const int* __restrict__ ei, int E, int N,
                       int* __restrict__ cur, int* __restrict__ es){
  int i = blockIdx.x*blockDim.x + threadIdx.x;
  if (i >= E + N) return;
  int s, d;
  if (i < E){ s = ei[i]; d = ei[E + i]; } else { s = d = i - E; }
  int pos = atomicAdd(&cur[d], 1);
  es[pos] = s;
}

__global__ void k_bounds(const int* __restrict__ batch, int N, int B, int* __restrict__ bs){
  int b = blockIdx.x*blockDim.x + threadIdx.x;
  if (b > B) return;
  int lo = 0, hi = N;
  while (lo < hi){ int mid = (lo + hi) >> 1; if (batch[mid] < b) lo = mid + 1; else hi = mid; }
  bs[b] = lo;
}

// ---------------- f32 -> f16 (layer-1 input) ----------------
__global__ __launch_bounds__(256)
void k_cvt16(const float* __restrict__ in, _Float16* __restrict__ out, int n4){
  int i = blockIdx.x*blockDim.x + threadIdx.x;
  if (i >= n4) return;
  float4 v = ((const float4*)in)[i];
  h16x4 o;
  o[0] = (_Float16)v.x; o[1] = (_Float16)v.y;
  o[2] = (_Float16)v.z; o[3] = (_Float16)v.w;
  ((h16x4*)out)[i] = o;
}

// all four W[K,Nc] f32 -> W^T f16 [Nc,K], packed at fixed offsets
__global__ __launch_bounds__(256)
void k_cvt_w_all(const float* __restrict__ W0, const float* __restrict__ W1,
                 const float* __restrict__ W2, const float* __restrict__ W3,
                 _Float16* __restrict__ out){
  int i = blockIdx.x*blockDim.x + threadIdx.x;
  if (i < 32768){                       // L1: K=128, Nc=256
    int k = i >> 8, n = i & 255;
    out[(size_t)n*128 + k] = (_Float16)W0[i];
  } else if (i < 98304){                // L2: K=256, Nc=256
    int j = i - 32768;
    int k = j >> 8, n = j & 255;
    out[32768 + (size_t)n*256 + k] = (_Float16)W1[j];
  } else if (i < 163840){               // L3: K=256, Nc=256
    int j = i - 98304;
    int k = j >> 8, n = j & 255;
    out[98304 + (size_t)n*256 + k] = (_Float16)W2[j];
  } else if (i < 294912){               // L4: K=256, Nc=512
    int j = i - 163840;
    int k = j >> 9, n = j & 511;
    out[163840 + (size_t)n*256 + k] = (_Float16)W3[j];
  }
}

// ---------------- fp16 MFMA GEMM (128x128 tile, 8 waves, dbuf LDS), fused alpha ----------------
// h = A@W via mfma_f32_16x16x32_f16 (f32 accum). A f16 [M,K]; W^T f16 [Nc,K].
// Double-buffered LDS: one barrier per K-step, next-tile loads overlap MFMA.
// alpha: CHEAD=64 -> each (row,head) has exactly one writer wave => plain store.
//        CHEAD=128 -> two waves (wc=0/1) share a head => 2KB LDS reduce, store.
template<int CHEAD>
__global__ __launch_bounds__(512)
void k_gemm_fused(const _Float16* __restrict__ Ax, const _Float16* __restrict__ Bw,
                  _Float16* __restrict__ Ch,
                  const float* __restrict__ asr, const float* __restrict__ adt,
                  float* __restrict__ as4, float* __restrict__ ad4,
                  int M, int K, int Nc){
  constexpr int LDP = 40;  // padded row stride (halves): 80 B -> <=2-way banks (free)
  __shared__ _Float16 sA[2][128*LDP], sB[2][128*LDP];   // 40 KB total
  const int tid = threadIdx.x;
  const int m0 = blockIdx.x*128, n0 = blockIdx.y*128;
  const int w = tid >> 6, l = tid & 63;
  const int wr = w >> 1, wc = w & 1;          // 4M x 2N waves
  const int sr = tid >> 2, sc = (tid & 3)*8;  // staging: 128 rows x 4 thr/row x 8 halves

  f32x4 acc00={0.f,0.f,0.f,0.f}, acc01=acc00, acc02=acc00, acc03=acc00;
  f32x4 acc10=acc00, acc11=acc00, acc12=acc00, acc13=acc00;

  const int arow = m0 + sr;
  const bool aval = arow < M;
  const size_t aoff = (size_t)arow*K + sc;
  const size_t boff = (size_t)(n0 + sr)*K + sc;

  const int fa0 = (wr*32 + (l & 15))*LDP + (l >> 4)*8;
  const int fa1 = fa0 + 16*LDP;
  const int fb0 = (wc*64 + (l & 15))*LDP + (l >> 4)*8;
  const int steps = K >> 5;

  // prologue: stage tile 0
  uint4 va = make_uint4(0,0,0,0), vb;
  if (aval) va = *(const uint4*)(Ax + aoff);
  vb = *(const uint4*)(Bw + boff);
  *(uint4*)&sA[0][sr*LDP + sc] = va;
  *(uint4*)&sB[0][sr*LDP + sc] = vb;
  __syncthreads();

  for (int ks = 0; ks < steps; ++ks){
    const int cur = ks & 1;
    const bool more = (ks + 1 < steps);
    if (more){
      const int k0 = (ks + 1)*32;
      va = make_uint4(0,0,0,0);
      if (aval) va = *(const uint4*)(Ax + aoff + k0);
      vb = *(const uint4*)(Bw + boff + k0);
    }

    h16x8 a0 = *(const h16x8*)&sA[cur][fa0];
    h16x8 a1 = *(const h16x8*)&sA[cur][fa1];
    h16x8 b;
    b = *(const h16x8*)&sB[cur][fb0];
    acc00 = __builtin_amdgcn_mfma_f32_16x16x32_f16(a0, b, acc00, 0, 0, 0);
    acc10 = __builtin_amdgcn_mfma_f32_16x16x32_f16(a1, b, acc10, 0, 0, 0);
    b = *(const h16x8*)&sB[cur][fb0 + 16*LDP];
    acc01 = __builtin_amdgcn_mfma_f32_16x16x32_f16(a0, b, acc01, 0, 0, 0);
    acc11 = __builtin_amdgcn_mfma_f32_16x16x32_f16(a1, b, acc11, 0, 0, 0);
    b = *(const h16x8*)&sB[cur][fb0 + 32*LDP];
    acc02 = __builtin_amdgcn_mfma_f32_16x16x32_f16(a0, b, acc02, 0, 0, 0);
    acc12 = __builtin_amdgcn_mfma_f32_16x16x32_f16(a1, b, acc12, 0, 0, 0);
    b = *(const h16x8*)&sB[cur][fb0 + 48*LDP];
    acc03 = __builtin_amdgcn_mfma_f32_16x16x32_f16(a0, b, acc03, 0, 0, 0);
    acc13 = __builtin_amdgcn_mfma_f32_16x16x32_f16(a1, b, acc13, 0, 0, 0);

    if (more){
      *(uint4*)&sA[cur^1][sr*LDP + sc] = va;
      *(uint4*)&sB[cur^1][sr*LDP + sc] = vb;
      __syncthreads();
    }
  }

  // C/D layout per 16x16 frag: col = lane&15, row = (lane>>4)*4 + j
  const int colb = n0 + wc*64 + (l & 15);
  const float ca0 = asr[colb], ca1 = asr[colb+16], ca2 = asr[colb+32], ca3 = asr[colb+48];
  const float cd0 = adt[colb], cd1 = adt[colb+16], cd2 = adt[colb+32], cd3 = adt[colb+48];

  float psA[1]; (void)psA; // (no arrays in hot path; scalars below)

  // fp16 h write + per-row alpha partials
  float psm0[4], pdm0[4], psm1[4], pdm1[4];   // compile-time unrolled only
  {
    const int rb = m0 + wr*32 + (l >> 4)*4;
    #pragma unroll
    for (int j = 0; j < 4; ++j){
      int row = rb + j;
      if (row < M){
        _Float16* hp = Ch + (size_t)row*Nc + colb;
        hp[0]  = (_Float16)acc00[j];
        hp[16] = (_Float16)acc01[j];
        hp[32] = (_Float16)acc02[j];
        hp[48] = (_Float16)acc03[j];
      }
      float ps = ca0*acc00[j] + ca1*acc01[j] + ca2*acc02[j] + ca3*acc03[j];
      float pd = cd0*acc00[j] + cd1*acc01[j] + cd2*acc02[j] + cd3*acc03[j];
      ps += __shfl_xor(ps, 1, WAVE);  pd += __shfl_xor(pd, 1, WAVE);
      ps += __shfl_xor(ps, 2, WAVE);  pd += __shfl_xor(pd, 2, WAVE);
      ps += __shfl_xor(ps, 4, WAVE);  pd += __shfl_xor(pd, 4, WAVE);
      ps += __shfl_xor(ps, 8, WAVE);  pd += __shfl_xor(pd, 8, WAVE);
      psm0[j] = ps; pdm0[j] = pd;
    }
  }
  {
    const int rb = m0 + wr*32 + 16 + (l >> 4)*4;
    #pragma unroll
    for (int j = 0; j < 4; ++j){
      int row = rb + j;
      if (row < M){
        _Float16* hp = Ch + (size_t)row*Nc + colb;
        hp[0]  = (_Float16)acc10[j];
        hp[16] = (_Float16)acc11[j];
        hp[32] = (_Float16)acc12[j];
        hp[48] = (_Float16)acc13[j];
      }
      float ps = ca0*acc10[j] + ca1*acc11[j] + ca2*acc12[j] + ca3*acc13[j];
      float pd = cd0*acc10[j] + cd1*acc11[j] + cd2*acc12[j] + cd3*acc13[j];
      ps += __shfl_xor(ps, 1, WAVE);  pd += __shfl_xor(pd, 1, WAVE);
      ps += __shfl_xor(ps, 2, WAVE);  pd += __shfl_xor(pd, 2, WAVE);
      ps += __shfl_xor(ps, 4, WAVE);  pd += __shfl_xor(pd, 4, WAVE);
      ps += __shfl_xor(ps, 8, WAVE);  pd += __shfl_xor(pd, 8, WAVE);
      psm1[j] = ps; pdm1[j] = pd;
    }
  }

  if (CHEAD == 64){
    // unique writer per (row, head): store directly
    const int hy = blockIdx.y*2 + wc;
    if ((l & 15) == 0){
      const int rb0 = m0 + wr*32 + (l >> 4)*4;
      #pragma unroll
      for (int j = 0; j < 4; ++j){
        int row = rb0 + j;
        if (row < M){ as4[(size_t)row*4 + hy] = psm0[j]; ad4[(size_t)row*4 + hy] = pdm0[j]; }
      }
      const int rb1 = rb0 + 16;
      #pragma unroll
      for (int j = 0; j < 4; ++j){
        int row = rb1 + j;
        if (row < M){ as4[(size_t)row*4 + hy] = psm1[j]; ad4[(size_t)row*4 + hy] = pdm1[j]; }
      }
    }
  } else {
    // CHEAD==128: head = blockIdx.y; two waves (wc=0/1) contribute -> LDS reduce
    float* red = (float*)&sA[0][0];    // 128 rows * 4 floats = 2 KB
    __syncthreads();                   // LDS reads from main loop done
    if ((l & 15) == 0){
      const int lr0 = wr*32 + (l >> 4)*4;
      #pragma unroll
      for (int j = 0; j < 4; ++j){
        red[(lr0 + j)*4 + wc*2 + 0] = psm0[j];
        red[(lr0 + j)*4 + wc*2 + 1] = pdm0[j];
      }
      const int lr1 = lr0 + 16;
      #pragma unroll
      for (int j = 0; j < 4; ++j){
        red[(lr1 + j)*4 + wc*2 + 0] = psm1[j];
        red[(lr1 + j)*4 + wc*2 + 1] = pdm1[j];
      }
    }
    __syncthreads();
    if (tid < 128){
      int row = m0 + tid;
      if (row < M){
        float ps = red[tid*4 + 0] + red[tid*4 + 2];
        float pd = red[tid*4 + 1] + red[tid*4 + 3];
        as4[(size_t)row*4 + blockIdx.y] = ps;
        ad4[(size_t)row*4 + blockIdx.y] = pd;
      }
    }
  }
}

// ---------------- fp16-gather agg (all layers) ----------------
// WF32=1: write f32 elu(out) (final layer, feeds pooling)
// WF32=0: write f16 elu(out) (feeds next GEMM)
template<int HC, int WF32>
__global__ __launch_bounds__(256)
void k_agg_h(const int* __restrict__ rp, const int* __restrict__ es,
             const float* __restrict__ as4, const float* __restrict__ ad4,
             const _Float16* __restrict__ h, const float* __restrict__ bias,
             float* __restrict__ outF, _Float16* __restrict__ oH, int N){
  constexpr int VEC = HC / 64;           // halves per lane (4 or 8)
  int wid  = (blockIdx.x*blockDim.x + threadIdx.x) >> 6;
  int lane = threadIdx.x & 63;
  if (wid >= N) return;
  int beg = rp[wid], end = rp[wid+1];

  const float4 adv = *(const float4*)(ad4 + (size_t)wid*4);
  const float ad0 = adv.x, ad1 = adv.y, ad2 = adv.z, ad3 = adv.w;

  float m0=-1e30f, m1=-1e30f, m2=-1e30f, m3=-1e30f;
  float s0=0.f, s1=0.f, s2=0.f, s3=0.f;
  for (int i = beg + lane; i < end; i += WAVE){
    int s = es[i];
    const float4 av = *(const float4*)(as4 + (size_t)s*4);
    float e, mn;
    e = av.x + ad0; e = (e >= 0.f) ? e : 0.2f*e;
    mn = fmaxf(m0, e); s0 = s0*__expf(m0-mn) + __expf(e-mn); m0 = mn;
    e = av.y + ad1; e = (e >= 0.f) ? e : 0.2f*e;
    mn = fmaxf(m1, e); s1 = s1*__expf(m1-mn) + __expf(e-mn); m1 = mn;
    e = av.z + ad2; e = (e >= 0.f) ? e : 0.2f*e;
    mn = fmaxf(m2, e); s2 = s2*__expf(m2-mn) + __expf(e-mn); m2 = mn;
    e = av.w + ad3; e = (e >= 0.f) ? e : 0.2f*e;
    mn = fmaxf(m3, e); s3 = s3*__expf(m3-mn) + __expf(e-mn); m3 = mn;
  }
  #pragma unroll
  for (int off = 32; off > 0; off >>= 1){
    float mo, so, mn;
    mo = __shfl_xor(m0, off, WAVE); so = __shfl_xor(s0, off, WAVE);
    mn = fmaxf(m0, mo); s0 = s0*__expf(m0-mn) + so*__expf(mo-mn); m0 = mn;
    mo = __shfl_xor(m1, off, WAVE); so = __shfl_xor(s1, off, WAVE);
    mn = fmaxf(m1, mo); s1 = s1*__expf(m1-mn) + so*__expf(mo-mn); m1 = mn;
    mo = __shfl_xor(m2, off, WAVE); so = __shfl_xor(s2, off, WAVE);
    mn = fmaxf(m2, mo); s2 = s2*__expf(m2-mn) + so*__expf(mo-mn); m2 = mn;
    mo = __shfl_xor(m3, off, WAVE); so = __shfl_xor(s3, off, WAVE);
    mn = fmaxf(m3, mo); s3 = s3*__expf(m3-mn) + so*__expf(mo-mn); m3 = mn;
  }
  const float i0 = 1.f/(s0 + 1e-16f), i1 = 1.f/(s1 + 1e-16f);
  const float i2 = 1.f/(s2 + 1e-16f), i3 = 1.f/(s3 + 1e-16f);
  const int myh = lane >> 4;

  float ac[VEC] = {};

  for (int cb = beg; cb < end; cb += WAVE){
    int nn = min(WAVE, end - cb);
    int sidx = 0;
    float w0 = 0.f, w1 = 0.f, w2 = 0.f, w3 = 0.f;
    if (cb + lane < end){
      sidx = es[cb + lane];
      const float4 av = *(const float4*)(as4 + (size_t)sidx*4);
      float e;
      e = av.x + ad0; e = (e >= 0.f) ? e : 0.2f*e; w0 = __expf(e - m0)*i0;
      e = av.y + ad1; e = (e >= 0.f) ? e : 0.2f*e; w1 = __expf(e - m1)*i1;
      e = av.z + ad2; e = (e >= 0.f) ? e : 0.2f*e; w2 = __expf(e - m2)*i2;
      e = av.w + ad3; e = (e >= 0.f) ? e : 0.2f*e; w3 = __expf(e - m3)*i3;
    }

    int j = 0;
    for (; j + 4 <= nn; j += 4){
      int sj0 = __shfl(sidx, j+0, WAVE), sj1 = __shfl(sidx, j+1, WAVE);
      int sj2 = __shfl(sidx, j+2, WAVE), sj3 = __shfl(sidx, j+3, WAVE);
      float u0 = selh(__shfl(w0,j+0,WAVE), __shfl(w1,j+0,WAVE), __shfl(w2,j+0,WAVE), __shfl(w3,j+0,WAVE), myh);
      float u1 = selh(__shfl(w0,j+1,WAVE), __shfl(w1,j+1,WAVE), __shfl(w2,j+1,WAVE), __shfl(w3,j+1,WAVE), myh);
      float u2 = selh(__shfl(w0,j+2,WAVE), __shfl(w1,j+2,WAVE), __shfl(w2,j+2,WAVE), __shfl(w3,j+2,WAVE), myh);
      float u3 = selh(__shfl(w0,j+3,WAVE), __shfl(w1,j+3,WAVE), __shfl(w2,j+3,WAVE), __shfl(w3,j+3,WAVE), myh);
      if (VEC == 4){
        h16x4 v0 = *(const h16x4*)(h + (size_t)sj0*HC + lane*4);
        h16x4 v1 = *(const h16x4*)(h + (size_t)sj1*HC + lane*4);
        h16x4 v2 = *(const h16x4*)(h + (size_t)sj2*HC + lane*4);
        h16x4 v3 = *(const h16x4*)(h + (size_t)sj3*HC + lane*4);
        #pragma unroll
        for (int c = 0; c < 4; ++c)
          ac[c] = fmaf(u0,(float)v0[c], fmaf(u1,(float)v1[c], fmaf(u2,(float)v2[c], fmaf(u3,(float)v3[c], ac[c]))));
      } else {
        h16x8 v0 = *(const h16x8*)(h + (size_t)sj0*HC + lane*8);
        h16x8 v1 = *(const h16x8*)(h + (size_t)sj1*HC + lane*8);
        h16x8 v2 = *(const h16x8*)(h + (size_t)sj2*HC + lane*8);
        h16x8 v3 = *(const h16x8*)(h + (size_t)sj3*HC + lane*8);
        #pragma unroll
        for (int c = 0; c < VEC; ++c)
          ac[c] = fmaf(u0,(float)v0[c], fmaf(u1,(float)v1[c], fmaf(u2,(float)v2[c], fmaf(u3,(float)v3[c], ac[c]))));
      }
    }
    for (; j < nn; ++j){
      int sj = __shfl(sidx, j, WAVE);
      float u = selh(__shfl(w0,j,WAVE), __shfl(w1,j,WAVE), __shfl(w2,j,WAVE), __shfl(w3,j,WAVE), myh);
      if (VEC == 4){
        h16x4 v = *(const h16x4*)(h + (size_t)sj*HC + lane*4);
        #pragma unroll
        for (int c = 0; c < 4; ++c) ac[c] = fmaf(u, (float)v[c], ac[c]);
      } else {
        h16x8 v = *(const h16x8*)(h + (size_t)sj*HC + lane*8);
        #pragma unroll
        for (int c = 0; c < VEC; ++c) ac[c] = fmaf(u, (float)v[c], ac[c]);
      }
    }
  }

  float r0=0,r1=0,r2=0,r3=0,r4=0,r5=0,r6=0,r7=0;
  {
    const float* bp = bias + lane*VEC;
    #pragma unroll
    for (int c = 0; c < VEC; ++c){
      float r = ac[c] + bp[c];
      r = r > 0.f ? r : expm1f(r);
      if (c==0) r0=r; else if (c==1) r1=r; else if (c==2) r2=r; else if (c==3) r3=r;
      else if (c==4) r4=r; else if (c==5) r5=r; else if (c==6) r6=r; else r7=r;
    }
  }
  if (WF32){
    float* op = outF + (size_t)wid*HC + lane*VEC;
    *(float4*)op = make_float4(r0,r1,r2,r3);
    if (VEC == 8) *(float4*)(op+4) = make_float4(r4,r5,r6,r7);
  } else {
    h16x4 o;
    o[0] = (_Float16)r0; o[1] = (_Float16)r1;
    o[2] = (_Float16)r2; o[3] = (_Float16)r3;
    *(h16x4*)(oH + (size_t)wid*HC + lane*VEC) = o;
    if (VEC == 8){
      h16x4 o2;
      o2[0] = (_Float16)r4; o2[1] = (_Float16)r5;
      o2[2] = (_Float16)r6; o2[3] = (_Float16)r7;
      *(h16x4*)(oH + (size_t)wid*HC + lane*VEC + 4) = o2;
    }
  }
}

// ---------------- pooling + FC ----------------
__global__ void k_pool_partial(const float* __restrict__ h, const int* __restrict__ bs,
                               float* __restrict__ psum, float* __restrict__ pmax){
  int b = blockIdx.x, ch = blockIdx.y;
  int f = threadIdx.x;
  int s = bs[b], e = bs[b+1];
  long long len = e - s;
  int i0 = s + (int)(len * ch / 8);
  int i1 = s + (int)(len * (ch+1) / 8);
  float sm = 0.f, mx = -3.0e38f;
  for (int i = i0; i < i1; ++i){
    float v = h[(size_t)i*512 + f];
    sm += v; mx = fmaxf(mx, v);
  }
  int idx = (b*8 + ch)*512 + f;
  psum[idx] = sm; pmax[idx] = mx;
}

__global__ void k_pool_final(const float* __restrict__ psum, const float* __restrict__ pmax,
                             const int* __restrict__ bs, float* __restrict__ g){
  int b = blockIdx.x, f = threadIdx.x;
  float sm = 0.f, mx = -3.0e38f;
  for (int c = 0; c < 8; ++c){
    int idx = (b*8 + c)*512 + f;
    sm += psum[idx]; mx = fmaxf(mx, pmax[idx]);
  }
  int cnt = bs[b+1] - bs[b];
  g[b*1024 + f] = sm / fmaxf((float)cnt, 1.f);
  g[b*1024 + 512 + f] = (mx > -1e37f) ? mx : 0.f;
}

__global__ __launch_bounds__(256)
void k_fc(const float* __restrict__ g, const float* __restrict__ fcW,
          const float* __restrict__ fcb, float* __restrict__ out){
  __shared__ float gs[1024];
  __shared__ float red[4][64];
  int b = blockIdx.x, t = threadIdx.x;
  int o0 = blockIdx.y * 64;
  for (int i = t; i < 1024; i += 256) gs[i] = g[b*1024 + i];
  __syncthreads();
  int ol = t & 63, q = t >> 6;
  const float* wp = fcW + (size_t)(q*256)*512 + o0 + ol;
  float acc = 0.f;
  #pragma unroll 8
  for (int k = 0; k < 256; ++k)
    acc = fmaf(gs[q*256 + k], wp[(size_t)k*512], acc);
  red[q][ol] = acc;
  __syncthreads();
  if (t < 64){
    float r = red[0][t] + red[1][t] + red[2][t] + red[3][t] + fcb[o0 + t];
    out[b*512 + o0 + t] = r;
  }
}

// ---------------- launcher ----------------
extern "C" void kernel_launch(void* const* d_in, const int* in_sizes, int n_in,
                              void* d_out, int out_size, void* d_ws, size_t ws_size,
                              hipStream_t stream){
  (void)n_in; (void)out_size; (void)ws_size;
  const float* x     = (const float*)d_in[0];
  const int*   ei    = (const int*)d_in[1];
  const int*   batch = (const int*)d_in[2];
  const float* W[4]   = {(const float*)d_in[3],(const float*)d_in[7],(const float*)d_in[11],(const float*)d_in[15]};
  const float* asr[4] = {(const float*)d_in[4],(const float*)d_in[8],(const float*)d_in[12],(const float*)d_in[16]};
  const float* adt[4] = {(const float*)d_in[5],(const float*)d_in[9],(const float*)d_in[13],(const float*)d_in[17]};
  const float* bb[4]  = {(const float*)d_in[6],(const float*)d_in[10],(const float*)d_in[14],(const float*)d_in[18]};
  const float* fcW = (const float*)d_in[19];
  const float* fcb = (const float*)d_in[20];

  const int N  = in_sizes[0] / 128;
  const int E  = in_sizes[1] / 2;
  const int EN = E + N;
  const int B  = 32;
  const int NB = (N + 1023) / 1024;

  char* p = (char*)d_ws;
  auto alloc = [&](size_t bytes){ void* r = (void*)p; p += (bytes + 255) & ~(size_t)255; return r; };
  float* bufA = (float*)alloc((size_t)N*512*4);            // final f32 h (pooling input)
  _Float16* hA = (_Float16*)alloc((size_t)N*512*2);        // GEMM out (gather input)
  _Float16* hB = (_Float16*)alloc((size_t)N*512*2);        // agg out (next GEMM A)
  _Float16* Wh = (_Float16*)alloc((size_t)294912*2);       // all W^T f16, packed
  float* a2   = (float*)alloc((size_t)N*8*4);              // as4 | ad4
  float* as4 = a2;
  float* ad4 = a2 + (size_t)N*4;
  int*   cnt  = (int*)alloc((size_t)N*4);
  int*   rp   = (int*)alloc((size_t)(N+1)*4);
  int*   cur  = (int*)alloc((size_t)N*4);
  int*   es   = (int*)alloc((size_t)EN*4);
  int*   bs   = (int*)alloc((size_t)(B+1)*4);
  int*   bsum = (int*)alloc((size_t)64*4);
  float* gpo  = (float*)alloc((size_t)B*1024*4);
  float* psum = (float*)alloc((size_t)B*8*512*4);
  float* pmax = (float*)alloc((size_t)B*8*512*4);

  // CSR build (7 launches)
  k_zero_i<<<(N+255)/256, 256, 0, stream>>>(cnt, N);
  k_count<<<(EN+255)/256, 256, 0, stream>>>(ei, E, N, cnt);
  k_scan1<<<NB, 1024, 0, stream>>>(cnt, rp, bsum, N);
  k_scan2<<<1, 64, 0, stream>>>(bsum, NB, rp, N);
  k_scan3<<<NB, 1024, 0, stream>>>(rp, cur, bsum, N);
  k_fill<<<(EN+255)/256, 256, 0, stream>>>(ei, E, N, cur, es);
  k_bounds<<<1, 64, 0, stream>>>(batch, N, B, bs);

  // input + all weights -> f16 (2 launches, independent of layer chain)
  k_cvt16<<<((N*128/4) + 255)/256, 256, 0, stream>>>(x, hB, N*128/4);
  k_cvt_w_all<<<(294912 + 255)/256, 256, 0, stream>>>(W[0], W[1], W[2], W[3], Wh);

  const int wgrid = (N + 3) / 4;
  const int Kd[4]  = {128, 256, 256, 256};
  const int HCd[4] = {256, 256, 256, 512};
  const size_t Woff[4] = {0, 32768, 98304, 163840};

  for (int L = 0; L < 4; ++L){
    const int K = Kd[L], Nc = HCd[L];
    dim3 gg((N + 127)/128, Nc/128);
    if (Nc == 256)
      k_gemm_fused<64><<<gg, 512, 0, stream>>>(hB, Wh + Woff[L], hA, asr[L], adt[L], as4, ad4, N, K, Nc);
    else
      k_gemm_fused<128><<<gg, 512, 0, stream>>>(hB, Wh + Woff[L], hA, asr[L], adt[L], as4, ad4, N, K, Nc);
    if (L < 3)
      k_agg_h<256,0><<<wgrid, 256, 0, stream>>>(rp, es, as4, ad4, hA, bb[L], (float*)nullptr, hB, N);
    else
      k_agg_h<512,1><<<wgrid, 256, 0, stream>>>(rp, es, as4, ad4, hA, bb[L], bufA, (_Float16*)nullptr, N);
  }

  dim3 pg(B, 8);
  k_pool_partial<<<pg, 512, 0, stream>>>(bufA, bs, psum, pmax);
  k_pool_final<<<B, 512, 0, stream>>>(psum, pmax, bs, gpo);
  dim3 fg(B, 8);
  k_fc<<<fg, 256, 0, stream>>>(gpo, fcW, fcb, (float*)d_out);
}

// Round 9
// 440.769 us; speedup vs baseline: 2.1671x; 1.0160x over previous
//
#include <hip/hip_runtime.h>
#include <math.h>

#define WAVE 64

typedef __attribute__((ext_vector_type(4))) float f32x4;
typedef _Float16 h16x4 __attribute__((ext_vector_type(4)));
typedef _Float16 h16x8 __attribute__((ext_vector_type(8)));

__device__ __forceinline__ float selh(float e0, float e1, float e2, float e3, int m){
  float r = (m == 1) ? e1 : e0;
  r = (m == 2) ? e2 : r;
  r = (m == 3) ? e3 : r;
  return r;
}

// ---------------- fused front: count | cvt16 | cvt_w_all | bounds ----------------
__global__ __launch_bounds__(256)
void k_front(const int* __restrict__ ei, int E, int N, int* __restrict__ cnt,
             const float* __restrict__ x, _Float16* __restrict__ hB,
             const float* __restrict__ W0, const float* __restrict__ W1,
             const float* __restrict__ W2, const float* __restrict__ W3,
             _Float16* __restrict__ Wh,
             const int* __restrict__ batch, int B, int* __restrict__ bs,
             int CB, int XB, int WB){
  int bid = blockIdx.x, t = threadIdx.x;
  if (bid < CB){
    int i = bid*256 + t;
    if (i < E + N){
      int d = (i < E) ? ei[E + i] : (i - E);
      atomicAdd(&cnt[d], 1);
    }
  } else if (bid < CB + XB){
    int i = (bid - CB)*256 + t;
    if (i < N*32){
      float4 v = ((const float4*)x)[i];
      h16x4 o;
      o[0] = (_Float16)v.x; o[1] = (_Float16)v.y;
      o[2] = (_Float16)v.z; o[3] = (_Float16)v.w;
      ((h16x4*)hB)[i] = o;
    }
  } else if (bid < CB + XB + WB){
    int i = (bid - CB - XB)*256 + t;
    if (i < 32768){                       // L1: K=128, Nc=256
      int k = i >> 8, n = i & 255;
      Wh[(size_t)n*128 + k] = (_Float16)W0[i];
    } else if (i < 98304){                // L2
      int j = i - 32768; int k = j >> 8, n = j & 255;
      Wh[32768 + (size_t)n*256 + k] = (_Float16)W1[j];
    } else if (i < 163840){               // L3
      int j = i - 98304; int k = j >> 8, n = j & 255;
      Wh[98304 + (size_t)n*256 + k] = (_Float16)W2[j];
    } else if (i < 294912){               // L4: K=256, Nc=512
      int j = i - 163840; int k = j >> 9, n = j & 511;
      Wh[163840 + (size_t)n*256 + k] = (_Float16)W3[j];
    }
  } else {
    int b = t;
    if (b <= B){
      int lo = 0, hi = N;
      while (lo < hi){ int mid = (lo + hi) >> 1; if (batch[mid] < b) lo = mid + 1; else hi = mid; }
      bs[b] = lo;
    }
  }
}

// ---------------- scan1 with fused block-sum scan (last-block pattern) ----------------
__global__ __launch_bounds__(1024)
void k_scan1(const int* __restrict__ cnt, int* __restrict__ rp, int* __restrict__ bsum,
             int* __restrict__ done, int N, int nb){
  __shared__ int sd[1024];
  int t = threadIdx.x, i = blockIdx.x*1024 + t;
  int v = (i < N) ? cnt[i] : 0;
  sd[t] = v;
  __syncthreads();
  for (int off = 1; off < 1024; off <<= 1){
    int x = (t >= off) ? sd[t-off] : 0;
    __syncthreads();
    sd[t] += x;
    __syncthreads();
  }
  if (i < N) rp[i] = sd[t] - v;
  if (t == 1023) bsum[blockIdx.x] = sd[1023];
  __threadfence();
  __syncthreads();
  if (t == 0){
    if (atomicAdd(done, 1) == nb - 1){
      int run = 0;
      for (int b2 = 0; b2 < nb; ++b2){ int s = bsum[b2]; bsum[b2] = run; run += s; }
      rp[N] = run;
    }
  }
}

// adds block offsets AND writes the fill cursor copy
__global__ __launch_bounds__(1024)
void k_scan3(int* __restrict__ rp, int* __restrict__ cur, const int* __restrict__ bsum, int N){
  int i = blockIdx.x*1024 + threadIdx.x;
  if (i < N){
    int v = rp[i] + bsum[blockIdx.x];
    rp[i] = v;
    cur[i] = v;
  }
}

__global__ void k_fill(const int* __restrict__ ei, int E, int N,
                       int* __restrict__ cur, int* __restrict__ es){
  int i = blockIdx.x*blockDim.x + threadIdx.x;
  if (i >= E + N) return;
  int s, d;
  if (i < E){ s = ei[i]; d = ei[E + i]; } else { s = d = i - E; }
  int pos = atomicAdd(&cur[d], 1);
  es[pos] = s;
}

// ---------------- fp16 MFMA GEMM (128x128 tile, 8 waves, dbuf LDS), fused alpha ----------------
template<int CHEAD>
__global__ __launch_bounds__(512)
void k_gemm_fused(const _Float16* __restrict__ Ax, const _Float16* __restrict__ Bw,
                  _Float16* __restrict__ Ch,
                  const float* __restrict__ asr, const float* __restrict__ adt,
                  float* __restrict__ as4, float* __restrict__ ad4,
                  int M, int K, int Nc){
  constexpr int LDP = 40;  // padded row stride (halves): 80 B -> <=2-way banks (free)
  __shared__ _Float16 sA[2][128*LDP], sB[2][128*LDP];   // 40 KB total
  const int tid = threadIdx.x;
  const int m0 = blockIdx.x*128, n0 = blockIdx.y*128;
  const int w = tid >> 6, l = tid & 63;
  const int wr = w >> 1, wc = w & 1;          // 4M x 2N waves
  const int sr = tid >> 2, sc = (tid & 3)*8;  // staging: 128 rows x 4 thr/row x 8 halves

  f32x4 acc00={0.f,0.f,0.f,0.f}, acc01=acc00, acc02=acc00, acc03=acc00;
  f32x4 acc10=acc00, acc11=acc00, acc12=acc00, acc13=acc00;

  const int arow = m0 + sr;
  const bool aval = arow < M;
  const size_t aoff = (size_t)arow*K + sc;
  const size_t boff = (size_t)(n0 + sr)*K + sc;

  const int fa0 = (wr*32 + (l & 15))*LDP + (l >> 4)*8;
  const int fa1 = fa0 + 16*LDP;
  const int fb0 = (wc*64 + (l & 15))*LDP + (l >> 4)*8;
  const int steps = K >> 5;

  uint4 va = make_uint4(0,0,0,0), vb;
  if (aval) va = *(const uint4*)(Ax + aoff);
  vb = *(const uint4*)(Bw + boff);
  *(uint4*)&sA[0][sr*LDP + sc] = va;
  *(uint4*)&sB[0][sr*LDP + sc] = vb;
  __syncthreads();

  for (int ks = 0; ks < steps; ++ks){
    const int cur = ks & 1;
    const bool more = (ks + 1 < steps);
    if (more){
      const int k0 = (ks + 1)*32;
      va = make_uint4(0,0,0,0);
      if (aval) va = *(const uint4*)(Ax + aoff + k0);
      vb = *(const uint4*)(Bw + boff + k0);
    }

    h16x8 a0 = *(const h16x8*)&sA[cur][fa0];
    h16x8 a1 = *(const h16x8*)&sA[cur][fa1];
    h16x8 b;
    b = *(const h16x8*)&sB[cur][fb0];
    acc00 = __builtin_amdgcn_mfma_f32_16x16x32_f16(a0, b, acc00, 0, 0, 0);
    acc10 = __builtin_amdgcn_mfma_f32_16x16x32_f16(a1, b, acc10, 0, 0, 0);
    b = *(const h16x8*)&sB[cur][fb0 + 16*LDP];
    acc01 = __builtin_amdgcn_mfma_f32_16x16x32_f16(a0, b, acc01, 0, 0, 0);
    acc11 = __builtin_amdgcn_mfma_f32_16x16x32_f16(a1, b, acc11, 0, 0, 0);
    b = *(const h16x8*)&sB[cur][fb0 + 32*LDP];
    acc02 = __builtin_amdgcn_mfma_f32_16x16x32_f16(a0, b, acc02, 0, 0, 0);
    acc12 = __builtin_amdgcn_mfma_f32_16x16x32_f16(a1, b, acc12, 0, 0, 0);
    b = *(const h16x8*)&sB[cur][fb0 + 48*LDP];
    acc03 = __builtin_amdgcn_mfma_f32_16x16x32_f16(a0, b, acc03, 0, 0, 0);
    acc13 = __builtin_amdgcn_mfma_f32_16x16x32_f16(a1, b, acc13, 0, 0, 0);

    if (more){
      *(uint4*)&sA[cur^1][sr*LDP + sc] = va;
      *(uint4*)&sB[cur^1][sr*LDP + sc] = vb;
      __syncthreads();
    }
  }

  // C/D layout per 16x16 frag: col = lane&15, row = (lane>>4)*4 + j
  const int colb = n0 + wc*64 + (l & 15);
  const float ca0 = asr[colb], ca1 = asr[colb+16], ca2 = asr[colb+32], ca3 = asr[colb+48];
  const float cd0 = adt[colb], cd1 = adt[colb+16], cd2 = adt[colb+32], cd3 = adt[colb+48];

  float psm0[4], pdm0[4], psm1[4], pdm1[4];   // compile-time unrolled only
  {
    const int rb = m0 + wr*32 + (l >> 4)*4;
    #pragma unroll
    for (int j = 0; j < 4; ++j){
      int row = rb + j;
      if (row < M){
        _Float16* hp = Ch + (size_t)row*Nc + colb;
        hp[0]  = (_Float16)acc00[j];
        hp[16] = (_Float16)acc01[j];
        hp[32] = (_Float16)acc02[j];
        hp[48] = (_Float16)acc03[j];
      }
      float ps = ca0*acc00[j] + ca1*acc01[j] + ca2*acc02[j] + ca3*acc03[j];
      float pd = cd0*acc00[j] + cd1*acc01[j] + cd2*acc02[j] + cd3*acc03[j];
      ps += __shfl_xor(ps, 1, WAVE);  pd += __shfl_xor(pd, 1, WAVE);
      ps += __shfl_xor(ps, 2, WAVE);  pd += __shfl_xor(pd, 2, WAVE);
      ps += __shfl_xor(ps, 4, WAVE);  pd += __shfl_xor(pd, 4, WAVE);
      ps += __shfl_xor(ps, 8, WAVE);  pd += __shfl_xor(pd, 8, WAVE);
      psm0[j] = ps; pdm0[j] = pd;
    }
  }
  {
    const int rb = m0 + wr*32 + 16 + (l >> 4)*4;
    #pragma unroll
    for (int j = 0; j < 4; ++j){
      int row = rb + j;
      if (row < M){
        _Float16* hp = Ch + (size_t)row*Nc + colb;
        hp[0]  = (_Float16)acc10[j];
        hp[16] = (_Float16)acc11[j];
        hp[32] = (_Float16)acc12[j];
        hp[48] = (_Float16)acc13[j];
      }
      float ps = ca0*acc10[j] + ca1*acc11[j] + ca2*acc12[j] + ca3*acc13[j];
      float pd = cd0*acc10[j] + cd1*acc11[j] + cd2*acc12[j] + cd3*acc13[j];
      ps += __shfl_xor(ps, 1, WAVE);  pd += __shfl_xor(pd, 1, WAVE);
      ps += __shfl_xor(ps, 2, WAVE);  pd += __shfl_xor(pd, 2, WAVE);
      ps += __shfl_xor(ps, 4, WAVE);  pd += __shfl_xor(pd, 4, WAVE);
      ps += __shfl_xor(ps, 8, WAVE);  pd += __shfl_xor(pd, 8, WAVE);
      psm1[j] = ps; pdm1[j] = pd;
    }
  }

  if (CHEAD == 64){
    const int hy = blockIdx.y*2 + wc;
    if ((l & 15) == 0){
      const int rb0 = m0 + wr*32 + (l >> 4)*4;
      #pragma unroll
      for (int j = 0; j < 4; ++j){
        int row = rb0 + j;
        if (row < M){ as4[(size_t)row*4 + hy] = psm0[j]; ad4[(size_t)row*4 + hy] = pdm0[j]; }
      }
      const int rb1 = rb0 + 16;
      #pragma unroll
      for (int j = 0; j < 4; ++j){
        int row = rb1 + j;
        if (row < M){ as4[(size_t)row*4 + hy] = psm1[j]; ad4[(size_t)row*4 + hy] = pdm1[j]; }
      }
    }
  } else {
    float* red = (float*)&sA[0][0];    // 128 rows * 4 floats = 2 KB
    __syncthreads();
    if ((l & 15) == 0){
      const int lr0 = wr*32 + (l >> 4)*4;
      #pragma unroll
      for (int j = 0; j < 4; ++j){
        red[(lr0 + j)*4 + wc*2 + 0] = psm0[j];
        red[(lr0 + j)*4 + wc*2 + 1] = pdm0[j];
      }
      const int lr1 = lr0 + 16;
      #pragma unroll
      for (int j = 0; j < 4; ++j){
        red[(lr1 + j)*4 + wc*2 + 0] = psm1[j];
        red[(lr1 + j)*4 + wc*2 + 1] = pdm1[j];
      }
    }
    __syncthreads();
    if (tid < 128){
      int row = m0 + tid;
      if (row < M){
        float ps = red[tid*4 + 0] + red[tid*4 + 2];
        float pd = red[tid*4 + 1] + red[tid*4 + 3];
        as4[(size_t)row*4 + blockIdx.y] = ps;
        ad4[(size_t)row*4 + blockIdx.y] = pd;
      }
    }
  }
}

// ---------------- fp16-gather agg (all layers; fp16 out) ----------------
template<int HC>
__global__ __launch_bounds__(256)
void k_agg_h(const int* __restrict__ rp, const int* __restrict__ es,
             const float* __restrict__ as4, const float* __restrict__ ad4,
             const _Float16* __restrict__ h, const float* __restrict__ bias,
             _Float16* __restrict__ oH, int N){
  constexpr int VEC = HC / 64;           // halves per lane (4 or 8)
  int wid  = (blockIdx.x*blockDim.x + threadIdx.x) >> 6;
  int lane = threadIdx.x & 63;
  if (wid >= N) return;
  int beg = rp[wid], end = rp[wid+1];

  const float4 adv = *(const float4*)(ad4 + (size_t)wid*4);
  const float ad0 = adv.x, ad1 = adv.y, ad2 = adv.z, ad3 = adv.w;

  float m0=-1e30f, m1=-1e30f, m2=-1e30f, m3=-1e30f;
  float s0=0.f, s1=0.f, s2=0.f, s3=0.f;
  for (int i = beg + lane; i < end; i += WAVE){
    int s = es[i];
    const float4 av = *(const float4*)(as4 + (size_t)s*4);
    float e, mn;
    e = av.x + ad0; e = (e >= 0.f) ? e : 0.2f*e;
    mn = fmaxf(m0, e); s0 = s0*__expf(m0-mn) + __expf(e-mn); m0 = mn;
    e = av.y + ad1; e = (e >= 0.f) ? e : 0.2f*e;
    mn = fmaxf(m1, e); s1 = s1*__expf(m1-mn) + __expf(e-mn); m1 = mn;
    e = av.z + ad2; e = (e >= 0.f) ? e : 0.2f*e;
    mn = fmaxf(m2, e); s2 = s2*__expf(m2-mn) + __expf(e-mn); m2 = mn;
    e = av.w + ad3; e = (e >= 0.f) ? e : 0.2f*e;
    mn = fmaxf(m3, e); s3 = s3*__expf(m3-mn) + __expf(e-mn); m3 = mn;
  }
  #pragma unroll
  for (int off = 32; off > 0; off >>= 1){
    float mo, so, mn;
    mo = __shfl_xor(m0, off, WAVE); so = __shfl_xor(s0, off, WAVE);
    mn = fmaxf(m0, mo); s0 = s0*__expf(m0-mn) + so*__expf(mo-mn); m0 = mn;
    mo = __shfl_xor(m1, off, WAVE); so = __shfl_xor(s1, off, WAVE);
    mn = fmaxf(m1, mo); s1 = s1*__expf(m1-mn) + so*__expf(mo-mn); m1 = mn;
    mo = __shfl_xor(m2, off, WAVE); so = __shfl_xor(s2, off, WAVE);
    mn = fmaxf(m2, mo); s2 = s2*__expf(m2-mn) + so*__expf(mo-mn); m2 = mn;
    mo = __shfl_xor(m3, off, WAVE); so = __shfl_xor(s3, off, WAVE);
    mn = fmaxf(m3, mo); s3 = s3*__expf(m3-mn) + so*__expf(mo-mn); m3 = mn;
  }
  const float i0 = 1.f/(s0 + 1e-16f), i1 = 1.f/(s1 + 1e-16f);
  const float i2 = 1.f/(s2 + 1e-16f), i3 = 1.f/(s3 + 1e-16f);
  const int myh = lane >> 4;

  float ac[VEC] = {};

  for (int cb = beg; cb < end; cb += WAVE){
    int nn = min(WAVE, end - cb);
    int sidx = 0;
    float w0 = 0.f, w1 = 0.f, w2 = 0.f, w3 = 0.f;
    if (cb + lane < end){
      sidx = es[cb + lane];
      const float4 av = *(const float4*)(as4 + (size_t)sidx*4);
      float e;
      e = av.x + ad0; e = (e >= 0.f) ? e : 0.2f*e; w0 = __expf(e - m0)*i0;
      e = av.y + ad1; e = (e >= 0.f) ? e : 0.2f*e; w1 = __expf(e - m1)*i1;
      e = av.z + ad2; e = (e >= 0.f) ? e : 0.2f*e; w2 = __expf(e - m2)*i2;
      e = av.w + ad3; e = (e >= 0.f) ? e : 0.2f*e; w3 = __expf(e - m3)*i3;
    }

    int j = 0;
    for (; j + 4 <= nn; j += 4){
      int sj0 = __shfl(sidx, j+0, WAVE), sj1 = __shfl(sidx, j+1, WAVE);
      int sj2 = __shfl(sidx, j+2, WAVE), sj3 = __shfl(sidx, j+3, WAVE);
      float u0 = selh(__shfl(w0,j+0,WAVE), __shfl(w1,j+0,WAVE), __shfl(w2,j+0,WAVE), __shfl(w3,j+0,WAVE), myh);
      float u1 = selh(__shfl(w0,j+1,WAVE), __shfl(w1,j+1,WAVE), __shfl(w2,j+1,WAVE), __shfl(w3,j+1,WAVE), myh);
      float u2 = selh(__shfl(w0,j+2,WAVE), __shfl(w1,j+2,WAVE), __shfl(w2,j+2,WAVE), __shfl(w3,j+2,WAVE), myh);
      float u3 = selh(__shfl(w0,j+3,WAVE), __shfl(w1,j+3,WAVE), __shfl(w2,j+3,WAVE), __shfl(w3,j+3,WAVE), myh);
      if (VEC == 4){
        h16x4 v0 = *(const h16x4*)(h + (size_t)sj0*HC + lane*4);
        h16x4 v1 = *(const h16x4*)(h + (size_t)sj1*HC + lane*4);
        h16x4 v2 = *(const h16x4*)(h + (size_t)sj2*HC + lane*4);
        h16x4 v3 = *(const h16x4*)(h + (size_t)sj3*HC + lane*4);
        #pragma unroll
        for (int c = 0; c < 4; ++c)
          ac[c] = fmaf(u0,(float)v0[c], fmaf(u1,(float)v1[c], fmaf(u2,(float)v2[c], fmaf(u3,(float)v3[c], ac[c]))));
      } else {
        h16x8 v0 = *(const h16x8*)(h + (size_t)sj0*HC + lane*8);
        h16x8 v1 = *(const h16x8*)(h + (size_t)sj1*HC + lane*8);
        h16x8 v2 = *(const h16x8*)(h + (size_t)sj2*HC + lane*8);
        h16x8 v3 = *(const h16x8*)(h + (size_t)sj3*HC + lane*8);
        #pragma unroll
        for (int c = 0; c < VEC; ++c)
          ac[c] = fmaf(u0,(float)v0[c], fmaf(u1,(float)v1[c], fmaf(u2,(float)v2[c], fmaf(u3,(float)v3[c], ac[c]))));
      }
    }
    for (; j < nn; ++j){
      int sj = __shfl(sidx, j, WAVE);
      float u = selh(__shfl(w0,j,WAVE), __shfl(w1,j,WAVE), __shfl(w2,j,WAVE), __shfl(w3,j,WAVE), myh);
      if (VEC == 4){
        h16x4 v = *(const h16x4*)(h + (size_t)sj*HC + lane*4);
        #pragma unroll
        for (int c = 0; c < 4; ++c) ac[c] = fmaf(u, (float)v[c], ac[c]);
      } else {
        h16x8 v = *(const h16x8*)(h + (size_t)sj*HC + lane*8);
        #pragma unroll
        for (int c = 0; c < VEC; ++c) ac[c] = fmaf(u, (float)v[c], ac[c]);
      }
    }
  }

  float r0=0,r1=0,r2=0,r3=0,r4=0,r5=0,r6=0,r7=0;
  {
    const float* bp = bias + lane*VEC;
    #pragma unroll
    for (int c = 0; c < VEC; ++c){
      float r = ac[c] + bp[c];
      r = r > 0.f ? r : expm1f(r);
      if (c==0) r0=r; else if (c==1) r1=r; else if (c==2) r2=r; else if (c==3) r3=r;
      else if (c==4) r4=r; else if (c==5) r5=r; else if (c==6) r6=r; else r7=r;
    }
  }
  h16x4 o;
  o[0] = (_Float16)r0; o[1] = (_Float16)r1;
  o[2] = (_Float16)r2; o[3] = (_Float16)r3;
  *(h16x4*)(oH + (size_t)wid*HC + lane*VEC) = o;
  if (VEC == 8){
    h16x4 o2;
    o2[0] = (_Float16)r4; o2[1] = (_Float16)r5;
    o2[2] = (_Float16)r6; o2[3] = (_Float16)r7;
    *(h16x4*)(oH + (size_t)wid*HC + lane*VEC + 4) = o2;
  }
}

// ---------------- pooling (fp16 input) + fused final/FC ----------------
__global__ void k_pool_partial(const _Float16* __restrict__ h, const int* __restrict__ bs,
                               float* __restrict__ psum, float* __restrict__ pmax){
  int b = blockIdx.x, ch = blockIdx.y;
  int f = threadIdx.x;
  int s = bs[b], e = bs[b+1];
  long long len = e - s;
  int i0 = s + (int)(len * ch / 8);
  int i1 = s + (int)(len * (ch+1) / 8);
  float sm = 0.f, mx = -3.0e38f;
  for (int i = i0; i < i1; ++i){
    float v = (float)h[(size_t)i*512 + f];
    sm += v; mx = fmaxf(mx, v);
  }
  int idx = (b*8 + ch)*512 + f;
  psum[idx] = sm; pmax[idx] = mx;
}

__global__ __launch_bounds__(256)
void k_fc(const float* __restrict__ psum, const float* __restrict__ pmax,
          const int* __restrict__ bs, const float* __restrict__ fcW,
          const float* __restrict__ fcb, float* __restrict__ out){
  __shared__ float gs[1024];
  __shared__ float red[4][64];
  int b = blockIdx.x, t = threadIdx.x;
  int o0 = blockIdx.y * 64;
  int cntb = bs[b+1] - bs[b];
  float inv = 1.f / fmaxf((float)cntb, 1.f);
  for (int i = t; i < 512; i += 256){
    float sm = 0.f, mx = -3.0e38f;
    #pragma unroll
    for (int c = 0; c < 8; ++c){
      int idx = (b*8 + c)*512 + i;
      sm += psum[idx]; mx = fmaxf(mx, pmax[idx]);
    }
    gs[i] = sm * inv;
    gs[512 + i] = (mx > -1e37f) ? mx : 0.f;
  }
  __syncthreads();
  int ol = t & 63, q = t >> 6;
  const float* wp = fcW + (size_t)(q*256)*512 + o0 + ol;
  float acc = 0.f;
  #pragma unroll 8
  for (int k = 0; k < 256; ++k)
    acc = fmaf(gs[q*256 + k], wp[(size_t)k*512], acc);
  red[q][ol] = acc;
  __syncthreads();
  if (t < 64){
    float r = red[0][t] + red[1][t] + red[2][t] + red[3][t] + fcb[o0 + t];
    out[b*512 + o0 + t] = r;
  }
}

// ---------------- launcher ----------------
extern "C" void kernel_launch(void* const* d_in, const int* in_sizes, int n_in,
                              void* d_out, int out_size, void* d_ws, size_t ws_size,
                              hipStream_t stream){
  (void)n_in; (void)out_size; (void)ws_size;
  const float* x     = (const float*)d_in[0];
  const int*   ei    = (const int*)d_in[1];
  const int*   batch = (const int*)d_in[2];
  const float* W[4]   = {(const float*)d_in[3],(const float*)d_in[7],(const float*)d_in[11],(const float*)d_in[15]};
  const float* asr[4] = {(const float*)d_in[4],(const float*)d_in[8],(const float*)d_in[12],(const float*)d_in[16]};
  const float* adt[4] = {(const float*)d_in[5],(const float*)d_in[9],(const float*)d_in[13],(const float*)d_in[17]};
  const float* bb[4]  = {(const float*)d_in[6],(const float*)d_in[10],(const float*)d_in[14],(const float*)d_in[18]};
  const float* fcW = (const float*)d_in[19];
  const float* fcb = (const float*)d_in[20];

  const int N  = in_sizes[0] / 128;
  const int E  = in_sizes[1] / 2;
  const int EN = E + N;
  const int B  = 32;
  const int NB = (N + 1023) / 1024;

  char* p = (char*)d_ws;
  auto alloc = [&](size_t bytes){ void* r = (void*)p; p += (bytes + 255) & ~(size_t)255; return r; };
  _Float16* hA = (_Float16*)alloc((size_t)N*512*2);        // GEMM out (gather input)
  _Float16* hB = (_Float16*)alloc((size_t)N*512*2);        // agg out (next GEMM A / pool input)
  _Float16* Wh = (_Float16*)alloc((size_t)294912*2);       // all W^T f16, packed
  float* a2   = (float*)alloc((size_t)N*8*4);              // as4 | ad4
  float* as4 = a2;
  float* ad4 = a2 + (size_t)N*4;
  int*   cntdone = (int*)alloc((size_t)(N+64)*4);          // cnt[N] + done[1]
  int*   cnt  = cntdone;
  int*   done = cntdone + N;
  int*   rp   = (int*)alloc((size_t)(N+1)*4);
  int*   cur  = (int*)alloc((size_t)N*4);
  int*   es   = (int*)alloc((size_t)EN*4);
  int*   bs   = (int*)alloc((size_t)(B+1)*4);
  int*   bsum = (int*)alloc((size_t)64*4);
  float* psum = (float*)alloc((size_t)B*8*512*4);
  float* pmax = (float*)alloc((size_t)B*8*512*4);

  // zero cnt + done in one memset
  hipMemsetAsync(cntdone, 0, (size_t)(N+1)*4, stream);

  // fused front: count | cvt16 | cvt_w_all | bounds
  const int CB = (EN + 255)/256;
  const int XB = (N*32 + 255)/256;
  const int WB = (294912 + 255)/256;
  k_front<<<CB + XB + WB + 1, 256, 0, stream>>>(ei, E, N, cnt, x, hB,
                                                W[0], W[1], W[2], W[3], Wh,
                                                batch, B, bs, CB, XB, WB);

  k_scan1<<<NB, 1024, 0, stream>>>(cnt, rp, bsum, done, N, NB);
  k_scan3<<<NB, 1024, 0, stream>>>(rp, cur, bsum, N);
  k_fill<<<(EN+255)/256, 256, 0, stream>>>(ei, E, N, cur, es);

  const int wgrid = (N + 3) / 4;
  const int Kd[4]  = {128, 256, 256, 256};
  const int HCd[4] = {256, 256, 256, 512};
  const size_t Woff[4] = {0, 32768, 98304, 163840};

  for (int L = 0; L < 4; ++L){
    const int K = Kd[L], Nc = HCd[L];
    dim3 gg((N + 127)/128, Nc/128);
    if (Nc == 256)
      k_gemm_fused<64><<<gg, 512, 0, stream>>>(hB, Wh + Woff[L], hA, asr[L], adt[L], as4, ad4, N, K, Nc);
    else
      k_gemm_fused<128><<<gg, 512, 0, stream>>>(hB, Wh + Woff[L], hA, asr[L], adt[L], as4, ad4, N, K, Nc);
    if (Nc == 256)
      k_agg_h<256><<<wgrid, 256, 0, stream>>>(rp, es, as4, ad4, hA, bb[L], hB, N);
    else
      k_agg_h<512><<<wgrid, 256, 0, stream>>>(rp, es, as4, ad4, hA, bb[L], hB, N);
  }

  dim3 pg(B, 8);
  k_pool_partial<<<pg, 512, 0, stream>>>(hB, bs, psum, pmax);
  dim3 fg(B, 8);
  k_fc<<<fg, 256, 0, stream>>>(psum, pmax, bs, fcW, fcb, (float*)d_out);
}

// Round 10
// 439.938 us; speedup vs baseline: 2.1712x; 1.0019x over previous
//
#include <hip/hip_runtime.h>
#include <math.h>

#define WAVE 64

typedef __attribute__((ext_vector_type(4))) float f32x4;
typedef _Float16 h16x4 __attribute__((ext_vector_type(4)));
typedef _Float16 h16x8 __attribute__((ext_vector_type(8)));

__device__ __forceinline__ float selh(float e0, float e1, float e2, float e3, int m){
  float r = (m == 1) ? e1 : e0;
  r = (m == 2) ? e2 : r;
  r = (m == 3) ? e3 : r;
  return r;
}

// ---------------- fused front: count | cvt16 | cvt_w_all | bounds ----------------
__global__ __launch_bounds__(256)
void k_front(const int* __restrict__ ei, int E, int N, int* __restrict__ cnt,
             const float* __restrict__ x, _Float16* __restrict__ hB,
             const float* __restrict__ W0, const float* __restrict__ W1,
             const float* __restrict__ W2, const float* __restrict__ W3,
             _Float16* __restrict__ Wh,
             const int* __restrict__ batch, int B, int* __restrict__ bs,
             int CB, int XB, int WB){
  int bid = blockIdx.x, t = threadIdx.x;
  if (bid < CB){
    int i = bid*256 + t;
    if (i < E + N){
      int d = (i < E) ? ei[E + i] : (i - E);
      atomicAdd(&cnt[d], 1);
    }
  } else if (bid < CB + XB){
    int i = (bid - CB)*256 + t;
    if (i < N*32){
      float4 v = ((const float4*)x)[i];
      h16x4 o;
      o[0] = (_Float16)v.x; o[1] = (_Float16)v.y;
      o[2] = (_Float16)v.z; o[3] = (_Float16)v.w;
      ((h16x4*)hB)[i] = o;
    }
  } else if (bid < CB + XB + WB){
    int i = (bid - CB - XB)*256 + t;
    if (i < 32768){                       // L1: K=128, Nc=256
      int k = i >> 8, n = i & 255;
      Wh[(size_t)n*128 + k] = (_Float16)W0[i];
    } else if (i < 98304){                // L2
      int j = i - 32768; int k = j >> 8, n = j & 255;
      Wh[32768 + (size_t)n*256 + k] = (_Float16)W1[j];
    } else if (i < 163840){               // L3
      int j = i - 98304; int k = j >> 8, n = j & 255;
      Wh[98304 + (size_t)n*256 + k] = (_Float16)W2[j];
    } else if (i < 294912){               // L4: K=256, Nc=512
      int j = i - 163840; int k = j >> 9, n = j & 511;
      Wh[163840 + (size_t)n*256 + k] = (_Float16)W3[j];
    }
  } else {
    int b = t;
    if (b <= B){
      int lo = 0, hi = N;
      while (lo < hi){ int mid = (lo + hi) >> 1; if (batch[mid] < b) lo = mid + 1; else hi = mid; }
      bs[b] = lo;
    }
  }
}

// ---------------- scan1 with fused block-sum scan (last-block pattern) ----------------
__global__ __launch_bounds__(1024)
void k_scan1(const int* __restrict__ cnt, int* __restrict__ rp, int* __restrict__ bsum,
             int* __restrict__ done, int N, int nb){
  __shared__ int sd[1024];
  int t = threadIdx.x, i = blockIdx.x*1024 + t;
  int v = (i < N) ? cnt[i] : 0;
  sd[t] = v;
  __syncthreads();
  for (int off = 1; off < 1024; off <<= 1){
    int x = (t >= off) ? sd[t-off] : 0;
    __syncthreads();
    sd[t] += x;
    __syncthreads();
  }
  if (i < N) rp[i] = sd[t] - v;
  if (t == 1023) bsum[blockIdx.x] = sd[1023];
  __threadfence();
  __syncthreads();
  if (t == 0){
    if (atomicAdd(done, 1) == nb - 1){
      int run = 0;
      for (int b2 = 0; b2 < nb; ++b2){ int s = bsum[b2]; bsum[b2] = run; run += s; }
      rp[N] = run;
    }
  }
}

__global__ __launch_bounds__(1024)
void k_scan3(int* __restrict__ rp, int* __restrict__ cur, const int* __restrict__ bsum, int N){
  int i = blockIdx.x*1024 + threadIdx.x;
  if (i < N){
    int v = rp[i] + bsum[blockIdx.x];
    rp[i] = v;
    cur[i] = v;
  }
}

__global__ void k_fill(const int* __restrict__ ei, int E, int N,
                       int* __restrict__ cur, int* __restrict__ es){
  int i = blockIdx.x*blockDim.x + threadIdx.x;
  if (i >= E + N) return;
  int s, d;
  if (i < E){ s = ei[i]; d = ei[E + i]; } else { s = d = i - E; }
  int pos = atomicAdd(&cur[d], 1);
  es[pos] = s;
}

// ---------------- fp16 MFMA GEMM (64x128 tile, 4 waves, dbuf LDS), fused alpha ----------------
// Tile: BM=64 rows x BN=128 cols; 4 waves (2M x 2N), each 32x64 (2x4 16x16 frags).
// Grid doubles vs 128x128 -> better machine fill for short-K latency hiding.
// LDS 30.7 KB -> 5 blocks/CU.
template<int CHEAD>
__global__ __launch_bounds__(256)
void k_gemm_fused(const _Float16* __restrict__ Ax, const _Float16* __restrict__ Bw,
                  _Float16* __restrict__ Ch,
                  const float* __restrict__ asr, const float* __restrict__ adt,
                  float* __restrict__ as4, float* __restrict__ ad4,
                  int M, int K, int Nc){
  constexpr int LDP = 40;
  __shared__ _Float16 sA[2][64*LDP], sB[2][128*LDP];   // 10 KB + 20.5 KB
  const int tid = threadIdx.x;
  const int m0 = blockIdx.x*64, n0 = blockIdx.y*128;
  const int w = tid >> 6, l = tid & 63;
  const int wr = w >> 1, wc = w & 1;          // 2M x 2N waves
  const int sr = tid >> 2, sc = (tid & 3)*8;  // 64 rows x 4 thr/row x 8 halves

  f32x4 acc00={0.f,0.f,0.f,0.f}, acc01=acc00, acc02=acc00, acc03=acc00;
  f32x4 acc10=acc00, acc11=acc00, acc12=acc00, acc13=acc00;

  const int arow = m0 + sr;
  const bool aval = arow < M;
  const size_t aoff  = (size_t)arow*K + sc;
  const size_t boff0 = (size_t)(n0 + sr)*K + sc;
  const size_t boff1 = (size_t)(n0 + 64 + sr)*K + sc;

  const int fa0 = (wr*32 + (l & 15))*LDP + (l >> 4)*8;
  const int fa1 = fa0 + 16*LDP;
  const int fb0 = (wc*64 + (l & 15))*LDP + (l >> 4)*8;
  const int steps = K >> 5;

  uint4 va = make_uint4(0,0,0,0), vb0, vb1;
  if (aval) va = *(const uint4*)(Ax + aoff);
  vb0 = *(const uint4*)(Bw + boff0);
  vb1 = *(const uint4*)(Bw + boff1);
  *(uint4*)&sA[0][sr*LDP + sc] = va;
  *(uint4*)&sB[0][sr*LDP + sc] = vb0;
  *(uint4*)&sB[0][(64 + sr)*LDP + sc] = vb1;
  __syncthreads();

  for (int ks = 0; ks < steps; ++ks){
    const int cur = ks & 1;
    const bool more = (ks + 1 < steps);
    if (more){
      const int k0 = (ks + 1)*32;
      va = make_uint4(0,0,0,0);
      if (aval) va = *(const uint4*)(Ax + aoff + k0);
      vb0 = *(const uint4*)(Bw + boff0 + k0);
      vb1 = *(const uint4*)(Bw + boff1 + k0);
    }

    h16x8 a0 = *(const h16x8*)&sA[cur][fa0];
    h16x8 a1 = *(const h16x8*)&sA[cur][fa1];
    h16x8 b;
    b = *(const h16x8*)&sB[cur][fb0];
    acc00 = __builtin_amdgcn_mfma_f32_16x16x32_f16(a0, b, acc00, 0, 0, 0);
    acc10 = __builtin_amdgcn_mfma_f32_16x16x32_f16(a1, b, acc10, 0, 0, 0);
    b = *(const h16x8*)&sB[cur][fb0 + 16*LDP];
    acc01 = __builtin_amdgcn_mfma_f32_16x16x32_f16(a0, b, acc01, 0, 0, 0);
    acc11 = __builtin_amdgcn_mfma_f32_16x16x32_f16(a1, b, acc11, 0, 0, 0);
    b = *(const h16x8*)&sB[cur][fb0 + 32*LDP];
    acc02 = __builtin_amdgcn_mfma_f32_16x16x32_f16(a0, b, acc02, 0, 0, 0);
    acc12 = __builtin_amdgcn_mfma_f32_16x16x32_f16(a1, b, acc12, 0, 0, 0);
    b = *(const h16x8*)&sB[cur][fb0 + 48*LDP];
    acc03 = __builtin_amdgcn_mfma_f32_16x16x32_f16(a0, b, acc03, 0, 0, 0);
    acc13 = __builtin_amdgcn_mfma_f32_16x16x32_f16(a1, b, acc13, 0, 0, 0);

    if (more){
      *(uint4*)&sA[cur^1][sr*LDP + sc] = va;
      *(uint4*)&sB[cur^1][sr*LDP + sc] = vb0;
      *(uint4*)&sB[cur^1][(64 + sr)*LDP + sc] = vb1;
      __syncthreads();
    }
  }

  // C/D layout per 16x16 frag: col = lane&15, row = (lane>>4)*4 + j
  const int colb = n0 + wc*64 + (l & 15);
  const float ca0 = asr[colb], ca1 = asr[colb+16], ca2 = asr[colb+32], ca3 = asr[colb+48];
  const float cd0 = adt[colb], cd1 = adt[colb+16], cd2 = adt[colb+32], cd3 = adt[colb+48];

  float psm0[4], pdm0[4], psm1[4], pdm1[4];   // compile-time unrolled only
  {
    const int rb = m0 + wr*32 + (l >> 4)*4;
    #pragma unroll
    for (int j = 0; j < 4; ++j){
      int row = rb + j;
      if (row < M){
        _Float16* hp = Ch + (size_t)row*Nc + colb;
        hp[0]  = (_Float16)acc00[j];
        hp[16] = (_Float16)acc01[j];
        hp[32] = (_Float16)acc02[j];
        hp[48] = (_Float16)acc03[j];
      }
      float ps = ca0*acc00[j] + ca1*acc01[j] + ca2*acc02[j] + ca3*acc03[j];
      float pd = cd0*acc00[j] + cd1*acc01[j] + cd2*acc02[j] + cd3*acc03[j];
      ps += __shfl_xor(ps, 1, WAVE);  pd += __shfl_xor(pd, 1, WAVE);
      ps += __shfl_xor(ps, 2, WAVE);  pd += __shfl_xor(pd, 2, WAVE);
      ps += __shfl_xor(ps, 4, WAVE);  pd += __shfl_xor(pd, 4, WAVE);
      ps += __shfl_xor(ps, 8, WAVE);  pd += __shfl_xor(pd, 8, WAVE);
      psm0[j] = ps; pdm0[j] = pd;
    }
  }
  {
    const int rb = m0 + wr*32 + 16 + (l >> 4)*4;
    #pragma unroll
    for (int j = 0; j < 4; ++j){
      int row = rb + j;
      if (row < M){
        _Float16* hp = Ch + (size_t)row*Nc + colb;
        hp[0]  = (_Float16)acc10[j];
        hp[16] = (_Float16)acc11[j];
        hp[32] = (_Float16)acc12[j];
        hp[48] = (_Float16)acc13[j];
      }
      float ps = ca0*acc10[j] + ca1*acc11[j] + ca2*acc12[j] + ca3*acc13[j];
      float pd = cd0*acc10[j] + cd1*acc11[j] + cd2*acc12[j] + cd3*acc13[j];
      ps += __shfl_xor(ps, 1, WAVE);  pd += __shfl_xor(pd, 1, WAVE);
      ps += __shfl_xor(ps, 2, WAVE);  pd += __shfl_xor(pd, 2, WAVE);
      ps += __shfl_xor(ps, 4, WAVE);  pd += __shfl_xor(pd, 4, WAVE);
      ps += __shfl_xor(ps, 8, WAVE);  pd += __shfl_xor(pd, 8, WAVE);
      psm1[j] = ps; pdm1[j] = pd;
    }
  }

  if (CHEAD == 64){
    // head hy = (n0 + wc*64)/64 = blockIdx.y*2 + wc -> unique writer per (row, head)
    const int hy = blockIdx.y*2 + wc;
    if ((l & 15) == 0){
      const int rb0 = m0 + wr*32 + (l >> 4)*4;
      #pragma unroll
      for (int j = 0; j < 4; ++j){
        int row = rb0 + j;
        if (row < M){ as4[(size_t)row*4 + hy] = psm0[j]; ad4[(size_t)row*4 + hy] = pdm0[j]; }
      }
      const int rb1 = rb0 + 16;
      #pragma unroll
      for (int j = 0; j < 4; ++j){
        int row = rb1 + j;
        if (row < M){ as4[(size_t)row*4 + hy] = psm1[j]; ad4[(size_t)row*4 + hy] = pdm1[j]; }
      }
    }
  } else {
    // CHEAD==128: head = blockIdx.y; wc=0/1 share it -> LDS reduce (64 rows x 4 floats)
    float* red = (float*)&sA[0][0];    // 1 KB
    __syncthreads();
    if ((l & 15) == 0){
      const int lr0 = wr*32 + (l >> 4)*4;
      #pragma unroll
      for (int j = 0; j < 4; ++j){
        red[(lr0 + j)*4 + wc*2 + 0] = psm0[j];
        red[(lr0 + j)*4 + wc*2 + 1] = pdm0[j];
      }
      const int lr1 = lr0 + 16;
      #pragma unroll
      for (int j = 0; j < 4; ++j){
        red[(lr1 + j)*4 + wc*2 + 0] = psm1[j];
        red[(lr1 + j)*4 + wc*2 + 1] = pdm1[j];
      }
    }
    __syncthreads();
    if (tid < 64){
      int row = m0 + tid;
      if (row < M){
        float ps = red[tid*4 + 0] + red[tid*4 + 2];
        float pd = red[tid*4 + 1] + red[tid*4 + 3];
        as4[(size_t)row*4 + blockIdx.y] = ps;
        ad4[(size_t)row*4 + blockIdx.y] = pd;
      }
    }
  }
}

// ---------------- fp16-gather agg (all layers; fp16 out) ----------------
template<int HC>
__global__ __launch_bounds__(256)
void k_agg_h(const int* __restrict__ rp, const int* __restrict__ es,
             const float* __restrict__ as4, const float* __restrict__ ad4,
             const _Float16* __restrict__ h, const float* __restrict__ bias,
             _Float16* __restrict__ oH, int N){
  constexpr int VEC = HC / 64;           // halves per lane (4 or 8)
  int wid  = (blockIdx.x*blockDim.x + threadIdx.x) >> 6;
  int lane = threadIdx.x & 63;
  if (wid >= N) return;
  int beg = rp[wid], end = rp[wid+1];

  const float4 adv = *(const float4*)(ad4 + (size_t)wid*4);
  const float ad0 = adv.x, ad1 = adv.y, ad2 = adv.z, ad3 = adv.w;

  float m0=-1e30f, m1=-1e30f, m2=-1e30f, m3=-1e30f;
  float s0=0.f, s1=0.f, s2=0.f, s3=0.f;
  for (int i = beg + lane; i < end; i += WAVE){
    int s = es[i];
    const float4 av = *(const float4*)(as4 + (size_t)s*4);
    float e, mn;
    e = av.x + ad0; e = (e >= 0.f) ? e : 0.2f*e;
    mn = fmaxf(m0, e); s0 = s0*__expf(m0-mn) + __expf(e-mn); m0 = mn;
    e = av.y + ad1; e = (e >= 0.f) ? e : 0.2f*e;
    mn = fmaxf(m1, e); s1 = s1*__expf(m1-mn) + __expf(e-mn); m1 = mn;
    e = av.z + ad2; e = (e >= 0.f) ? e : 0.2f*e;
    mn = fmaxf(m2, e); s2 = s2*__expf(m2-mn) + __expf(e-mn); m2 = mn;
    e = av.w + ad3; e = (e >= 0.f) ? e : 0.2f*e;
    mn = fmaxf(m3, e); s3 = s3*__expf(m3-mn) + __expf(e-mn); m3 = mn;
  }
  #pragma unroll
  for (int off = 32; off > 0; off >>= 1){
    float mo, so, mn;
    mo = __shfl_xor(m0, off, WAVE); so = __shfl_xor(s0, off, WAVE);
    mn = fmaxf(m0, mo); s0 = s0*__expf(m0-mn) + so*__expf(mo-mn); m0 = mn;
    mo = __shfl_xor(m1, off, WAVE); so = __shfl_xor(s1, off, WAVE);
    mn = fmaxf(m1, mo); s1 = s1*__expf(m1-mn) + so*__expf(mo-mn); m1 = mn;
    mo = __shfl_xor(m2, off, WAVE); so = __shfl_xor(s2, off, WAVE);
    mn = fmaxf(m2, mo); s2 = s2*__expf(m2-mn) + so*__expf(mo-mn); m2 = mn;
    mo = __shfl_xor(m3, off, WAVE); so = __shfl_xor(s3, off, WAVE);
    mn = fmaxf(m3, mo); s3 = s3*__expf(m3-mn) + so*__expf(mo-mn); m3 = mn;
  }
  const float i0 = 1.f/(s0 + 1e-16f), i1 = 1.f/(s1 + 1e-16f);
  const float i2 = 1.f/(s2 + 1e-16f), i3 = 1.f/(s3 + 1e-16f);
  const int myh = lane >> 4;

  float ac[VEC] = {};

  for (int cb = beg; cb < end; cb += WAVE){
    int nn = min(WAVE, end - cb);
    int sidx = 0;
    float w0 = 0.f, w1 = 0.f, w2 = 0.f, w3 = 0.f;
    if (cb + lane < end){
      sidx = es[cb + lane];
      const float4 av = *(const float4*)(as4 + (size_t)sidx*4);
      float e;
      e = av.x + ad0; e = (e >= 0.f) ? e : 0.2f*e; w0 = __expf(e - m0)*i0;
      e = av.y + ad1; e = (e >= 0.f) ? e : 0.2f*e; w1 = __expf(e - m1)*i1;
      e = av.z + ad2; e = (e >= 0.f) ? e : 0.2f*e; w2 = __expf(e - m2)*i2;
      e = av.w + ad3; e = (e >= 0.f) ? e : 0.2f*e; w3 = __expf(e - m3)*i3;
    }

    int j = 0;
    for (; j + 4 <= nn; j += 4){
      int sj0 = __shfl(sidx, j+0, WAVE), sj1 = __shfl(sidx, j+1, WAVE);
      int sj2 = __shfl(sidx, j+2, WAVE), sj3 = __shfl(sidx, j+3, WAVE);
      float u0 = selh(__shfl(w0,j+0,WAVE), __shfl(w1,j+0,WAVE), __shfl(w2,j+0,WAVE), __shfl(w3,j+0,WAVE), myh);
      float u1 = selh(__shfl(w0,j+1,WAVE), __shfl(w1,j+1,WAVE), __shfl(w2,j+1,WAVE), __shfl(w3,j+1,WAVE), myh);
      float u2 = selh(__shfl(w0,j+2,WAVE), __shfl(w1,j+2,WAVE), __shfl(w2,j+2,WAVE), __shfl(w3,j+2,WAVE), myh);
      float u3 = selh(__shfl(w0,j+3,WAVE), __shfl(w1,j+3,WAVE), __shfl(w2,j+3,WAVE), __shfl(w3,j+3,WAVE), myh);
      if (VEC == 4){
        h16x4 v0 = *(const h16x4*)(h + (size_t)sj0*HC + lane*4);
        h16x4 v1 = *(const h16x4*)(h + (size_t)sj1*HC + lane*4);
        h16x4 v2 = *(const h16x4*)(h + (size_t)sj2*HC + lane*4);
        h16x4 v3 = *(const h16x4*)(h + (size_t)sj3*HC + lane*4);
        #pragma unroll
        for (int c = 0; c < 4; ++c)
          ac[c] = fmaf(u0,(float)v0[c], fmaf(u1,(float)v1[c], fmaf(u2,(float)v2[c], fmaf(u3,(float)v3[c], ac[c]))));
      } else {
        h16x8 v0 = *(const h16x8*)(h + (size_t)sj0*HC + lane*8);
        h16x8 v1 = *(const h16x8*)(h + (size_t)sj1*HC + lane*8);
        h16x8 v2 = *(const h16x8*)(h + (size_t)sj2*HC + lane*8);
        h16x8 v3 = *(const h16x8*)(h + (size_t)sj3*HC + lane*8);
        #pragma unroll
        for (int c = 0; c < VEC; ++c)
          ac[c] = fmaf(u0,(float)v0[c], fmaf(u1,(float)v1[c], fmaf(u2,(float)v2[c], fmaf(u3,(float)v3[c], ac[c]))));
      }
    }
    for (; j < nn; ++j){
      int sj = __shfl(sidx, j, WAVE);
      float u = selh(__shfl(w0,j,WAVE), __shfl(w1,j,WAVE), __shfl(w2,j,WAVE), __shfl(w3,j,WAVE), myh);
      if (VEC == 4){
        h16x4 v = *(const h16x4*)(h + (size_t)sj*HC + lane*4);
        #pragma unroll
        for (int c = 0; c < 4; ++c) ac[c] = fmaf(u, (float)v[c], ac[c]);
      } else {
        h16x8 v = *(const h16x8*)(h + (size_t)sj*HC + lane*8);
        #pragma unroll
        for (int c = 0; c < VEC; ++c) ac[c] = fmaf(u, (float)v[c], ac[c]);
      }
    }
  }

  float r0=0,r1=0,r2=0,r3=0,r4=0,r5=0,r6=0,r7=0;
  {
    const float* bp = bias + lane*VEC;
    #pragma unroll
    for (int c = 0; c < VEC; ++c){
      float r = ac[c] + bp[c];
      r = r > 0.f ? r : expm1f(r);
      if (c==0) r0=r; else if (c==1) r1=r; else if (c==2) r2=r; else if (c==3) r3=r;
      else if (c==4) r4=r; else if (c==5) r5=r; else if (c==6) r6=r; else r7=r;
    }
  }
  h16x4 o;
  o[0] = (_Float16)r0; o[1] = (_Float16)r1;
  o[2] = (_Float16)r2; o[3] = (_Float16)r3;
  *(h16x4*)(oH + (size_t)wid*HC + lane*VEC) = o;
  if (VEC == 8){
    h16x4 o2;
    o2[0] = (_Float16)r4; o2[1] = (_Float16)r5;
    o2[2] = (_Float16)r6; o2[3] = (_Float16)r7;
    *(h16x4*)(oH + (size_t)wid*HC + lane*VEC + 4) = o2;
  }
}

// ---------------- pooling (fp16 input) + fused final/FC ----------------
__global__ void k_pool_partial(const _Float16* __restrict__ h, const int* __restrict__ bs,
                               float* __restrict__ psum, float* __restrict__ pmax){
  int b = blockIdx.x, ch = blockIdx.y;
  int f = threadIdx.x;
  int s = bs[b], e = bs[b+1];
  long long len = e - s;
  int i0 = s + (int)(len * ch / 8);
  int i1 = s + (int)(len * (ch+1) / 8);
  float sm = 0.f, mx = -3.0e38f;
  for (int i = i0; i < i1; ++i){
    float v = (float)h[(size_t)i*512 + f];
    sm += v; mx = fmaxf(mx, v);
  }
  int idx = (b*8 + ch)*512 + f;
  psum[idx] = sm; pmax[idx] = mx;
}

__global__ __launch_bounds__(256)
void k_fc(const float* __restrict__ psum, const float* __restrict__ pmax,
          const int* __restrict__ bs, const float* __restrict__ fcW,
          const float* __restrict__ fcb, float* __restrict__ out){
  __shared__ float gs[1024];
  __shared__ float red[4][64];
  int b = blockIdx.x, t = threadIdx.x;
  int o0 = blockIdx.y * 64;
  int cntb = bs[b+1] - bs[b];
  float inv = 1.f / fmaxf((float)cntb, 1.f);
  for (int i = t; i < 512; i += 256){
    float sm = 0.f, mx = -3.0e38f;
    #pragma unroll
    for (int c = 0; c < 8; ++c){
      int idx = (b*8 + c)*512 + i;
      sm += psum[idx]; mx = fmaxf(mx, pmax[idx]);
    }
    gs[i] = sm * inv;
    gs[512 + i] = (mx > -1e37f) ? mx : 0.f;
  }
  __syncthreads();
  int ol = t & 63, q = t >> 6;
  const float* wp = fcW + (size_t)(q*256)*512 + o0 + ol;
  float acc = 0.f;
  #pragma unroll 8
  for (int k = 0; k < 256; ++k)
    acc = fmaf(gs[q*256 + k], wp[(size_t)k*512], acc);
  red[q][ol] = acc;
  __syncthreads();
  if (t < 64){
    float r = red[0][t] + red[1][t] + red[2][t] + red[3][t] + fcb[o0 + t];
    out[b*512 + o0 + t] = r;
  }
}

// ---------------- launcher ----------------
extern "C" void kernel_launch(void* const* d_in, const int* in_sizes, int n_in,
                              void* d_out, int out_size, void* d_ws, size_t ws_size,
                              hipStream_t stream){
  (void)n_in; (void)out_size; (void)ws_size;
  const float* x     = (const float*)d_in[0];
  const int*   ei    = (const int*)d_in[1];
  const int*   batch = (const int*)d_in[2];
  const float* W[4]   = {(const float*)d_in[3],(const float*)d_in[7],(const float*)d_in[11],(const float*)d_in[15]};
  const float* asr[4] = {(const float*)d_in[4],(const float*)d_in[8],(const float*)d_in[12],(const float*)d_in[16]};
  const float* adt[4] = {(const float*)d_in[5],(const float*)d_in[9],(const float*)d_in[13],(const float*)d_in[17]};
  const float* bb[4]  = {(const float*)d_in[6],(const float*)d_in[10],(const float*)d_in[14],(const float*)d_in[18]};
  const float* fcW = (const float*)d_in[19];
  const float* fcb = (const float*)d_in[20];

  const int N  = in_sizes[0] / 128;
  const int E  = in_sizes[1] / 2;
  const int EN = E + N;
  const int B  = 32;
  const int NB = (N + 1023) / 1024;

  char* p = (char*)d_ws;
  auto alloc = [&](size_t bytes){ void* r = (void*)p; p += (bytes + 255) & ~(size_t)255; return r; };
  _Float16* hA = (_Float16*)alloc((size_t)N*512*2);        // GEMM out (gather input)
  _Float16* hB = (_Float16*)alloc((size_t)N*512*2);        // agg out (next GEMM A / pool input)
  _Float16* Wh = (_Float16*)alloc((size_t)294912*2);       // all W^T f16, packed
  float* a2   = (float*)alloc((size_t)N*8*4);              // as4 | ad4
  float* as4 = a2;
  float* ad4 = a2 + (size_t)N*4;
  int*   cntdone = (int*)alloc((size_t)(N+64)*4);          // cnt[N] + done[1]
  int*   cnt  = cntdone;
  int*   done = cntdone + N;
  int*   rp   = (int*)alloc((size_t)(N+1)*4);
  int*   cur  = (int*)alloc((size_t)N*4);
  int*   es   = (int*)alloc((size_t)EN*4);
  int*   bs   = (int*)alloc((size_t)(B+1)*4);
  int*   bsum = (int*)alloc((size_t)64*4);
  float* psum = (float*)alloc((size_t)B*8*512*4);
  float* pmax = (float*)alloc((size_t)B*8*512*4);

  hipMemsetAsync(cntdone, 0, (size_t)(N+1)*4, stream);

  const int CB = (EN + 255)/256;
  const int XB = (N*32 + 255)/256;
  const int WB = (294912 + 255)/256;
  k_front<<<CB + XB + WB + 1, 256, 0, stream>>>(ei, E, N, cnt, x, hB,
                                                W[0], W[1], W[2], W[3], Wh,
                                                batch, B, bs, CB, XB, WB);

  k_scan1<<<NB, 1024, 0, stream>>>(cnt, rp, bsum, done, N, NB);
  k_scan3<<<NB, 1024, 0, stream>>>(rp, cur, bsum, N);
  k_fill<<<(EN+255)/256, 256, 0, stream>>>(ei, E, N, cur, es);

  const int wgrid = (N + 3) / 4;
  const int Kd[4]  = {128, 256, 256, 256};
  const int HCd[4] = {256, 256, 256, 512};
  const size_t Woff[4] = {0, 32768, 98304, 163840};

  for (int L = 0; L < 4; ++L){
    const int K = Kd[L], Nc = HCd[L];
    dim3 gg((N + 63)/64, Nc/128);
    if (Nc == 256)
      k_gemm_fused<64><<<gg, 256, 0, stream>>>(hB, Wh + Woff[L], hA, asr[L], adt[L], as4, ad4, N, K, Nc);
    else
      k_gemm_fused<128><<<gg, 256, 0, stream>>>(hB, Wh + Woff[L], hA, asr[L], adt[L], as4, ad4, N, K, Nc);
    if (Nc == 256)
      k_agg_h<256><<<wgrid, 256, 0, stream>>>(rp, es, as4, ad4, hA, bb[L], hB, N);
    else
      k_agg_h<512><<<wgrid, 256, 0, stream>>>(rp, es, as4, ad4, hA, bb[L], hB, N);
  }

  dim3 pg(B, 8);
  k_pool_partial<<<pg, 512, 0, stream>>>(hB, bs, psum, pmax);
  dim3 fg(B, 8);
  k_fc<<<fg, 256, 0, stream>>>(psum, pmax, bs, fcW, fcb, (float*)d_out);
}